// Round 1
// baseline (3035.745 us; speedup 1.0000x reference)
//
#include <hip/hip_runtime.h>
#include <math.h>

#define HID 128
#define NSTR 6              // STRUCT-1
#define GAMMA 1.0f
#define DELTA 0.5f
#define LN_EPS 1e-5f

// order-preserving float<->uint encoding for atomicMax on floats
__device__ __forceinline__ unsigned enc_f(float f) {
    unsigned i = __float_as_uint(f);
    return (i & 0x80000000u) ? ~i : (i | 0x80000000u);
}
__device__ __forceinline__ float dec_f(unsigned u) {
    unsigned i = (u & 0x80000000u) ? (u ^ 0x80000000u) : ~u;
    return __uint_as_float(i);
}

// ---------------------------------------------------------------------------
// Y{a,p,q}[n] = H[n] @ W{a,p,q}   (three 128x128 GEMMs, W staged in LDS)
// block = 128 threads (one output column each), 64 rows per block
// ---------------------------------------------------------------------------
__global__ __launch_bounds__(128) void k_gemm3(
    const float* __restrict__ H,
    const float* __restrict__ W0, const float* __restrict__ W1, const float* __restrict__ W2,
    float* __restrict__ O0, float* __restrict__ O1, float* __restrict__ O2, int N)
{
    extern __shared__ float sm[];
    float* Wl = sm;                 // 128*128
    float* hs = sm + HID * HID;     // 64*128
    const int tid  = threadIdx.x;
    const int row0 = blockIdx.x * 64;
    const int nrows = min(64, N - row0);

    for (int r = 0; r < nrows; ++r)
        hs[r * HID + tid] = H[(size_t)(row0 + r) * HID + tid];

    const float* Ws[3] = {W0, W1, W2};
    float*       Os[3] = {O0, O1, O2};
    for (int ph = 0; ph < 3; ++ph) {
        __syncthreads();
        const float* W = Ws[ph];
        for (int i = 0; i < HID; ++i)
            Wl[i * HID + tid] = W[i * HID + tid];
        __syncthreads();
        float* O = Os[ph];
        for (int r = 0; r < nrows; ++r) {
            float acc = 0.f;
            #pragma unroll
            for (int k = 0; k < HID; ++k)
                acc = fmaf(hs[r * HID + k], Wl[k * HID + tid], acc);
            O[(size_t)(row0 + r) * HID + tid] = acc;
        }
    }
}

// Y[n] = H[n] @ W + b   (single GEMM with bias)
__global__ __launch_bounds__(128) void k_gemm1(
    const float* __restrict__ H, const float* __restrict__ W, const float* __restrict__ b,
    float* __restrict__ O, int N)
{
    extern __shared__ float sm[];
    float* Wl = sm;
    float* hs = sm + HID * HID;
    const int tid  = threadIdx.x;
    const int row0 = blockIdx.x * 64;
    const int nrows = min(64, N - row0);

    for (int r = 0; r < nrows; ++r)
        hs[r * HID + tid] = H[(size_t)(row0 + r) * HID + tid];
    for (int i = 0; i < HID; ++i)
        Wl[i * HID + tid] = W[i * HID + tid];
    const float bias = b[tid];
    __syncthreads();
    for (int r = 0; r < nrows; ++r) {
        float acc = bias;
        #pragma unroll
        for (int k = 0; k < HID; ++k)
            acc = fmaf(hs[r * HID + k], Wl[k * HID + tid], acc);
        O[(size_t)(row0 + r) * HID + tid] = acc;
    }
}

// psi[n] = dot(H[n], f_def_w) + f_def_b   (wave per node)
__global__ __launch_bounds__(256) void k_psi(
    const float* __restrict__ H, const float* __restrict__ fw, const float* __restrict__ fb,
    float* __restrict__ psi, int N)
{
    const int wid = threadIdx.x >> 6, lane = threadIdx.x & 63;
    const int n = blockIdx.x * 4 + wid;
    if (n >= N) return;
    const size_t o = (size_t)n * HID;
    float a = H[o + lane] * fw[lane] + H[o + 64 + lane] * fw[64 + lane];
    #pragma unroll
    for (int off = 32; off; off >>= 1) a += __shfl_down(a, off);
    if (lane == 0) psi[n] = a + fb[0];
}

// per edge: score = dot(H[tgt], Wh[src]) + dot(s_src, s_tgt)
//           pair  = dot(Hp[src], Hq[tgt]);   atomicMax into segment maxes
__global__ __launch_bounds__(256) void k_edge1(
    const int* __restrict__ esrc, const int* __restrict__ etgt,
    const float* __restrict__ H, const float* __restrict__ Wh,
    const float* __restrict__ Hp, const float* __restrict__ Hq,
    float* __restrict__ score, float* __restrict__ pairv,
    unsigned* __restrict__ maxt, unsigned* __restrict__ maxs, int E)
{
    const int wid = threadIdx.x >> 6, lane = threadIdx.x & 63;
    const int e = blockIdx.x * 4 + wid;
    if (e >= E) return;
    const int s = esrc[e], t = etgt[e];
    const size_t so = (size_t)s * HID, to = (size_t)t * HID;
    const float ht0 = H[to + lane], ht1 = H[to + 64 + lane];
    float ps = ht0 * Wh[so + lane] + ht1 * Wh[so + 64 + lane];
    if (lane < NSTR) ps += H[so + lane] * ht0;
    float pp = Hp[so + lane] * Hq[to + lane] + Hp[so + 64 + lane] * Hq[to + 64 + lane];
    #pragma unroll
    for (int off = 32; off; off >>= 1) {
        ps += __shfl_down(ps, off);
        pp += __shfl_down(pp, off);
    }
    if (lane == 0) {
        score[e] = ps;
        pairv[e] = pp;
        atomicMax(&maxt[t], enc_f(ps));
        atomicMax(&maxs[s], enc_f(pp));
    }
}

// per edge: exponentiate both scores against segment maxes, accumulate sums
__global__ __launch_bounds__(256) void k_exp(
    const int* __restrict__ esrc, const int* __restrict__ etgt,
    float* __restrict__ score, float* __restrict__ pairv,
    const unsigned* __restrict__ maxt, const unsigned* __restrict__ maxs,
    float* __restrict__ sumt, float* __restrict__ sums, int E)
{
    const int e = blockIdx.x * 256 + threadIdx.x;
    if (e >= E) return;
    const int s = esrc[e], t = etgt[e];
    const float es = expf(score[e] - dec_f(maxt[t]));
    score[e] = es;
    atomicAdd(&sumt[t], es);
    const float ep = expf(pairv[e] - dec_f(maxs[s]));
    pairv[e] = ep;
    atomicAdd(&sums[s], ep);
}

// per edge: sum_term[src] += beta * exp(-psi[tgt])
__global__ __launch_bounds__(256) void k_sumterm(
    const int* __restrict__ esrc, const int* __restrict__ etgt,
    const float* __restrict__ pairv, const float* __restrict__ sums,
    const float* __restrict__ psi, float* __restrict__ sumterm, int E)
{
    const int e = blockIdx.x * 256 + threadIdx.x;
    if (e >= E) return;
    const int s = esrc[e], t = etgt[e];
    const float beta = pairv[e] / sums[s];
    atomicAdd(&sumterm[s], beta * expf(-psi[t]));
}

// per node: rho1m = 1 - sigmoid(GAMMA * (-log(sum_term + 1e-8) - DELTA))
__global__ __launch_bounds__(256) void k_rho(
    const float* __restrict__ sumterm, float* __restrict__ rho1m, int N)
{
    const int n = blockIdx.x * 256 + threadIdx.x;
    if (n >= N) return;
    const float d  = -logf(sumterm[n] + 1e-8f);
    const float rr = 1.f / (1.f + expf(-(GAMMA * (d - DELTA))));
    rho1m[n] = 1.f - rr;
}

// per edge (wave): m_att[tgt] += (escore/sumt[tgt]) * rho1m[src] * Hphi[src]
__global__ __launch_bounds__(256) void k_scatter(
    const int* __restrict__ esrc, const int* __restrict__ etgt,
    const float* __restrict__ score, const float* __restrict__ sumt,
    const float* __restrict__ rho1m, const float* __restrict__ Hphi,
    float* __restrict__ matt, int E)
{
    const int wid = threadIdx.x >> 6, lane = threadIdx.x & 63;
    const int e = blockIdx.x * 4 + wid;
    if (e >= E) return;
    const int s = esrc[e], t = etgt[e];
    const float coef = (score[e] / sumt[t]) * rho1m[s];
    const size_t so = (size_t)s * HID, to = (size_t)t * HID;
    atomicAdd(&matt[to + lane],      coef * Hphi[so + lane]);
    atomicAdd(&matt[to + 64 + lane], coef * Hphi[so + 64 + lane]);
}

// final: relu(H@Wself + b + m_att@WA + b + s_feat@Wstr + b) + H, then LayerNorm
__global__ __launch_bounds__(128) void k_final(
    const float* __restrict__ H, const float* __restrict__ Matt,
    const float* __restrict__ Wself, const float* __restrict__ bself,
    const float* __restrict__ WA, const float* __restrict__ bA,
    const float* __restrict__ Wstr, const float* __restrict__ bstr,
    const float* __restrict__ lng, const float* __restrict__ lnb,
    float* __restrict__ out, int N)
{
    extern __shared__ float sm[];
    float* Ws   = sm;                       // 128*128
    float* Wa   = sm + HID * HID;           // 128*128
    float* hrow = sm + 2 * HID * HID;       // 128
    float* mrow = hrow + HID;               // 128
    float* red  = mrow + HID;               // 4
    const int tid = threadIdx.x, lane = tid & 63, wid = tid >> 6;
    const int row0 = blockIdx.x * 64;
    const int nrows = min(64, N - row0);

    for (int i = 0; i < HID; ++i) {
        Ws[i * HID + tid] = Wself[i * HID + tid];
        Wa[i * HID + tid] = WA[i * HID + tid];
    }
    const float bsum = bself[tid] + bA[tid] + bstr[tid];
    const float g = lng[tid], bb = lnb[tid];
    __syncthreads();

    for (int r = 0; r < nrows; ++r) {
        const size_t n = (size_t)(row0 + r);
        hrow[tid] = H[n * HID + tid];
        mrow[tid] = Matt[n * HID + tid];
        __syncthreads();
        float acc = bsum;
        #pragma unroll
        for (int k = 0; k < HID; ++k) acc = fmaf(hrow[k], Ws[k * HID + tid], acc);
        #pragma unroll
        for (int k = 0; k < HID; ++k) acc = fmaf(mrow[k], Wa[k * HID + tid], acc);
        #pragma unroll
        for (int j = 0; j < NSTR; ++j) acc = fmaf(hrow[j], Wstr[j * HID + tid], acc);
        const float v = fmaxf(acc, 0.f) + hrow[tid];

        float s1 = v, s2 = v * v;
        #pragma unroll
        for (int off = 32; off; off >>= 1) {
            s1 += __shfl_down(s1, off);
            s2 += __shfl_down(s2, off);
        }
        if (lane == 0) { red[wid] = s1; red[2 + wid] = s2; }
        __syncthreads();
        const float mean = (red[0] + red[1]) * (1.f / HID);
        const float var  = (red[2] + red[3]) * (1.f / HID) - mean * mean;
        out[n * HID + tid] = (v - mean) * rsqrtf(var + LN_EPS) * g + bb;
        __syncthreads();
    }
}

extern "C" void kernel_launch(void* const* d_in, const int* in_sizes, int n_in,
                              void* d_out, int out_size, void* d_ws, size_t ws_size,
                              hipStream_t stream)
{
    const int*   eidx   = (const int*)  d_in[0];
    const float* H      = (const float*)d_in[1];
    const float* W_att  = (const float*)d_in[2];
    const float* phi_w  = (const float*)d_in[3];
    const float* phi_b  = (const float*)d_in[4];
    const float* W_p    = (const float*)d_in[5];
    const float* W_pp   = (const float*)d_in[6];
    const float* fdef_w = (const float*)d_in[7];
    const float* fdef_b = (const float*)d_in[8];
    const float* Wself  = (const float*)d_in[9];
    const float* bself  = (const float*)d_in[10];
    const float* WA     = (const float*)d_in[11];
    const float* bA     = (const float*)d_in[12];
    const float* Wstr   = (const float*)d_in[13];
    const float* bstr   = (const float*)d_in[14];
    const float* lng    = (const float*)d_in[15];
    const float* lnb    = (const float*)d_in[16];
    float* out = (float*)d_out;

    const int E = in_sizes[0] / 2;
    const int N = in_sizes[1] / HID;
    const int* esrc = eidx;
    const int* etgt = eidx + E;

    // ---- workspace layout (~85 MB) ----
    char* w = (char*)d_ws;
    const size_t NH   = (size_t)N * HID * sizeof(float);            // 25.6 MB
    const size_t Epad = (((size_t)E * sizeof(float)) + 255) & ~255ull;
    const size_t Npad = (((size_t)N * sizeof(float)) + 255) & ~255ull;

    float* Wh    = (float*)w; w += NH;   // later reused as Hphi
    float* Hp    = (float*)w; w += NH;   // later reused as m_att
    float* Hq    = (float*)w; w += NH;
    float* score = (float*)w; w += Epad;
    float* pairv = (float*)w; w += Epad;
    char*  zero0 = w;                    // 5 contiguous zero-init node arrays
    unsigned* maxt    = (unsigned*)w; w += Npad;
    unsigned* maxs    = (unsigned*)w; w += Npad;
    float*    sumt    = (float*)w;    w += Npad;
    float*    sums    = (float*)w;    w += Npad;
    float*    sumterm = (float*)w;    w += Npad;
    float*    psi     = (float*)w;    w += Npad;
    float*    rho1m   = (float*)w;    w += Npad;
    float* Hphi = Wh;   // alias (Wh dead after k_edge1)
    float* matt = Hp;   // alias (Hp dead after k_edge1)

    const int nblk64 = (N + 63) / 64;
    const size_t lds_gemm  = (size_t)(HID * HID + 64 * HID) * sizeof(float);       // 96 KB
    const size_t lds_final = (size_t)(2 * HID * HID + 2 * HID + 4) * sizeof(float); // ~129 KB

    // zero: maxt, maxs, sumt, sums, sumterm (contiguous)
    hipMemsetAsync(zero0, 0, 5 * Npad, stream);

    k_gemm3<<<nblk64, 128, lds_gemm, stream>>>(H, W_att, W_p, W_pp, Wh, Hp, Hq, N);
    k_psi<<<(N + 3) / 4, 256, 0, stream>>>(H, fdef_w, fdef_b, psi, N);
    k_edge1<<<(E + 3) / 4, 256, 0, stream>>>(esrc, etgt, H, Wh, Hp, Hq,
                                             score, pairv, maxt, maxs, E);
    // Hp is dead now -> zero its buffer for m_att accumulation
    hipMemsetAsync(matt, 0, NH, stream);
    k_exp<<<(E + 255) / 256, 256, 0, stream>>>(esrc, etgt, score, pairv,
                                               maxt, maxs, sumt, sums, E);
    k_sumterm<<<(E + 255) / 256, 256, 0, stream>>>(esrc, etgt, pairv, sums,
                                                   psi, sumterm, E);
    k_rho<<<(N + 255) / 256, 256, 0, stream>>>(sumterm, rho1m, N);
    k_gemm1<<<nblk64, 128, lds_gemm, stream>>>(H, phi_w, phi_b, Hphi, N);
    k_scatter<<<(E + 3) / 4, 256, 0, stream>>>(esrc, etgt, score, sumt,
                                               rho1m, Hphi, matt, E);
    k_final<<<nblk64, 128, lds_final, stream>>>(H, matt, Wself, bself, WA, bA,
                                                Wstr, bstr, lng, lnb, out, N);
}

// Round 2
// 1073.059 us; speedup vs baseline: 2.8291x; 2.8291x over previous
//
#include <hip/hip_runtime.h>
#include <math.h>

#define HID 128
#define NSTR 6              // STRUCT-1
#define GAMMA 1.0f
#define DELTA 0.5f
#define LN_EPS 1e-5f
#define PADT 132            // padded row stride for transposed A tile

typedef __attribute__((ext_vector_type(4))) float f4;

// order-preserving float<->uint encoding for atomicMax on floats
__device__ __forceinline__ unsigned enc_f(float f) {
    unsigned i = __float_as_uint(f);
    return (i & 0x80000000u) ? ~i : (i | 0x80000000u);
}
__device__ __forceinline__ float dec_f(unsigned u) {
    unsigned i = (u & 0x80000000u) ? (u ^ 0x80000000u) : ~u;
    return __uint_as_float(i);
}

struct GemmArgs {
    const float* W[3];
    const float* b[3];
    float*       O[3];
    int          nph;
};

// ---------------------------------------------------------------------------
// Tall-skinny GEMM: O[ph] = A @ W[ph] (+ b[ph]).  Tile 128 rows x 128 cols,
// 256 threads, 8x8 micro-tile/thread. A staged transposed [k][r] (pad 132),
// W staged [k][c]. Cols per thread: {c0..c0+3} and {64+c0..64+c0+3}.
// ---------------------------------------------------------------------------
__global__ __launch_bounds__(256) void k_gemm(const float* __restrict__ A,
                                              GemmArgs g, int N)
{
    extern __shared__ float sm[];
    float* AsT = sm;              // [128][PADT]
    float* Ws  = sm + HID * PADT; // [128][128]
    const int tid  = threadIdx.x;
    const int row0 = blockIdx.x * HID;
    const int nrows = min(HID, N - row0);

    for (int i = tid; i < HID * HID; i += 256) {
        const int r = i >> 7, k = i & 127;
        AsT[k * PADT + r] = (r < nrows) ? A[(size_t)(row0 + r) * HID + k] : 0.f;
    }

    const int rg = tid >> 4, cg = tid & 15;
    const int r0 = rg * 8, c0 = cg * 4;

    for (int ph = 0; ph < g.nph; ++ph) {
        __syncthreads();   // prev-phase readers done (also covers AsT staging)
        const float* __restrict__ W = g.W[ph];
        for (int i = tid; i < HID * HID; i += 256) Ws[i] = W[i];
        __syncthreads();

        const float* bp = g.b[ph];
        float bj[8];
        #pragma unroll
        for (int j = 0; j < 4; ++j) {
            bj[j]     = bp ? bp[c0 + j]      : 0.f;
            bj[j + 4] = bp ? bp[64 + c0 + j] : 0.f;
        }
        float acc[8][8];
        #pragma unroll
        for (int i = 0; i < 8; ++i)
            #pragma unroll
            for (int j = 0; j < 8; ++j) acc[i][j] = bj[j];

        #pragma unroll 4
        for (int k = 0; k < HID; ++k) {
            const f4 a0 = *(const f4*)&AsT[k * PADT + r0];
            const f4 a1 = *(const f4*)&AsT[k * PADT + r0 + 4];
            const f4 w0 = *(const f4*)&Ws[k * HID + c0];
            const f4 w1 = *(const f4*)&Ws[k * HID + 64 + c0];
            #pragma unroll
            for (int i = 0; i < 4; ++i)
                #pragma unroll
                for (int j = 0; j < 4; ++j) {
                    acc[i][j]         = fmaf(a0[i], w0[j], acc[i][j]);
                    acc[i][j + 4]     = fmaf(a0[i], w1[j], acc[i][j + 4]);
                    acc[i + 4][j]     = fmaf(a1[i], w0[j], acc[i + 4][j]);
                    acc[i + 4][j + 4] = fmaf(a1[i], w1[j], acc[i + 4][j + 4]);
                }
        }

        float* __restrict__ O = g.O[ph];
        #pragma unroll
        for (int i = 0; i < 8; ++i) {
            const int r = r0 + i;
            if (r < nrows) {
                f4 v0, v1;
                #pragma unroll
                for (int j = 0; j < 4; ++j) { v0[j] = acc[i][j]; v1[j] = acc[i][j + 4]; }
                *(f4*)&O[(size_t)(row0 + r) * HID + c0]      = v0;
                *(f4*)&O[(size_t)(row0 + r) * HID + 64 + c0] = v1;
            }
        }
    }
}

// ---------------------------------------------------------------------------
// Fused final: out = LN(relu(H@Wself + Matt@WA + s@Wstr + biases) + H)
// Same tile structure; phase 1 = Matt@WA, phase 2 = H@Wself (+Wstr rows),
// residual read from the staged H tile, LayerNorm via 16-lane shfl_xor.
// ---------------------------------------------------------------------------
__global__ __launch_bounds__(256) void k_final(
    const float* __restrict__ H, const float* __restrict__ Matt,
    const float* __restrict__ Wself, const float* __restrict__ bself,
    const float* __restrict__ WA, const float* __restrict__ bA,
    const float* __restrict__ Wstr, const float* __restrict__ bstr,
    const float* __restrict__ lng, const float* __restrict__ lnb,
    float* __restrict__ out, int N)
{
    extern __shared__ float sm[];
    float* AsT = sm;              // [128][PADT]
    float* Ws  = sm + HID * PADT; // [128][128]
    const int tid  = threadIdx.x;
    const int row0 = blockIdx.x * HID;
    const int nrows = min(HID, N - row0);
    const int rg = tid >> 4, cg = tid & 15;
    const int r0 = rg * 8, c0 = cg * 4;

    float gg[8], bb[8], acc[8][8];
    #pragma unroll
    for (int j = 0; j < 4; ++j) {
        const int ca = c0 + j, cb = 64 + c0 + j;
        gg[j] = lng[ca];  gg[j + 4] = lng[cb];
        bb[j] = lnb[ca];  bb[j + 4] = lnb[cb];
        const float ba = bself[ca] + bA[ca] + bstr[ca];
        const float bc = bself[cb] + bA[cb] + bstr[cb];
        #pragma unroll
        for (int i = 0; i < 8; ++i) { acc[i][j] = ba; acc[i][j + 4] = bc; }
    }

    // ---- phase 1: Matt @ WA ----
    for (int i = tid; i < HID * HID; i += 256) {
        const int r = i >> 7, k = i & 127;
        AsT[k * PADT + r] = (r < nrows) ? Matt[(size_t)(row0 + r) * HID + k] : 0.f;
    }
    for (int i = tid; i < HID * HID; i += 256) Ws[i] = WA[i];
    __syncthreads();

    #pragma unroll 4
    for (int k = 0; k < HID; ++k) {
        const f4 a0 = *(const f4*)&AsT[k * PADT + r0];
        const f4 a1 = *(const f4*)&AsT[k * PADT + r0 + 4];
        const f4 w0 = *(const f4*)&Ws[k * HID + c0];
        const f4 w1 = *(const f4*)&Ws[k * HID + 64 + c0];
        #pragma unroll
        for (int i = 0; i < 4; ++i)
            #pragma unroll
            for (int j = 0; j < 4; ++j) {
                acc[i][j]         = fmaf(a0[i], w0[j], acc[i][j]);
                acc[i][j + 4]     = fmaf(a0[i], w1[j], acc[i][j + 4]);
                acc[i + 4][j]     = fmaf(a1[i], w0[j], acc[i + 4][j]);
                acc[i + 4][j + 4] = fmaf(a1[i], w1[j], acc[i + 4][j + 4]);
            }
    }
    __syncthreads();

    // ---- phase 2: H @ Wself + s_feat @ Wstr ----
    for (int i = tid; i < HID * HID; i += 256) {
        const int r = i >> 7, k = i & 127;
        AsT[k * PADT + r] = (r < nrows) ? H[(size_t)(row0 + r) * HID + k] : 0.f;
    }
    for (int i = tid; i < HID * HID; i += 256) Ws[i] = Wself[i];
    __syncthreads();

    #pragma unroll 4
    for (int k = 0; k < HID; ++k) {
        const f4 a0 = *(const f4*)&AsT[k * PADT + r0];
        const f4 a1 = *(const f4*)&AsT[k * PADT + r0 + 4];
        const f4 w0 = *(const f4*)&Ws[k * HID + c0];
        const f4 w1 = *(const f4*)&Ws[k * HID + 64 + c0];
        #pragma unroll
        for (int i = 0; i < 4; ++i)
            #pragma unroll
            for (int j = 0; j < 4; ++j) {
                acc[i][j]         = fmaf(a0[i], w0[j], acc[i][j]);
                acc[i][j + 4]     = fmaf(a0[i], w1[j], acc[i][j + 4]);
                acc[i + 4][j]     = fmaf(a1[i], w0[j], acc[i + 4][j]);
                acc[i + 4][j + 4] = fmaf(a1[i], w1[j], acc[i + 4][j + 4]);
            }
    }

    // s_feat (= H[:, :6]) @ Wstr — Wstr read from global (L1/L2 hot)
    #pragma unroll
    for (int k = 0; k < NSTR; ++k) {
        const f4 a0 = *(const f4*)&AsT[k * PADT + r0];
        const f4 a1 = *(const f4*)&AsT[k * PADT + r0 + 4];
        #pragma unroll
        for (int j = 0; j < 4; ++j) {
            const float wa = Wstr[k * HID + c0 + j];
            const float wb = Wstr[k * HID + 64 + c0 + j];
            #pragma unroll
            for (int i = 0; i < 4; ++i) {
                acc[i][j]         = fmaf(a0[i], wa, acc[i][j]);
                acc[i][j + 4]     = fmaf(a0[i], wb, acc[i][j + 4]);
                acc[i + 4][j]     = fmaf(a1[i], wa, acc[i + 4][j]);
                acc[i + 4][j + 4] = fmaf(a1[i], wb, acc[i + 4][j + 4]);
            }
        }
    }

    // ---- relu + residual + LayerNorm ----
    #pragma unroll
    for (int i = 0; i < 8; ++i) {
        const int r = r0 + i;
        float v[8];
        #pragma unroll
        for (int j = 0; j < 4; ++j) {
            v[j]     = fmaxf(acc[i][j],     0.f) + AsT[(c0 + j) * PADT + r];
            v[j + 4] = fmaxf(acc[i][j + 4], 0.f) + AsT[(64 + c0 + j) * PADT + r];
        }
        float s1 = 0.f, s2 = 0.f;
        #pragma unroll
        for (int j = 0; j < 8; ++j) { s1 += v[j]; s2 += v[j] * v[j]; }
        #pragma unroll
        for (int m = 1; m < 16; m <<= 1) {
            s1 += __shfl_xor(s1, m);
            s2 += __shfl_xor(s2, m);
        }
        const float mean = s1 * (1.f / HID);
        const float var  = s2 * (1.f / HID) - mean * mean;
        const float rs   = rsqrtf(var + LN_EPS);
        if (r < nrows) {
            f4 o0, o1;
            #pragma unroll
            for (int j = 0; j < 4; ++j) {
                o0[j] = (v[j]     - mean) * rs * gg[j]     + bb[j];
                o1[j] = (v[j + 4] - mean) * rs * gg[j + 4] + bb[j + 4];
            }
            *(f4*)&out[(size_t)(row0 + r) * HID + c0]      = o0;
            *(f4*)&out[(size_t)(row0 + r) * HID + 64 + c0] = o1;
        }
    }
}

// psi[n] = dot(H[n], f_def_w) + f_def_b   (wave per node)
__global__ __launch_bounds__(256) void k_psi(
    const float* __restrict__ H, const float* __restrict__ fw, const float* __restrict__ fb,
    float* __restrict__ psi, int N)
{
    const int wid = threadIdx.x >> 6, lane = threadIdx.x & 63;
    const int n = blockIdx.x * 4 + wid;
    if (n >= N) return;
    const size_t o = (size_t)n * HID;
    float a = H[o + lane] * fw[lane] + H[o + 64 + lane] * fw[64 + lane];
    #pragma unroll
    for (int off = 32; off; off >>= 1) a += __shfl_down(a, off);
    if (lane == 0) psi[n] = a + fb[0];
}

// per edge: score = dot(H[tgt], Wh[src]) + dot(s_src, s_tgt)
//           pair  = dot(Hp[src], Hq[tgt]);   atomicMax into segment maxes
__global__ __launch_bounds__(256) void k_edge1(
    const int* __restrict__ esrc, const int* __restrict__ etgt,
    const float* __restrict__ H, const float* __restrict__ Wh,
    const float* __restrict__ Hp, const float* __restrict__ Hq,
    float* __restrict__ score, float* __restrict__ pairv,
    unsigned* __restrict__ maxt, unsigned* __restrict__ maxs, int E)
{
    const int wid = threadIdx.x >> 6, lane = threadIdx.x & 63;
    const int e = blockIdx.x * 4 + wid;
    if (e >= E) return;
    const int s = esrc[e], t = etgt[e];
    const size_t so = (size_t)s * HID, to = (size_t)t * HID;
    const float ht0 = H[to + lane], ht1 = H[to + 64 + lane];
    float ps = ht0 * Wh[so + lane] + ht1 * Wh[so + 64 + lane];
    if (lane < NSTR) ps += H[so + lane] * ht0;
    float pp = Hp[so + lane] * Hq[to + lane] + Hp[so + 64 + lane] * Hq[to + 64 + lane];
    #pragma unroll
    for (int off = 32; off; off >>= 1) {
        ps += __shfl_down(ps, off);
        pp += __shfl_down(pp, off);
    }
    if (lane == 0) {
        score[e] = ps;
        pairv[e] = pp;
        atomicMax(&maxt[t], enc_f(ps));
        atomicMax(&maxs[s], enc_f(pp));
    }
}

// per edge: exponentiate both scores against segment maxes, accumulate sums
__global__ __launch_bounds__(256) void k_exp(
    const int* __restrict__ esrc, const int* __restrict__ etgt,
    float* __restrict__ score, float* __restrict__ pairv,
    const unsigned* __restrict__ maxt, const unsigned* __restrict__ maxs,
    float* __restrict__ sumt, float* __restrict__ sums, int E)
{
    const int e = blockIdx.x * 256 + threadIdx.x;
    if (e >= E) return;
    const int s = esrc[e], t = etgt[e];
    const float es = expf(score[e] - dec_f(maxt[t]));
    score[e] = es;
    atomicAdd(&sumt[t], es);
    const float ep = expf(pairv[e] - dec_f(maxs[s]));
    pairv[e] = ep;
    atomicAdd(&sums[s], ep);
}

// per edge: sum_term[src] += beta * exp(-psi[tgt])
__global__ __launch_bounds__(256) void k_sumterm(
    const int* __restrict__ esrc, const int* __restrict__ etgt,
    const float* __restrict__ pairv, const float* __restrict__ sums,
    const float* __restrict__ psi, float* __restrict__ sumterm, int E)
{
    const int e = blockIdx.x * 256 + threadIdx.x;
    if (e >= E) return;
    const int s = esrc[e], t = etgt[e];
    const float beta = pairv[e] / sums[s];
    atomicAdd(&sumterm[s], beta * expf(-psi[t]));
}

// per node: rho1m = 1 - sigmoid(GAMMA * (-log(sum_term + 1e-8) - DELTA))
__global__ __launch_bounds__(256) void k_rho(
    const float* __restrict__ sumterm, float* __restrict__ rho1m, int N)
{
    const int n = blockIdx.x * 256 + threadIdx.x;
    if (n >= N) return;
    const float d  = -logf(sumterm[n] + 1e-8f);
    const float rr = 1.f / (1.f + expf(-(GAMMA * (d - DELTA))));
    rho1m[n] = 1.f - rr;
}

// per edge (wave): m_att[tgt] += (escore/sumt[tgt]) * rho1m[src] * Hphi[src]
__global__ __launch_bounds__(256) void k_scatter(
    const int* __restrict__ esrc, const int* __restrict__ etgt,
    const float* __restrict__ score, const float* __restrict__ sumt,
    const float* __restrict__ rho1m, const float* __restrict__ Hphi,
    float* __restrict__ matt, int E)
{
    const int wid = threadIdx.x >> 6, lane = threadIdx.x & 63;
    const int e = blockIdx.x * 4 + wid;
    if (e >= E) return;
    const int s = esrc[e], t = etgt[e];
    const float coef = (score[e] / sumt[t]) * rho1m[s];
    const size_t so = (size_t)s * HID, to = (size_t)t * HID;
    atomicAdd(&matt[to + lane],      coef * Hphi[so + lane]);
    atomicAdd(&matt[to + 64 + lane], coef * Hphi[so + 64 + lane]);
}

extern "C" void kernel_launch(void* const* d_in, const int* in_sizes, int n_in,
                              void* d_out, int out_size, void* d_ws, size_t ws_size,
                              hipStream_t stream)
{
    const int*   eidx   = (const int*)  d_in[0];
    const float* H      = (const float*)d_in[1];
    const float* W_att  = (const float*)d_in[2];
    const float* phi_w  = (const float*)d_in[3];
    const float* phi_b  = (const float*)d_in[4];
    const float* W_p    = (const float*)d_in[5];
    const float* W_pp   = (const float*)d_in[6];
    const float* fdef_w = (const float*)d_in[7];
    const float* fdef_b = (const float*)d_in[8];
    const float* Wself  = (const float*)d_in[9];
    const float* bself  = (const float*)d_in[10];
    const float* WA     = (const float*)d_in[11];
    const float* bA     = (const float*)d_in[12];
    const float* Wstr   = (const float*)d_in[13];
    const float* bstr   = (const float*)d_in[14];
    const float* lng    = (const float*)d_in[15];
    const float* lnb    = (const float*)d_in[16];
    float* out = (float*)d_out;

    const int E = in_sizes[0] / 2;
    const int N = in_sizes[1] / HID;
    const int* esrc = eidx;
    const int* etgt = eidx + E;

    // ---- workspace layout (~85 MB) ----
    char* w = (char*)d_ws;
    const size_t NH   = (size_t)N * HID * sizeof(float);            // 25.6 MB
    const size_t Epad = (((size_t)E * sizeof(float)) + 255) & ~255ull;
    const size_t Npad = (((size_t)N * sizeof(float)) + 255) & ~255ull;

    float* Wh    = (float*)w; w += NH;   // later reused as Hphi
    float* Hp    = (float*)w; w += NH;   // later reused as m_att
    float* Hq    = (float*)w; w += NH;
    float* score = (float*)w; w += Epad;
    float* pairv = (float*)w; w += Epad;
    char*  zero0 = w;                    // 5 contiguous zero-init node arrays
    unsigned* maxt    = (unsigned*)w; w += Npad;
    unsigned* maxs    = (unsigned*)w; w += Npad;
    float*    sumt    = (float*)w;    w += Npad;
    float*    sums    = (float*)w;    w += Npad;
    float*    sumterm = (float*)w;    w += Npad;
    float*    psi     = (float*)w;    w += Npad;
    float*    rho1m   = (float*)w;    w += Npad;
    float* Hphi = Wh;   // alias (Wh dead after k_edge1)
    float* matt = Hp;   // alias (Hp dead after k_edge1)

    const int nblk128 = (N + 127) / 128;
    const size_t lds_gemm = (size_t)(HID * PADT + HID * HID) * sizeof(float); // 130 KB

    // zero: maxt, maxs, sumt, sums, sumterm (contiguous)
    hipMemsetAsync(zero0, 0, 5 * Npad, stream);

    GemmArgs g3;
    g3.W[0] = W_att; g3.W[1] = W_p; g3.W[2] = W_pp;
    g3.b[0] = nullptr; g3.b[1] = nullptr; g3.b[2] = nullptr;
    g3.O[0] = Wh; g3.O[1] = Hp; g3.O[2] = Hq;
    g3.nph = 3;
    k_gemm<<<nblk128, 256, lds_gemm, stream>>>(H, g3, N);

    k_psi<<<(N + 3) / 4, 256, 0, stream>>>(H, fdef_w, fdef_b, psi, N);
    k_edge1<<<(E + 3) / 4, 256, 0, stream>>>(esrc, etgt, H, Wh, Hp, Hq,
                                             score, pairv, maxt, maxs, E);
    // Hp is dead now -> zero its buffer for m_att accumulation
    hipMemsetAsync(matt, 0, NH, stream);
    k_exp<<<(E + 255) / 256, 256, 0, stream>>>(esrc, etgt, score, pairv,
                                               maxt, maxs, sumt, sums, E);
    k_sumterm<<<(E + 255) / 256, 256, 0, stream>>>(esrc, etgt, pairv, sums,
                                                   psi, sumterm, E);
    k_rho<<<(N + 255) / 256, 256, 0, stream>>>(sumterm, rho1m, N);

    GemmArgs g1;
    g1.W[0] = phi_w; g1.W[1] = nullptr; g1.W[2] = nullptr;
    g1.b[0] = phi_b; g1.b[1] = nullptr; g1.b[2] = nullptr;
    g1.O[0] = Hphi;  g1.O[1] = nullptr; g1.O[2] = nullptr;
    g1.nph = 1;
    k_gemm<<<nblk128, 256, lds_gemm, stream>>>(H, g1, N);

    k_scatter<<<(E + 3) / 4, 256, 0, stream>>>(esrc, etgt, score, sumt,
                                               rho1m, Hphi, matt, E);
    k_final<<<nblk128, 256, lds_gemm, stream>>>(H, matt, Wself, bself, WA, bA,
                                                Wstr, bstr, lng, lnb, out, N);
}

// Round 3
// 811.277 us; speedup vs baseline: 3.7419x; 1.3227x over previous
//
#include <hip/hip_runtime.h>
#include <math.h>

#define HID 128
#define NSTR 6              // STRUCT-1
#define GAMMA 1.0f
#define DELTA 0.5f
#define LN_EPS 1e-5f
#define PADT 132            // padded row stride for transposed A tile

typedef __attribute__((ext_vector_type(4))) float f4;

// order-preserving float<->uint encoding for atomicMax on floats
__device__ __forceinline__ unsigned enc_f(float f) {
    unsigned i = __float_as_uint(f);
    return (i & 0x80000000u) ? ~i : (i | 0x80000000u);
}
__device__ __forceinline__ float dec_f(unsigned u) {
    unsigned i = (u & 0x80000000u) ? (u ^ 0x80000000u) : ~u;
    return __uint_as_float(i);
}

struct GemmArgs {
    const float* W[3];
    const float* b[3];
    float*       O[3];
    int          nph;
};

// ---------------------------------------------------------------------------
// Tall-skinny GEMM: O[ph] = A @ W[ph] (+ b[ph]).  128x128 tile, 256 threads,
// 8x8 micro-tile/thread. (unchanged from round 1 — no longer the bottleneck)
// ---------------------------------------------------------------------------
__global__ __launch_bounds__(256) void k_gemm(const float* __restrict__ A,
                                              GemmArgs g, int N)
{
    extern __shared__ float sm[];
    float* AsT = sm;              // [128][PADT]
    float* Ws  = sm + HID * PADT; // [128][128]
    const int tid  = threadIdx.x;
    const int row0 = blockIdx.x * HID;
    const int nrows = min(HID, N - row0);

    for (int i = tid; i < HID * HID; i += 256) {
        const int r = i >> 7, k = i & 127;
        AsT[k * PADT + r] = (r < nrows) ? A[(size_t)(row0 + r) * HID + k] : 0.f;
    }

    const int rg = tid >> 4, cg = tid & 15;
    const int r0 = rg * 8, c0 = cg * 4;

    for (int ph = 0; ph < g.nph; ++ph) {
        __syncthreads();
        const float* __restrict__ W = g.W[ph];
        for (int i = tid; i < HID * HID; i += 256) Ws[i] = W[i];
        __syncthreads();

        const float* bp = g.b[ph];
        float bj[8];
        #pragma unroll
        for (int j = 0; j < 4; ++j) {
            bj[j]     = bp ? bp[c0 + j]      : 0.f;
            bj[j + 4] = bp ? bp[64 + c0 + j] : 0.f;
        }
        float acc[8][8];
        #pragma unroll
        for (int i = 0; i < 8; ++i)
            #pragma unroll
            for (int j = 0; j < 8; ++j) acc[i][j] = bj[j];

        #pragma unroll 4
        for (int k = 0; k < HID; ++k) {
            const f4 a0 = *(const f4*)&AsT[k * PADT + r0];
            const f4 a1 = *(const f4*)&AsT[k * PADT + r0 + 4];
            const f4 w0 = *(const f4*)&Ws[k * HID + c0];
            const f4 w1 = *(const f4*)&Ws[k * HID + 64 + c0];
            #pragma unroll
            for (int i = 0; i < 4; ++i)
                #pragma unroll
                for (int j = 0; j < 4; ++j) {
                    acc[i][j]         = fmaf(a0[i], w0[j], acc[i][j]);
                    acc[i][j + 4]     = fmaf(a0[i], w1[j], acc[i][j + 4]);
                    acc[i + 4][j]     = fmaf(a1[i], w0[j], acc[i + 4][j]);
                    acc[i + 4][j + 4] = fmaf(a1[i], w1[j], acc[i + 4][j + 4]);
                }
        }

        float* __restrict__ O = g.O[ph];
        #pragma unroll
        for (int i = 0; i < 8; ++i) {
            const int r = r0 + i;
            if (r < nrows) {
                f4 v0, v1;
                #pragma unroll
                for (int j = 0; j < 4; ++j) { v0[j] = acc[i][j]; v1[j] = acc[i][j + 4]; }
                *(f4*)&O[(size_t)(row0 + r) * HID + c0]      = v0;
                *(f4*)&O[(size_t)(row0 + r) * HID + 64 + c0] = v1;
            }
        }
    }
}

// ---------------------------------------------------------------------------
// Fused final: out = LN(relu(H@Wself + Matt@WA + s@Wstr + biases) + H)
// ---------------------------------------------------------------------------
__global__ __launch_bounds__(256) void k_final(
    const float* __restrict__ H, const float* __restrict__ Matt,
    const float* __restrict__ Wself, const float* __restrict__ bself,
    const float* __restrict__ WA, const float* __restrict__ bA,
    const float* __restrict__ Wstr, const float* __restrict__ bstr,
    const float* __restrict__ lng, const float* __restrict__ lnb,
    float* __restrict__ out, int N)
{
    extern __shared__ float sm[];
    float* AsT = sm;              // [128][PADT]
    float* Ws  = sm + HID * PADT; // [128][128]
    const int tid  = threadIdx.x;
    const int row0 = blockIdx.x * HID;
    const int nrows = min(HID, N - row0);
    const int rg = tid >> 4, cg = tid & 15;
    const int r0 = rg * 8, c0 = cg * 4;

    float gg[8], bb[8], acc[8][8];
    #pragma unroll
    for (int j = 0; j < 4; ++j) {
        const int ca = c0 + j, cb = 64 + c0 + j;
        gg[j] = lng[ca];  gg[j + 4] = lng[cb];
        bb[j] = lnb[ca];  bb[j + 4] = lnb[cb];
        const float ba = bself[ca] + bA[ca] + bstr[ca];
        const float bc = bself[cb] + bA[cb] + bstr[cb];
        #pragma unroll
        for (int i = 0; i < 8; ++i) { acc[i][j] = ba; acc[i][j + 4] = bc; }
    }

    // ---- phase 1: Matt @ WA ----
    for (int i = tid; i < HID * HID; i += 256) {
        const int r = i >> 7, k = i & 127;
        AsT[k * PADT + r] = (r < nrows) ? Matt[(size_t)(row0 + r) * HID + k] : 0.f;
    }
    for (int i = tid; i < HID * HID; i += 256) Ws[i] = WA[i];
    __syncthreads();

    #pragma unroll 4
    for (int k = 0; k < HID; ++k) {
        const f4 a0 = *(const f4*)&AsT[k * PADT + r0];
        const f4 a1 = *(const f4*)&AsT[k * PADT + r0 + 4];
        const f4 w0 = *(const f4*)&Ws[k * HID + c0];
        const f4 w1 = *(const f4*)&Ws[k * HID + 64 + c0];
        #pragma unroll
        for (int i = 0; i < 4; ++i)
            #pragma unroll
            for (int j = 0; j < 4; ++j) {
                acc[i][j]         = fmaf(a0[i], w0[j], acc[i][j]);
                acc[i][j + 4]     = fmaf(a0[i], w1[j], acc[i][j + 4]);
                acc[i + 4][j]     = fmaf(a1[i], w0[j], acc[i + 4][j]);
                acc[i + 4][j + 4] = fmaf(a1[i], w1[j], acc[i + 4][j + 4]);
            }
    }
    __syncthreads();

    // ---- phase 2: H @ Wself + s_feat @ Wstr ----
    for (int i = tid; i < HID * HID; i += 256) {
        const int r = i >> 7, k = i & 127;
        AsT[k * PADT + r] = (r < nrows) ? H[(size_t)(row0 + r) * HID + k] : 0.f;
    }
    for (int i = tid; i < HID * HID; i += 256) Ws[i] = Wself[i];
    __syncthreads();

    #pragma unroll 4
    for (int k = 0; k < HID; ++k) {
        const f4 a0 = *(const f4*)&AsT[k * PADT + r0];
        const f4 a1 = *(const f4*)&AsT[k * PADT + r0 + 4];
        const f4 w0 = *(const f4*)&Ws[k * HID + c0];
        const f4 w1 = *(const f4*)&Ws[k * HID + 64 + c0];
        #pragma unroll
        for (int i = 0; i < 4; ++i)
            #pragma unroll
            for (int j = 0; j < 4; ++j) {
                acc[i][j]         = fmaf(a0[i], w0[j], acc[i][j]);
                acc[i][j + 4]     = fmaf(a0[i], w1[j], acc[i][j + 4]);
                acc[i + 4][j]     = fmaf(a1[i], w0[j], acc[i + 4][j]);
                acc[i + 4][j + 4] = fmaf(a1[i], w1[j], acc[i + 4][j + 4]);
            }
    }

    #pragma unroll
    for (int k = 0; k < NSTR; ++k) {
        const f4 a0 = *(const f4*)&AsT[k * PADT + r0];
        const f4 a1 = *(const f4*)&AsT[k * PADT + r0 + 4];
        #pragma unroll
        for (int j = 0; j < 4; ++j) {
            const float wa = Wstr[k * HID + c0 + j];
            const float wb = Wstr[k * HID + 64 + c0 + j];
            #pragma unroll
            for (int i = 0; i < 4; ++i) {
                acc[i][j]         = fmaf(a0[i], wa, acc[i][j]);
                acc[i][j + 4]     = fmaf(a0[i], wb, acc[i][j + 4]);
                acc[i + 4][j]     = fmaf(a1[i], wa, acc[i + 4][j]);
                acc[i + 4][j + 4] = fmaf(a1[i], wb, acc[i + 4][j + 4]);
            }
        }
    }

    // ---- relu + residual + LayerNorm ----
    #pragma unroll
    for (int i = 0; i < 8; ++i) {
        const int r = r0 + i;
        float v[8];
        #pragma unroll
        for (int j = 0; j < 4; ++j) {
            v[j]     = fmaxf(acc[i][j],     0.f) + AsT[(c0 + j) * PADT + r];
            v[j + 4] = fmaxf(acc[i][j + 4], 0.f) + AsT[(64 + c0 + j) * PADT + r];
        }
        float s1 = 0.f, s2 = 0.f;
        #pragma unroll
        for (int j = 0; j < 8; ++j) { s1 += v[j]; s2 += v[j] * v[j]; }
        #pragma unroll
        for (int m = 1; m < 16; m <<= 1) {
            s1 += __shfl_xor(s1, m);
            s2 += __shfl_xor(s2, m);
        }
        const float mean = s1 * (1.f / HID);
        const float var  = s2 * (1.f / HID) - mean * mean;
        const float rs   = rsqrtf(var + LN_EPS);
        if (r < nrows) {
            f4 o0, o1;
            #pragma unroll
            for (int j = 0; j < 4; ++j) {
                o0[j] = (v[j]     - mean) * rs * gg[j]     + bb[j];
                o1[j] = (v[j + 4] - mean) * rs * gg[j + 4] + bb[j + 4];
            }
            *(f4*)&out[(size_t)(row0 + r) * HID + c0]      = o0;
            *(f4*)&out[(size_t)(row0 + r) * HID + 64 + c0] = o1;
        }
    }
}

// psi[n] = dot(H[n], f_def_w) + f_def_b   (wave per node)
__global__ __launch_bounds__(256) void k_psi(
    const float* __restrict__ H, const float* __restrict__ fw, const float* __restrict__ fb,
    float* __restrict__ psi, int N)
{
    const int wid = threadIdx.x >> 6, lane = threadIdx.x & 63;
    const int n = blockIdx.x * 4 + wid;
    if (n >= N) return;
    const size_t o = (size_t)n * HID;
    float a = H[o + lane] * fw[lane] + H[o + 64 + lane] * fw[64 + lane];
    #pragma unroll
    for (int off = 32; off; off >>= 1) a += __shfl_down(a, off);
    if (lane == 0) psi[n] = a + fb[0];
}

// ---------------------------------------------------------------------------
// CSR-by-target build: histogram, single-block scan, fill
// ---------------------------------------------------------------------------
__global__ __launch_bounds__(256) void k_hist(
    const int* __restrict__ etgt, int* __restrict__ deg, int E)
{
    const int e = blockIdx.x * 256 + threadIdx.x;
    if (e < E) atomicAdd(&deg[etgt[e]], 1);
}

__global__ __launch_bounds__(1024) void k_scan(
    const int* __restrict__ deg, int* __restrict__ base, int N)
{
    __shared__ int warp_sums[16];
    __shared__ int carry_s;
    const int tid = threadIdx.x, lane = tid & 63, wid = tid >> 6;
    if (tid == 0) carry_s = 0;
    __syncthreads();
    for (int i0 = 0; i0 < N; i0 += 1024) {
        const int i = i0 + tid;
        const int v = (i < N) ? deg[i] : 0;
        int x = v;
        #pragma unroll
        for (int d = 1; d < 64; d <<= 1) {
            const int y = __shfl_up(x, d);
            if (lane >= d) x += y;
        }
        if (lane == 63) warp_sums[wid] = x;
        __syncthreads();
        if (wid == 0) {
            int ws = (lane < 16) ? warp_sums[lane] : 0;
            #pragma unroll
            for (int d = 1; d < 16; d <<= 1) {
                const int y = __shfl_up(ws, d);
                if (lane >= d) ws += y;
            }
            if (lane < 16) warp_sums[lane] = ws;
        }
        __syncthreads();
        const int carry = carry_s;
        if (i < N) base[i] = carry + (wid ? warp_sums[wid - 1] : 0) + x - v;
        __syncthreads();
        if (tid == 1023) carry_s = carry + warp_sums[15];
        __syncthreads();
    }
    if (tid == 0) base[N] = carry_s;
}

__global__ __launch_bounds__(256) void k_fill(
    const int* __restrict__ etgt, const int* __restrict__ base,
    int* __restrict__ cur, int* __restrict__ eid_t, int E)
{
    const int e = blockIdx.x * 256 + threadIdx.x;
    if (e < E) {
        const int t = etgt[e];
        const int p = atomicAdd(&cur[t], 1);
        eid_t[base[t] + p] = e;
    }
}

// ---------------------------------------------------------------------------
// k_score: wave per TARGET node. Computes BOTH edge dots with tgt-side
// operands resident in registers; alpha softmax fully in-wave (no atomics);
// raw pair scores scattered for the beta path (+ atomicMax by src).
// ---------------------------------------------------------------------------
__global__ __launch_bounds__(256) void k_score(
    const int* __restrict__ eid_t, const int* __restrict__ base_t,
    const int* __restrict__ esrc,
    const float* __restrict__ H, const float* __restrict__ Wh,
    const float* __restrict__ Hp, const float* __restrict__ Hq,
    float* __restrict__ score, float* __restrict__ pairv,
    unsigned* __restrict__ maxs, float* __restrict__ sumt_inv, int N)
{
    const int lane = threadIdx.x & 63, wv = threadIdx.x >> 6;
    const int t = blockIdx.x * 4 + wv;
    if (t >= N) return;
    const int b0 = base_t[t], deg = base_t[t + 1] - b0;
    if (deg == 0) { if (lane == 0) sumt_inv[t] = 0.f; return; }
    const size_t to = (size_t)t * HID;
    const float2 ht = *(const float2*)&H[to + 2 * lane];
    const float2 hq = *(const float2*)&Hq[to + 2 * lane];
    const float stl = (lane < NSTR) ? H[to + lane] : 0.f;

    float m = -1e30f;
    float mysc = 0.f;
    for (int j0 = 0; j0 < deg; j0 += 64) {
        const int jn = min(64, deg - j0);
        const int myidx = j0 + lane;
        const int myeid = (myidx < deg) ? eid_t[b0 + myidx] : 0;
        const int mysrc = (myidx < deg) ? esrc[myeid] : 0;
        float mysc_c = 0.f;
        for (int j = 0; j < jn; ++j) {
            const int src = __shfl(mysrc, j);
            const size_t so = (size_t)src * HID;
            const float2 wh = *(const float2*)&Wh[so + 2 * lane];
            const float2 hp = *(const float2*)&Hp[so + 2 * lane];
            float ps = ht.x * wh.x + ht.y * wh.y;
            if (lane < NSTR) ps += H[so + lane] * stl;
            float pp = hp.x * hq.x + hp.y * hq.y;
            #pragma unroll
            for (int mk = 1; mk < 64; mk <<= 1) {
                ps += __shfl_xor(ps, mk);
                pp += __shfl_xor(pp, mk);
            }
            if (lane == j) {
                mysc_c = ps;
                pairv[myeid] = pp;
                atomicMax(&maxs[mysrc], enc_f(pp));
            }
            m = fmaxf(m, ps);
        }
        if (deg > 64 && myidx < deg) score[b0 + myidx] = mysc_c;
        mysc = mysc_c;
    }
    // alpha = exp(score - max); store exp'ed, keep 1/sum per node
    float psum = 0.f;
    if (deg <= 64) {
        float e = 0.f;
        if (lane < deg) { e = expf(mysc - m); score[b0 + lane] = e; }
        psum = e;
    } else {
        for (int j0 = 0; j0 < deg; j0 += 64) {
            const int myidx = j0 + lane;
            if (myidx < deg) {
                const float e = expf(score[b0 + myidx] - m);
                score[b0 + myidx] = e;
                psum += e;
            }
        }
    }
    #pragma unroll
    for (int mk = 1; mk < 64; mk <<= 1) psum += __shfl_xor(psum, mk);
    if (lane == 0) sumt_inv[t] = 1.f / psum;
}

// per edge: e = exp(pair - max_src); sums[s] += e; num[s] += e * exp(-psi[t])
__global__ __launch_bounds__(256) void k_beta(
    const int* __restrict__ esrc, const int* __restrict__ etgt,
    const float* __restrict__ pairv, const unsigned* __restrict__ maxs,
    const float* __restrict__ psi,
    float* __restrict__ sums, float* __restrict__ num, int E)
{
    const int e = blockIdx.x * 256 + threadIdx.x;
    if (e >= E) return;
    const int s = esrc[e], t = etgt[e];
    const float ep = expf(pairv[e] - dec_f(maxs[s]));
    atomicAdd(&sums[s], ep);
    atomicAdd(&num[s], ep * expf(-psi[t]));
}

// per node: sum_term = num/sums; rho1m = 1 - sigmoid(GAMMA*(-log(st+1e-8)-DELTA))
__global__ __launch_bounds__(256) void k_rho(
    const float* __restrict__ sums, const float* __restrict__ num,
    float* __restrict__ rho1m, int N)
{
    const int n = blockIdx.x * 256 + threadIdx.x;
    if (n >= N) return;
    const float sm = sums[n];
    const float st = (sm > 0.f) ? num[n] / sm : 0.f;
    const float d  = -logf(st + 1e-8f);
    rho1m[n] = 1.f - 1.f / (1.f + expf(-(GAMMA * (d - DELTA))));
}

// wave per TARGET node: matt[t] = sum_e alpha_e * rho1m[src] * Hphi[src]
__global__ __launch_bounds__(256) void k_matt(
    const int* __restrict__ eid_t, const int* __restrict__ base_t,
    const int* __restrict__ esrc,
    const float* __restrict__ score, const float* __restrict__ sumt_inv,
    const float* __restrict__ rho1m, const float* __restrict__ Hphi,
    float* __restrict__ matt, int N)
{
    const int lane = threadIdx.x & 63, wv = threadIdx.x >> 6;
    const int t = blockIdx.x * 4 + wv;
    if (t >= N) return;
    const int b0 = base_t[t], deg = base_t[t + 1] - b0;
    float2 acc = {0.f, 0.f};
    const float inv = sumt_inv[t];
    for (int j0 = 0; j0 < deg; j0 += 64) {
        const int jn = min(64, deg - j0);
        const int myidx = j0 + lane;
        int mysrc = 0; float myc = 0.f;
        if (myidx < deg) {
            const int eid = eid_t[b0 + myidx];
            mysrc = esrc[eid];
            myc = score[b0 + myidx] * inv * rho1m[mysrc];
        }
        for (int j = 0; j < jn; ++j) {
            const int src = __shfl(mysrc, j);
            const float c = __shfl(myc, j);
            const float2 hp = *(const float2*)&Hphi[(size_t)src * HID + 2 * lane];
            acc.x = fmaf(c, hp.x, acc.x);
            acc.y = fmaf(c, hp.y, acc.y);
        }
    }
    *(float2*)&matt[(size_t)t * HID + 2 * lane] = acc;
}

extern "C" void kernel_launch(void* const* d_in, const int* in_sizes, int n_in,
                              void* d_out, int out_size, void* d_ws, size_t ws_size,
                              hipStream_t stream)
{
    const int*   eidx   = (const int*)  d_in[0];
    const float* H      = (const float*)d_in[1];
    const float* W_att  = (const float*)d_in[2];
    const float* phi_w  = (const float*)d_in[3];
    const float* phi_b  = (const float*)d_in[4];
    const float* W_p    = (const float*)d_in[5];
    const float* W_pp   = (const float*)d_in[6];
    const float* fdef_w = (const float*)d_in[7];
    const float* fdef_b = (const float*)d_in[8];
    const float* Wself  = (const float*)d_in[9];
    const float* bself  = (const float*)d_in[10];
    const float* WA     = (const float*)d_in[11];
    const float* bA     = (const float*)d_in[12];
    const float* Wstr   = (const float*)d_in[13];
    const float* bstr   = (const float*)d_in[14];
    const float* lng    = (const float*)d_in[15];
    const float* lnb    = (const float*)d_in[16];
    float* out = (float*)d_out;

    const int E = in_sizes[0] / 2;
    const int N = in_sizes[1] / HID;
    const int* esrc = eidx;
    const int* etgt = eidx + E;

    // ---- workspace layout (~88 MB) ----
    char* w = (char*)d_ws;
    const size_t NH   = (size_t)N * HID * sizeof(float);              // 25.6 MB
    const size_t Epad = (((size_t)E * sizeof(float)) + 255) & ~255ull;
    const size_t Npad = (((size_t)(N + 1) * sizeof(float)) + 255) & ~255ull;

    float* Wh    = (float*)w; w += NH;   // later reused as Hphi
    float* Hp    = (float*)w; w += NH;   // later reused as m_att
    float* Hq    = (float*)w; w += NH;
    float* score = (float*)w; w += Epad; // exp'ed alpha, CSR order
    float* pairv = (float*)w; w += Epad; // raw pair scores, edge order
    int*   eid_t = (int*)  w; w += Epad;
    char*  zero0 = w;                    // 5 contiguous zero-init arrays
    int*      deg_t = (int*)     w; w += Npad;
    int*      cur_t = (int*)     w; w += Npad;
    unsigned* maxs  = (unsigned*)w; w += Npad;
    float*    sums  = (float*)   w; w += Npad;
    float*    num   = (float*)   w; w += Npad;
    int*   base_t   = (int*)     w; w += Npad;  // N+1 entries
    float* sumt_inv = (float*)   w; w += Npad;
    float* psi      = (float*)   w; w += Npad;
    float* rho1m    = (float*)   w; w += Npad;
    float* Hphi = Wh;   // alias (Wh dead after k_score)
    float* matt = Hp;   // alias (Hp dead after k_score)

    const int nblk128 = (N + 127) / 128;
    const int nblkN4  = (N + 3) / 4;
    const int nblkE   = (E + 255) / 256;
    const size_t lds_gemm = (size_t)(HID * PADT + HID * HID) * sizeof(float); // 130 KB

    hipMemsetAsync(zero0, 0, 5 * Npad, stream);  // deg_t, cur_t, maxs, sums, num

    GemmArgs g3;
    g3.W[0] = W_att; g3.W[1] = W_p; g3.W[2] = W_pp;
    g3.b[0] = nullptr; g3.b[1] = nullptr; g3.b[2] = nullptr;
    g3.O[0] = Wh; g3.O[1] = Hp; g3.O[2] = Hq;
    g3.nph = 3;
    k_gemm<<<nblk128, 256, lds_gemm, stream>>>(H, g3, N);

    k_psi<<<nblkN4, 256, 0, stream>>>(H, fdef_w, fdef_b, psi, N);

    k_hist<<<nblkE, 256, 0, stream>>>(etgt, deg_t, E);
    k_scan<<<1, 1024, 0, stream>>>(deg_t, base_t, N);
    k_fill<<<nblkE, 256, 0, stream>>>(etgt, base_t, cur_t, eid_t, E);

    k_score<<<nblkN4, 256, 0, stream>>>(eid_t, base_t, esrc, H, Wh, Hp, Hq,
                                        score, pairv, maxs, sumt_inv, N);
    k_beta<<<nblkE, 256, 0, stream>>>(esrc, etgt, pairv, maxs, psi, sums, num, E);
    k_rho<<<(N + 255) / 256, 256, 0, stream>>>(sums, num, rho1m, N);

    GemmArgs g1;
    g1.W[0] = phi_w; g1.W[1] = nullptr; g1.W[2] = nullptr;
    g1.b[0] = phi_b; g1.b[1] = nullptr; g1.b[2] = nullptr;
    g1.O[0] = Hphi;  g1.O[1] = nullptr; g1.O[2] = nullptr;
    g1.nph = 1;
    k_gemm<<<nblk128, 256, lds_gemm, stream>>>(H, g1, N);

    k_matt<<<nblkN4, 256, 0, stream>>>(eid_t, base_t, esrc, score, sumt_inv,
                                       rho1m, Hphi, matt, N);

    k_final<<<nblk128, 256, lds_gemm, stream>>>(H, matt, Wself, bself, WA, bA,
                                                Wstr, bstr, lng, lnb, out, N);
}

// Round 4
// 679.508 us; speedup vs baseline: 4.4676x; 1.1939x over previous
//
#include <hip/hip_runtime.h>
#include <math.h>

#define HID 128
#define NSTR 6              // STRUCT-1
#define GAMMA 1.0f
#define DELTA 0.5f
#define LN_EPS 1e-5f
#define PADT 132            // padded row stride for transposed A tile

typedef __attribute__((ext_vector_type(4))) float f4;

// order-preserving float<->uint encoding for atomicMax on floats
__device__ __forceinline__ unsigned enc_f(float f) {
    unsigned i = __float_as_uint(f);
    return (i & 0x80000000u) ? ~i : (i | 0x80000000u);
}
__device__ __forceinline__ float dec_f(unsigned u) {
    unsigned i = (u & 0x80000000u) ? (u ^ 0x80000000u) : ~u;
    return __uint_as_float(i);
}

// f32 -> bf16 (round-to-nearest-even), bf16x2-in-uint -> two f32
__device__ __forceinline__ unsigned short f2bf(float f) {
    unsigned u = __float_as_uint(f);
    unsigned r = u + 0x7FFFu + ((u >> 16) & 1u);
    return (unsigned short)(r >> 16);
}
__device__ __forceinline__ void bf2f2(unsigned u, float& lo, float& hi) {
    lo = __uint_as_float(u << 16);
    hi = __uint_as_float(u & 0xFFFF0000u);
}
// unpack 8 bf16 (uint4) -> float[8]
__device__ __forceinline__ void unpack8(const uint4 u, float* f) {
    bf2f2(u.x, f[0], f[1]); bf2f2(u.y, f[2], f[3]);
    bf2f2(u.z, f[4], f[5]); bf2f2(u.w, f[6], f[7]);
}

struct GemmArgs {
    const float*    W[4];
    const float*    b[4];
    unsigned short* O[4];
    int             nph;
};

// ---------------------------------------------------------------------------
// Tall-skinny GEMM: O[ph] = bf16( A @ W[ph] (+ b[ph]) ).  128x128 tile,
// 256 threads, 8x8 micro-tile/thread, up to 4 phases sharing the A tile.
// ---------------------------------------------------------------------------
__global__ __launch_bounds__(256) void k_gemm(const float* __restrict__ A,
                                              GemmArgs g, int N)
{
    extern __shared__ float sm[];
    float* AsT = sm;              // [128][PADT]
    float* Ws  = sm + HID * PADT; // [128][128]
    const int tid  = threadIdx.x;
    const int row0 = blockIdx.x * HID;
    const int nrows = min(HID, N - row0);

    for (int i = tid; i < HID * HID; i += 256) {
        const int r = i >> 7, k = i & 127;
        AsT[k * PADT + r] = (r < nrows) ? A[(size_t)(row0 + r) * HID + k] : 0.f;
    }

    const int rg = tid >> 4, cg = tid & 15;
    const int r0 = rg * 8, c0 = cg * 4;

    for (int ph = 0; ph < g.nph; ++ph) {
        __syncthreads();
        const float* __restrict__ W = g.W[ph];
        for (int i = tid; i < HID * HID; i += 256) Ws[i] = W[i];
        __syncthreads();

        const float* bp = g.b[ph];
        float bj[8];
        #pragma unroll
        for (int j = 0; j < 4; ++j) {
            bj[j]     = bp ? bp[c0 + j]      : 0.f;
            bj[j + 4] = bp ? bp[64 + c0 + j] : 0.f;
        }
        float acc[8][8];
        #pragma unroll
        for (int i = 0; i < 8; ++i)
            #pragma unroll
            for (int j = 0; j < 8; ++j) acc[i][j] = bj[j];

        #pragma unroll 4
        for (int k = 0; k < HID; ++k) {
            const f4 a0 = *(const f4*)&AsT[k * PADT + r0];
            const f4 a1 = *(const f4*)&AsT[k * PADT + r0 + 4];
            const f4 w0 = *(const f4*)&Ws[k * HID + c0];
            const f4 w1 = *(const f4*)&Ws[k * HID + 64 + c0];
            #pragma unroll
            for (int i = 0; i < 4; ++i)
                #pragma unroll
                for (int j = 0; j < 4; ++j) {
                    acc[i][j]         = fmaf(a0[i], w0[j], acc[i][j]);
                    acc[i][j + 4]     = fmaf(a0[i], w1[j], acc[i][j + 4]);
                    acc[i + 4][j]     = fmaf(a1[i], w0[j], acc[i + 4][j]);
                    acc[i + 4][j + 4] = fmaf(a1[i], w1[j], acc[i + 4][j + 4]);
                }
        }

        unsigned short* __restrict__ O = g.O[ph];
        #pragma unroll
        for (int i = 0; i < 8; ++i) {
            const int r = r0 + i;
            if (r < nrows) {
                ushort4 v0, v1;
                v0.x = f2bf(acc[i][0]); v0.y = f2bf(acc[i][1]);
                v0.z = f2bf(acc[i][2]); v0.w = f2bf(acc[i][3]);
                v1.x = f2bf(acc[i][4]); v1.y = f2bf(acc[i][5]);
                v1.z = f2bf(acc[i][6]); v1.w = f2bf(acc[i][7]);
                *(ushort4*)&O[(size_t)(row0 + r) * HID + c0]      = v0;
                *(ushort4*)&O[(size_t)(row0 + r) * HID + 64 + c0] = v1;
            }
        }
    }
}

// ---------------------------------------------------------------------------
// Fused final: out = LN(relu(H@Wself + Matt@WA + s@Wstr + biases) + H)
// ---------------------------------------------------------------------------
__global__ __launch_bounds__(256) void k_final(
    const float* __restrict__ H, const float* __restrict__ Matt,
    const float* __restrict__ Wself, const float* __restrict__ bself,
    const float* __restrict__ WA, const float* __restrict__ bA,
    const float* __restrict__ Wstr, const float* __restrict__ bstr,
    const float* __restrict__ lng, const float* __restrict__ lnb,
    float* __restrict__ out, int N)
{
    extern __shared__ float sm[];
    float* AsT = sm;              // [128][PADT]
    float* Ws  = sm + HID * PADT; // [128][128]
    const int tid  = threadIdx.x;
    const int row0 = blockIdx.x * HID;
    const int nrows = min(HID, N - row0);
    const int rg = tid >> 4, cg = tid & 15;
    const int r0 = rg * 8, c0 = cg * 4;

    float gg[8], bb[8], acc[8][8];
    #pragma unroll
    for (int j = 0; j < 4; ++j) {
        const int ca = c0 + j, cb = 64 + c0 + j;
        gg[j] = lng[ca];  gg[j + 4] = lng[cb];
        bb[j] = lnb[ca];  bb[j + 4] = lnb[cb];
        const float ba = bself[ca] + bA[ca] + bstr[ca];
        const float bc = bself[cb] + bA[cb] + bstr[cb];
        #pragma unroll
        for (int i = 0; i < 8; ++i) { acc[i][j] = ba; acc[i][j + 4] = bc; }
    }

    // ---- phase 1: Matt @ WA ----
    for (int i = tid; i < HID * HID; i += 256) {
        const int r = i >> 7, k = i & 127;
        AsT[k * PADT + r] = (r < nrows) ? Matt[(size_t)(row0 + r) * HID + k] : 0.f;
    }
    for (int i = tid; i < HID * HID; i += 256) Ws[i] = WA[i];
    __syncthreads();

    #pragma unroll 4
    for (int k = 0; k < HID; ++k) {
        const f4 a0 = *(const f4*)&AsT[k * PADT + r0];
        const f4 a1 = *(const f4*)&AsT[k * PADT + r0 + 4];
        const f4 w0 = *(const f4*)&Ws[k * HID + c0];
        const f4 w1 = *(const f4*)&Ws[k * HID + 64 + c0];
        #pragma unroll
        for (int i = 0; i < 4; ++i)
            #pragma unroll
            for (int j = 0; j < 4; ++j) {
                acc[i][j]         = fmaf(a0[i], w0[j], acc[i][j]);
                acc[i][j + 4]     = fmaf(a0[i], w1[j], acc[i][j + 4]);
                acc[i + 4][j]     = fmaf(a1[i], w0[j], acc[i + 4][j]);
                acc[i + 4][j + 4] = fmaf(a1[i], w1[j], acc[i + 4][j + 4]);
            }
    }
    __syncthreads();

    // ---- phase 2: H @ Wself + s_feat @ Wstr ----
    for (int i = tid; i < HID * HID; i += 256) {
        const int r = i >> 7, k = i & 127;
        AsT[k * PADT + r] = (r < nrows) ? H[(size_t)(row0 + r) * HID + k] : 0.f;
    }
    for (int i = tid; i < HID * HID; i += 256) Ws[i] = Wself[i];
    __syncthreads();

    #pragma unroll 4
    for (int k = 0; k < HID; ++k) {
        const f4 a0 = *(const f4*)&AsT[k * PADT + r0];
        const f4 a1 = *(const f4*)&AsT[k * PADT + r0 + 4];
        const f4 w0 = *(const f4*)&Ws[k * HID + c0];
        const f4 w1 = *(const f4*)&Ws[k * HID + 64 + c0];
        #pragma unroll
        for (int i = 0; i < 4; ++i)
            #pragma unroll
            for (int j = 0; j < 4; ++j) {
                acc[i][j]         = fmaf(a0[i], w0[j], acc[i][j]);
                acc[i][j + 4]     = fmaf(a0[i], w1[j], acc[i][j + 4]);
                acc[i + 4][j]     = fmaf(a1[i], w0[j], acc[i + 4][j]);
                acc[i + 4][j + 4] = fmaf(a1[i], w1[j], acc[i + 4][j + 4]);
            }
    }

    #pragma unroll
    for (int k = 0; k < NSTR; ++k) {
        const f4 a0 = *(const f4*)&AsT[k * PADT + r0];
        const f4 a1 = *(const f4*)&AsT[k * PADT + r0 + 4];
        #pragma unroll
        for (int j = 0; j < 4; ++j) {
            const float wa = Wstr[k * HID + c0 + j];
            const float wb = Wstr[k * HID + 64 + c0 + j];
            #pragma unroll
            for (int i = 0; i < 4; ++i) {
                acc[i][j]         = fmaf(a0[i], wa, acc[i][j]);
                acc[i][j + 4]     = fmaf(a0[i], wb, acc[i][j + 4]);
                acc[i + 4][j]     = fmaf(a1[i], wa, acc[i + 4][j]);
                acc[i + 4][j + 4] = fmaf(a1[i], wb, acc[i + 4][j + 4]);
            }
        }
    }

    // ---- relu + residual + LayerNorm ----
    #pragma unroll
    for (int i = 0; i < 8; ++i) {
        const int r = r0 + i;
        float v[8];
        #pragma unroll
        for (int j = 0; j < 4; ++j) {
            v[j]     = fmaxf(acc[i][j],     0.f) + AsT[(c0 + j) * PADT + r];
            v[j + 4] = fmaxf(acc[i][j + 4], 0.f) + AsT[(64 + c0 + j) * PADT + r];
        }
        float s1 = 0.f, s2 = 0.f;
        #pragma unroll
        for (int j = 0; j < 8; ++j) { s1 += v[j]; s2 += v[j] * v[j]; }
        #pragma unroll
        for (int m = 1; m < 16; m <<= 1) {
            s1 += __shfl_xor(s1, m);
            s2 += __shfl_xor(s2, m);
        }
        const float mean = s1 * (1.f / HID);
        const float var  = s2 * (1.f / HID) - mean * mean;
        const float rs   = rsqrtf(var + LN_EPS);
        if (r < nrows) {
            f4 o0, o1;
            #pragma unroll
            for (int j = 0; j < 4; ++j) {
                o0[j] = (v[j]     - mean) * rs * gg[j]     + bb[j];
                o1[j] = (v[j + 4] - mean) * rs * gg[j + 4] + bb[j + 4];
            }
            *(f4*)&out[(size_t)(row0 + r) * HID + c0]      = o0;
            *(f4*)&out[(size_t)(row0 + r) * HID + 64 + c0] = o1;
        }
    }
}

// psi[n] = dot(H[n], f_def_w) + f_def_b   (wave per node)
__global__ __launch_bounds__(256) void k_psi(
    const float* __restrict__ H, const float* __restrict__ fw, const float* __restrict__ fb,
    float* __restrict__ psi, int N)
{
    const int wid = threadIdx.x >> 6, lane = threadIdx.x & 63;
    const int n = blockIdx.x * 4 + wid;
    if (n >= N) return;
    const size_t o = (size_t)n * HID;
    float a = H[o + lane] * fw[lane] + H[o + 64 + lane] * fw[64 + lane];
    #pragma unroll
    for (int off = 32; off; off >>= 1) a += __shfl_down(a, off);
    if (lane == 0) psi[n] = a + fb[0];
}

// ---------------------------------------------------------------------------
// CSR-by-target build: histogram, single-block scan, fill
// ---------------------------------------------------------------------------
__global__ __launch_bounds__(256) void k_hist(
    const int* __restrict__ etgt, int* __restrict__ deg, int E)
{
    const int e = blockIdx.x * 256 + threadIdx.x;
    if (e < E) atomicAdd(&deg[etgt[e]], 1);
}

__global__ __launch_bounds__(1024) void k_scan(
    const int* __restrict__ deg, int* __restrict__ base, int N)
{
    __shared__ int warp_sums[16];
    __shared__ int carry_s;
    const int tid = threadIdx.x, lane = tid & 63, wid = tid >> 6;
    if (tid == 0) carry_s = 0;
    __syncthreads();
    for (int i0 = 0; i0 < N; i0 += 1024) {
        const int i = i0 + tid;
        const int v = (i < N) ? deg[i] : 0;
        int x = v;
        #pragma unroll
        for (int d = 1; d < 64; d <<= 1) {
            const int y = __shfl_up(x, d);
            if (lane >= d) x += y;
        }
        if (lane == 63) warp_sums[wid] = x;
        __syncthreads();
        if (wid == 0) {
            int ws = (lane < 16) ? warp_sums[lane] : 0;
            #pragma unroll
            for (int d = 1; d < 16; d <<= 1) {
                const int y = __shfl_up(ws, d);
                if (lane >= d) ws += y;
            }
            if (lane < 16) warp_sums[lane] = ws;
        }
        __syncthreads();
        const int carry = carry_s;
        if (i < N) base[i] = carry + (wid ? warp_sums[wid - 1] : 0) + x - v;
        __syncthreads();
        if (tid == 1023) carry_s = carry + warp_sums[15];
        __syncthreads();
    }
    if (tid == 0) base[N] = carry_s;
}

__global__ __launch_bounds__(256) void k_fill(
    const int* __restrict__ etgt, const int* __restrict__ base,
    int* __restrict__ cur, int* __restrict__ eid_t, int E)
{
    const int e = blockIdx.x * 256 + threadIdx.x;
    if (e < E) {
        const int t = etgt[e];
        const int p = atomicAdd(&cur[t], 1);
        eid_t[base[t] + p] = e;
    }
}

// ---------------------------------------------------------------------------
// k_score: wave per TARGET node, 16-lane edge groups (4 edges in flight).
// Gathers are bf16 rows (256 B). Alpha softmax in-wave via score[] re-pass.
// ---------------------------------------------------------------------------
__global__ __launch_bounds__(256) void k_score(
    const int* __restrict__ eid_t, const int* __restrict__ base_t,
    const int* __restrict__ esrc,
    const float* __restrict__ H,
    const unsigned short* __restrict__ WhB,
    const unsigned short* __restrict__ HpB,
    const unsigned short* __restrict__ HqB,
    float* __restrict__ score, float* __restrict__ pairv,
    unsigned* __restrict__ maxs, float* __restrict__ sumt_inv, int N)
{
    const int lane = threadIdx.x & 63, wv = threadIdx.x >> 6;
    const int t = blockIdx.x * 4 + wv;
    if (t >= N) return;
    const int b0 = base_t[t], deg = base_t[t + 1] - b0;
    if (deg == 0) { if (lane == 0) sumt_inv[t] = 0.f; return; }
    const int sub = lane & 15, grp = lane >> 4;
    const size_t to = (size_t)t * HID;

    // tgt-side slices (dims sub*8 .. sub*8+7) resident in registers
    float ht[8], hq[8];
    {
        const f4 h0 = *(const f4*)&H[to + sub * 8];
        const f4 h1 = *(const f4*)&H[to + sub * 8 + 4];
        ht[0] = h0[0]; ht[1] = h0[1]; ht[2] = h0[2]; ht[3] = h0[3];
        ht[4] = h1[0]; ht[5] = h1[1]; ht[6] = h1[2]; ht[7] = h1[3];
        unpack8(*(const uint4*)&HqB[to + sub * 8], hq);
    }

    for (int j0 = 0; j0 < deg; j0 += 4) {
        const int jj = j0 + grp;
        const bool val = jj < deg;
        int eid = 0, src = 0;
        if (val) { eid = eid_t[b0 + jj]; src = esrc[eid]; }
        const size_t so = (size_t)src * HID;
        float wh[8], hp[8];
        unpack8(*(const uint4*)&WhB[so + sub * 8], wh);
        unpack8(*(const uint4*)&HpB[so + sub * 8], hp);
        float ps = 0.f, pp = 0.f;
        #pragma unroll
        for (int d = 0; d < 8; ++d) {
            ps = fmaf(ht[d], wh[d], ps);
            pp = fmaf(hp[d], hq[d], pp);
        }
        if (sub == 0) {  // struct term: dims 0..5 (this lane holds ht[0..7]=dims 0..7)
            const f4 s0 = *(const f4*)&H[so];
            const float2 s1 = *(const float2*)&H[so + 4];
            ps += s0[0]*ht[0] + s0[1]*ht[1] + s0[2]*ht[2] + s0[3]*ht[3]
                + s1.x*ht[4] + s1.y*ht[5];
        }
        #pragma unroll
        for (int mk = 1; mk < 16; mk <<= 1) {
            ps += __shfl_xor(ps, mk);
            pp += __shfl_xor(pp, mk);
        }
        if (sub == 0 && val) {
            score[b0 + jj] = ps;
            pairv[eid] = pp;
            atomicMax(&maxs[src], enc_f(pp));
        }
    }

    // alpha softmax over score[b0 .. b0+deg)
    float m = -1e30f;
    for (int i = lane; i < deg; i += 64) m = fmaxf(m, score[b0 + i]);
    #pragma unroll
    for (int mk = 1; mk < 64; mk <<= 1) m = fmaxf(m, __shfl_xor(m, mk));
    float psum = 0.f;
    for (int i = lane; i < deg; i += 64) {
        const float e = expf(score[b0 + i] - m);
        score[b0 + i] = e;
        psum += e;
    }
    #pragma unroll
    for (int mk = 1; mk < 64; mk <<= 1) psum += __shfl_xor(psum, mk);
    if (lane == 0) sumt_inv[t] = 1.f / psum;
}

// per edge: e = exp(pair - max_src); sums[s] += e; num[s] += e * exp(-psi[t])
__global__ __launch_bounds__(256) void k_beta(
    const int* __restrict__ esrc, const int* __restrict__ etgt,
    const float* __restrict__ pairv, const unsigned* __restrict__ maxs,
    const float* __restrict__ psi,
    float* __restrict__ sums, float* __restrict__ num, int E)
{
    const int e = blockIdx.x * 256 + threadIdx.x;
    if (e >= E) return;
    const int s = esrc[e], t = etgt[e];
    const float ep = expf(pairv[e] - dec_f(maxs[s]));
    atomicAdd(&sums[s], ep);
    atomicAdd(&num[s], ep * expf(-psi[t]));
}

// per node: sum_term = num/sums; rho1m = 1 - sigmoid(GAMMA*(-log(st+1e-8)-DELTA))
__global__ __launch_bounds__(256) void k_rho(
    const float* __restrict__ sums, const float* __restrict__ num,
    float* __restrict__ rho1m, int N)
{
    const int n = blockIdx.x * 256 + threadIdx.x;
    if (n >= N) return;
    const float sm = sums[n];
    const float st = (sm > 0.f) ? num[n] / sm : 0.f;
    const float d  = -logf(st + 1e-8f);
    rho1m[n] = 1.f - 1.f / (1.f + expf(-(GAMMA * (d - DELTA))));
}

// ---------------------------------------------------------------------------
// k_matt: wave per TARGET, 16-lane edge groups; Hphi gathered as bf16.
// matt[t] = sum_e alpha_e * rho1m[src] * Hphi[src]
// ---------------------------------------------------------------------------
__global__ __launch_bounds__(256) void k_matt(
    const int* __restrict__ eid_t, const int* __restrict__ base_t,
    const int* __restrict__ esrc,
    const float* __restrict__ score, const float* __restrict__ sumt_inv,
    const float* __restrict__ rho1m,
    const unsigned short* __restrict__ HphiB,
    float* __restrict__ matt, int N)
{
    const int lane = threadIdx.x & 63, wv = threadIdx.x >> 6;
    const int t = blockIdx.x * 4 + wv;
    if (t >= N) return;
    const int b0 = base_t[t], deg = base_t[t + 1] - b0;
    const int sub = lane & 15, grp = lane >> 4;
    const size_t to = (size_t)t * HID;

    float acc[8];
    #pragma unroll
    for (int d = 0; d < 8; ++d) acc[d] = 0.f;
    const float inv = (deg > 0) ? sumt_inv[t] : 0.f;

    for (int j0 = 0; j0 < deg; j0 += 4) {
        const int jj = j0 + grp;
        const bool val = jj < deg;
        float c = 0.f;
        size_t so = 0;
        if (val) {
            const int eid = eid_t[b0 + jj];
            const int src = esrc[eid];
            c = score[b0 + jj] * inv * rho1m[src];
            so = (size_t)src * HID;
        }
        float hf[8];
        unpack8(*(const uint4*)&HphiB[so + sub * 8], hf);
        #pragma unroll
        for (int d = 0; d < 8; ++d) acc[d] = fmaf(c, hf[d], acc[d]);
    }
    #pragma unroll
    for (int d = 0; d < 8; ++d) {
        acc[d] += __shfl_xor(acc[d], 16);
        acc[d] += __shfl_xor(acc[d], 32);
    }
    if (grp == 0) {
        f4 o0, o1;
        #pragma unroll
        for (int d = 0; d < 4; ++d) { o0[d] = acc[d]; o1[d] = acc[d + 4]; }
        *(f4*)&matt[to + sub * 8]     = o0;
        *(f4*)&matt[to + sub * 8 + 4] = o1;
    }
}

extern "C" void kernel_launch(void* const* d_in, const int* in_sizes, int n_in,
                              void* d_out, int out_size, void* d_ws, size_t ws_size,
                              hipStream_t stream)
{
    const int*   eidx   = (const int*)  d_in[0];
    const float* H      = (const float*)d_in[1];
    const float* W_att  = (const float*)d_in[2];
    const float* phi_w  = (const float*)d_in[3];
    const float* phi_b  = (const float*)d_in[4];
    const float* W_p    = (const float*)d_in[5];
    const float* W_pp   = (const float*)d_in[6];
    const float* fdef_w = (const float*)d_in[7];
    const float* fdef_b = (const float*)d_in[8];
    const float* Wself  = (const float*)d_in[9];
    const float* bself  = (const float*)d_in[10];
    const float* WA     = (const float*)d_in[11];
    const float* bA     = (const float*)d_in[12];
    const float* Wstr   = (const float*)d_in[13];
    const float* bstr   = (const float*)d_in[14];
    const float* lng    = (const float*)d_in[15];
    const float* lnb    = (const float*)d_in[16];
    float* out = (float*)d_out;

    const int E = in_sizes[0] / 2;
    const int N = in_sizes[1] / HID;
    const int* esrc = eidx;
    const int* etgt = eidx + E;

    // ---- workspace layout (~88 MB) ----
    char* w = (char*)d_ws;
    const size_t NHb  = (size_t)N * HID * sizeof(unsigned short);     // 12.8 MB
    const size_t NH   = (size_t)N * HID * sizeof(float);              // 25.6 MB
    const size_t Epad = (((size_t)E * sizeof(float)) + 255) & ~255ull;
    const size_t Npad = (((size_t)(N + 1) * sizeof(float)) + 255) & ~255ull;

    unsigned short* WhB   = (unsigned short*)w; w += NHb;
    unsigned short* HpB   = (unsigned short*)w; w += NHb;
    unsigned short* HqB   = (unsigned short*)w; w += NHb;
    unsigned short* HphiB = (unsigned short*)w; w += NHb;
    float* matt  = (float*)w; w += NH;
    float* score = (float*)w; w += Epad; // raw then exp'ed alpha, CSR order
    float* pairv = (float*)w; w += Epad; // raw pair scores, edge order
    int*   eid_t = (int*)  w; w += Epad;
    char*  zero0 = w;                    // 5 contiguous zero-init arrays
    int*      deg_t = (int*)     w; w += Npad;
    int*      cur_t = (int*)     w; w += Npad;
    unsigned* maxs  = (unsigned*)w; w += Npad;
    float*    sums  = (float*)   w; w += Npad;
    float*    num   = (float*)   w; w += Npad;
    int*   base_t   = (int*)     w; w += Npad;  // N+1 entries
    float* sumt_inv = (float*)   w; w += Npad;
    float* psi      = (float*)   w; w += Npad;
    float* rho1m    = (float*)   w; w += Npad;

    const int nblk128 = (N + 127) / 128;
    const int nblkN4  = (N + 3) / 4;
    const int nblkE   = (E + 255) / 256;
    const size_t lds_gemm = (size_t)(HID * PADT + HID * HID) * sizeof(float); // 130 KB

    hipMemsetAsync(zero0, 0, 5 * Npad, stream);  // deg_t, cur_t, maxs, sums, num

    GemmArgs g4;
    g4.W[0] = W_att; g4.W[1] = W_p; g4.W[2] = W_pp; g4.W[3] = phi_w;
    g4.b[0] = nullptr; g4.b[1] = nullptr; g4.b[2] = nullptr; g4.b[3] = phi_b;
    g4.O[0] = WhB; g4.O[1] = HpB; g4.O[2] = HqB; g4.O[3] = HphiB;
    g4.nph = 4;
    k_gemm<<<nblk128, 256, lds_gemm, stream>>>(H, g4, N);

    k_psi<<<nblkN4, 256, 0, stream>>>(H, fdef_w, fdef_b, psi, N);

    k_hist<<<nblkE, 256, 0, stream>>>(etgt, deg_t, E);
    k_scan<<<1, 1024, 0, stream>>>(deg_t, base_t, N);
    k_fill<<<nblkE, 256, 0, stream>>>(etgt, base_t, cur_t, eid_t, E);

    k_score<<<nblkN4, 256, 0, stream>>>(eid_t, base_t, esrc, H, WhB, HpB, HqB,
                                        score, pairv, maxs, sumt_inv, N);
    k_beta<<<nblkE, 256, 0, stream>>>(esrc, etgt, pairv, maxs, psi, sums, num, E);
    k_rho<<<(N + 255) / 256, 256, 0, stream>>>(sums, num, rho1m, N);

    k_matt<<<nblkN4, 256, 0, stream>>>(eid_t, base_t, esrc, score, sumt_inv,
                                       rho1m, HphiB, matt, N);

    k_final<<<nblk128, 256, lds_gemm, stream>>>(H, matt, Wself, bself, WA, bA,
                                                Wstr, bstr, lng, lnb, out, N);
}

// Round 5
// 661.512 us; speedup vs baseline: 4.5891x; 1.0272x over previous
//
#include <hip/hip_runtime.h>
#include <math.h>

#define HID 128
#define NSTR 6              // STRUCT-1
#define GAMMA 1.0f
#define DELTA 0.5f
#define LN_EPS 1e-5f
#define PADT 132            // padded row stride for transposed A tile
#define CHUNK 64            // k-chunk: LDS = 64*132*4 + 64*128*4 = 65 KB -> 2 blocks/CU

typedef __attribute__((ext_vector_type(4))) float f4;

// order-preserving float<->uint encoding for atomicMax on floats
__device__ __forceinline__ unsigned enc_f(float f) {
    unsigned i = __float_as_uint(f);
    return (i & 0x80000000u) ? ~i : (i | 0x80000000u);
}
__device__ __forceinline__ float dec_f(unsigned u) {
    unsigned i = (u & 0x80000000u) ? (u ^ 0x80000000u) : ~u;
    return __uint_as_float(i);
}

// f32 -> bf16 (round-to-nearest-even), bf16x2-in-uint -> two f32
__device__ __forceinline__ unsigned short f2bf(float f) {
    unsigned u = __float_as_uint(f);
    unsigned r = u + 0x7FFFu + ((u >> 16) & 1u);
    return (unsigned short)(r >> 16);
}
__device__ __forceinline__ void bf2f2(unsigned u, float& lo, float& hi) {
    lo = __uint_as_float(u << 16);
    hi = __uint_as_float(u & 0xFFFF0000u);
}
__device__ __forceinline__ void unpack8(const uint4 u, float* f) {
    bf2f2(u.x, f[0], f[1]); bf2f2(u.y, f[2], f[3]);
    bf2f2(u.z, f[4], f[5]); bf2f2(u.w, f[6], f[7]);
}

struct GemmArgs {
    const float*    W[4];
    const float*    b[4];
    unsigned short* O[4];
    int             nph;
};

// ---------------------------------------------------------------------------
// Tall-skinny GEMM: O[ph] = bf16( A @ W[ph] (+ b[ph]) ).  128x128 tile,
// 256 threads, 8x8 micro-tile/thread, k staged in 64-wide chunks so LDS
// fits 2 blocks/CU (2 waves/SIMD for latency hiding).
// ---------------------------------------------------------------------------
__global__ __launch_bounds__(256) void k_gemm(const float* __restrict__ A,
                                              GemmArgs g, int N)
{
    extern __shared__ float sm[];
    float* AsT = sm;                  // [CHUNK][PADT]  (k-major, transposed)
    float* Ws  = sm + CHUNK * PADT;   // [CHUNK][HID]
    const int tid  = threadIdx.x;
    const int row0 = blockIdx.x * HID;
    const int nrows = min(HID, N - row0);
    const int rg = tid >> 4, cg = tid & 15;
    const int r0 = rg * 8, c0 = cg * 4;

    for (int ph = 0; ph < g.nph; ++ph) {
        const float* __restrict__ W = g.W[ph];
        const float* bp = g.b[ph];
        float bj[8];
        #pragma unroll
        for (int j = 0; j < 4; ++j) {
            bj[j]     = bp ? bp[c0 + j]      : 0.f;
            bj[j + 4] = bp ? bp[64 + c0 + j] : 0.f;
        }
        float acc[8][8];
        #pragma unroll
        for (int i = 0; i < 8; ++i)
            #pragma unroll
            for (int j = 0; j < 8; ++j) acc[i][j] = bj[j];

        for (int ch = 0; ch < 2; ++ch) {
            __syncthreads();   // protect prev chunk/phase readers
            for (int i = tid; i < CHUNK * HID; i += 256) {
                const int kl = i & 63, r = i >> 6;
                AsT[kl * PADT + r] =
                    (r < nrows) ? A[(size_t)(row0 + r) * HID + ch * CHUNK + kl] : 0.f;
            }
            for (int i = tid; i < CHUNK * HID; i += 256) {
                const int kl = i >> 7, c = i & 127;
                Ws[kl * HID + c] = W[(size_t)(ch * CHUNK + kl) * HID + c];
            }
            __syncthreads();

            #pragma unroll 4
            for (int k = 0; k < CHUNK; ++k) {
                const f4 a0 = *(const f4*)&AsT[k * PADT + r0];
                const f4 a1 = *(const f4*)&AsT[k * PADT + r0 + 4];
                const f4 w0 = *(const f4*)&Ws[k * HID + c0];
                const f4 w1 = *(const f4*)&Ws[k * HID + 64 + c0];
                #pragma unroll
                for (int i = 0; i < 4; ++i)
                    #pragma unroll
                    for (int j = 0; j < 4; ++j) {
                        acc[i][j]         = fmaf(a0[i], w0[j], acc[i][j]);
                        acc[i][j + 4]     = fmaf(a0[i], w1[j], acc[i][j + 4]);
                        acc[i + 4][j]     = fmaf(a1[i], w0[j], acc[i + 4][j]);
                        acc[i + 4][j + 4] = fmaf(a1[i], w1[j], acc[i + 4][j + 4]);
                    }
            }
        }

        unsigned short* __restrict__ O = g.O[ph];
        #pragma unroll
        for (int i = 0; i < 8; ++i) {
            const int r = r0 + i;
            if (r < nrows) {
                ushort4 v0, v1;
                v0.x = f2bf(acc[i][0]); v0.y = f2bf(acc[i][1]);
                v0.z = f2bf(acc[i][2]); v0.w = f2bf(acc[i][3]);
                v1.x = f2bf(acc[i][4]); v1.y = f2bf(acc[i][5]);
                v1.z = f2bf(acc[i][6]); v1.w = f2bf(acc[i][7]);
                *(ushort4*)&O[(size_t)(row0 + r) * HID + c0]      = v0;
                *(ushort4*)&O[(size_t)(row0 + r) * HID + 64 + c0] = v1;
            }
        }
    }
}

// ---------------------------------------------------------------------------
// Fused final: out = LN(relu(H@Wself + Matt@WA + s@Wstr + biases) + H)
// Same chunked-k structure; residual re-read from global (L2-hot).
// ---------------------------------------------------------------------------
__global__ __launch_bounds__(256) void k_final(
    const float* __restrict__ H, const float* __restrict__ Matt,
    const float* __restrict__ Wself, const float* __restrict__ bself,
    const float* __restrict__ WA, const float* __restrict__ bA,
    const float* __restrict__ Wstr, const float* __restrict__ bstr,
    const float* __restrict__ lng, const float* __restrict__ lnb,
    float* __restrict__ out, int N)
{
    extern __shared__ float sm[];
    float* AsT = sm;                  // [CHUNK][PADT]
    float* Ws  = sm + CHUNK * PADT;   // [CHUNK][HID]
    const int tid  = threadIdx.x;
    const int row0 = blockIdx.x * HID;
    const int nrows = min(HID, N - row0);
    const int rg = tid >> 4, cg = tid & 15;
    const int r0 = rg * 8, c0 = cg * 4;

    float gg[8], bb[8], acc[8][8];
    #pragma unroll
    for (int j = 0; j < 4; ++j) {
        const int ca = c0 + j, cb = 64 + c0 + j;
        gg[j] = lng[ca];  gg[j + 4] = lng[cb];
        bb[j] = lnb[ca];  bb[j + 4] = lnb[cb];
        const float ba = bself[ca] + bA[ca] + bstr[ca];
        const float bc = bself[cb] + bA[cb] + bstr[cb];
        #pragma unroll
        for (int i = 0; i < 8; ++i) { acc[i][j] = ba; acc[i][j + 4] = bc; }
    }

    // ---- two phases: 0 = Matt @ WA, 1 = H @ Wself (+ Wstr on chunk 0) ----
    for (int ph = 0; ph < 2; ++ph) {
        const float* __restrict__ Am = ph ? H : Matt;
        const float* __restrict__ W  = ph ? Wself : WA;
        for (int ch = 0; ch < 2; ++ch) {
            __syncthreads();
            for (int i = tid; i < CHUNK * HID; i += 256) {
                const int kl = i & 63, r = i >> 6;
                AsT[kl * PADT + r] =
                    (r < nrows) ? Am[(size_t)(row0 + r) * HID + ch * CHUNK + kl] : 0.f;
            }
            for (int i = tid; i < CHUNK * HID; i += 256) {
                const int kl = i >> 7, c = i & 127;
                Ws[kl * HID + c] = W[(size_t)(ch * CHUNK + kl) * HID + c];
            }
            __syncthreads();

            #pragma unroll 4
            for (int k = 0; k < CHUNK; ++k) {
                const f4 a0 = *(const f4*)&AsT[k * PADT + r0];
                const f4 a1 = *(const f4*)&AsT[k * PADT + r0 + 4];
                const f4 w0 = *(const f4*)&Ws[k * HID + c0];
                const f4 w1 = *(const f4*)&Ws[k * HID + 64 + c0];
                #pragma unroll
                for (int i = 0; i < 4; ++i)
                    #pragma unroll
                    for (int j = 0; j < 4; ++j) {
                        acc[i][j]         = fmaf(a0[i], w0[j], acc[i][j]);
                        acc[i][j + 4]     = fmaf(a0[i], w1[j], acc[i][j + 4]);
                        acc[i + 4][j]     = fmaf(a1[i], w0[j], acc[i + 4][j]);
                        acc[i + 4][j + 4] = fmaf(a1[i], w1[j], acc[i + 4][j + 4]);
                    }
            }

            if (ph == 1 && ch == 0) {
                // s_feat (= H[:, :6]) @ Wstr — H cols 0..5 live in this chunk
                #pragma unroll
                for (int k = 0; k < NSTR; ++k) {
                    const f4 a0 = *(const f4*)&AsT[k * PADT + r0];
                    const f4 a1 = *(const f4*)&AsT[k * PADT + r0 + 4];
                    #pragma unroll
                    for (int j = 0; j < 4; ++j) {
                        const float wa = Wstr[k * HID + c0 + j];
                        const float wb = Wstr[k * HID + 64 + c0 + j];
                        #pragma unroll
                        for (int i = 0; i < 4; ++i) {
                            acc[i][j]         = fmaf(a0[i], wa, acc[i][j]);
                            acc[i][j + 4]     = fmaf(a0[i], wb, acc[i][j + 4]);
                            acc[i + 4][j]     = fmaf(a1[i], wa, acc[i + 4][j]);
                            acc[i + 4][j + 4] = fmaf(a1[i], wb, acc[i + 4][j + 4]);
                        }
                    }
                }
            }
        }
    }

    // ---- relu + residual (global re-read, L2-hot) + LayerNorm ----
    #pragma unroll
    for (int i = 0; i < 8; ++i) {
        const int r = r0 + i;
        float v[8];
        if (r < nrows) {
            const size_t n = (size_t)(row0 + r);
            const f4 h0 = *(const f4*)&H[n * HID + c0];
            const f4 h1 = *(const f4*)&H[n * HID + 64 + c0];
            #pragma unroll
            for (int j = 0; j < 4; ++j) {
                v[j]     = fmaxf(acc[i][j],     0.f) + h0[j];
                v[j + 4] = fmaxf(acc[i][j + 4], 0.f) + h1[j];
            }
        } else {
            #pragma unroll
            for (int j = 0; j < 8; ++j) v[j] = 0.f;
        }
        float s1 = 0.f, s2 = 0.f;
        #pragma unroll
        for (int j = 0; j < 8; ++j) { s1 += v[j]; s2 += v[j] * v[j]; }
        #pragma unroll
        for (int m = 1; m < 16; m <<= 1) {
            s1 += __shfl_xor(s1, m);
            s2 += __shfl_xor(s2, m);
        }
        const float mean = s1 * (1.f / HID);
        const float var  = s2 * (1.f / HID) - mean * mean;
        const float rs   = rsqrtf(var + LN_EPS);
        if (r < nrows) {
            f4 o0, o1;
            #pragma unroll
            for (int j = 0; j < 4; ++j) {
                o0[j] = (v[j]     - mean) * rs * gg[j]     + bb[j];
                o1[j] = (v[j + 4] - mean) * rs * gg[j + 4] + bb[j + 4];
            }
            *(f4*)&out[(size_t)(row0 + r) * HID + c0]      = o0;
            *(f4*)&out[(size_t)(row0 + r) * HID + 64 + c0] = o1;
        }
    }
}

// psi[n] = dot(H[n], f_def_w) + f_def_b   (wave per node)
__global__ __launch_bounds__(256) void k_psi(
    const float* __restrict__ H, const float* __restrict__ fw, const float* __restrict__ fb,
    float* __restrict__ psi, int N)
{
    const int wid = threadIdx.x >> 6, lane = threadIdx.x & 63;
    const int n = blockIdx.x * 4 + wid;
    if (n >= N) return;
    const size_t o = (size_t)n * HID;
    float a = H[o + lane] * fw[lane] + H[o + 64 + lane] * fw[64 + lane];
    #pragma unroll
    for (int off = 32; off; off >>= 1) a += __shfl_down(a, off);
    if (lane == 0) psi[n] = a + fb[0];
}

// ---------------------------------------------------------------------------
// CSR-by-target build: histogram, single-block scan, fill
// ---------------------------------------------------------------------------
__global__ __launch_bounds__(256) void k_hist(
    const int* __restrict__ etgt, int* __restrict__ deg, int E)
{
    const int e = blockIdx.x * 256 + threadIdx.x;
    if (e < E) atomicAdd(&deg[etgt[e]], 1);
}

__global__ __launch_bounds__(1024) void k_scan(
    const int* __restrict__ deg, int* __restrict__ base, int N)
{
    __shared__ int warp_sums[16];
    __shared__ int carry_s;
    const int tid = threadIdx.x, lane = tid & 63, wid = tid >> 6;
    if (tid == 0) carry_s = 0;
    __syncthreads();
    for (int i0 = 0; i0 < N; i0 += 1024) {
        const int i = i0 + tid;
        const int v = (i < N) ? deg[i] : 0;
        int x = v;
        #pragma unroll
        for (int d = 1; d < 64; d <<= 1) {
            const int y = __shfl_up(x, d);
            if (lane >= d) x += y;
        }
        if (lane == 63) warp_sums[wid] = x;
        __syncthreads();
        if (wid == 0) {
            int ws = (lane < 16) ? warp_sums[lane] : 0;
            #pragma unroll
            for (int d = 1; d < 16; d <<= 1) {
                const int y = __shfl_up(ws, d);
                if (lane >= d) ws += y;
            }
            if (lane < 16) warp_sums[lane] = ws;
        }
        __syncthreads();
        const int carry = carry_s;
        if (i < N) base[i] = carry + (wid ? warp_sums[wid - 1] : 0) + x - v;
        __syncthreads();
        if (tid == 1023) carry_s = carry + warp_sums[15];
        __syncthreads();
    }
    if (tid == 0) base[N] = carry_s;
}

__global__ __launch_bounds__(256) void k_fill(
    const int* __restrict__ etgt, const int* __restrict__ base,
    int* __restrict__ cur, int* __restrict__ eid_t, int E)
{
    const int e = blockIdx.x * 256 + threadIdx.x;
    if (e < E) {
        const int t = etgt[e];
        const int p = atomicAdd(&cur[t], 1);
        eid_t[base[t] + p] = e;
    }
}

// ---------------------------------------------------------------------------
// k_score: wave per TARGET node, 16-lane edge groups (4 edges in flight).
// Gathers are bf16 rows (256 B). Alpha softmax in-wave via score[] re-pass.
// ---------------------------------------------------------------------------
__global__ __launch_bounds__(256) void k_score(
    const int* __restrict__ eid_t, const int* __restrict__ base_t,
    const int* __restrict__ esrc,
    const float* __restrict__ H,
    const unsigned short* __restrict__ WhB,
    const unsigned short* __restrict__ HpB,
    const unsigned short* __restrict__ HqB,
    float* __restrict__ score, float* __restrict__ pairv,
    unsigned* __restrict__ maxs, float* __restrict__ sumt_inv, int N)
{
    const int lane = threadIdx.x & 63, wv = threadIdx.x >> 6;
    const int t = blockIdx.x * 4 + wv;
    if (t >= N) return;
    const int b0 = base_t[t], deg = base_t[t + 1] - b0;
    if (deg == 0) { if (lane == 0) sumt_inv[t] = 0.f; return; }
    const int sub = lane & 15, grp = lane >> 4;
    const size_t to = (size_t)t * HID;

    float ht[8], hq[8];
    {
        const f4 h0 = *(const f4*)&H[to + sub * 8];
        const f4 h1 = *(const f4*)&H[to + sub * 8 + 4];
        ht[0] = h0[0]; ht[1] = h0[1]; ht[2] = h0[2]; ht[3] = h0[3];
        ht[4] = h1[0]; ht[5] = h1[1]; ht[6] = h1[2]; ht[7] = h1[3];
        unpack8(*(const uint4*)&HqB[to + sub * 8], hq);
    }

    for (int j0 = 0; j0 < deg; j0 += 4) {
        const int jj = j0 + grp;
        const bool val = jj < deg;
        int eid = 0, src = 0;
        if (val) { eid = eid_t[b0 + jj]; src = esrc[eid]; }
        const size_t so = (size_t)src * HID;
        float wh[8], hp[8];
        unpack8(*(const uint4*)&WhB[so + sub * 8], wh);
        unpack8(*(const uint4*)&HpB[so + sub * 8], hp);
        float ps = 0.f, pp = 0.f;
        #pragma unroll
        for (int d = 0; d < 8; ++d) {
            ps = fmaf(ht[d], wh[d], ps);
            pp = fmaf(hp[d], hq[d], pp);
        }
        if (sub == 0) {
            const f4 s0 = *(const f4*)&H[so];
            const float2 s1 = *(const float2*)&H[so + 4];
            ps += s0[0]*ht[0] + s0[1]*ht[1] + s0[2]*ht[2] + s0[3]*ht[3]
                + s1.x*ht[4] + s1.y*ht[5];
        }
        #pragma unroll
        for (int mk = 1; mk < 16; mk <<= 1) {
            ps += __shfl_xor(ps, mk);
            pp += __shfl_xor(pp, mk);
        }
        if (sub == 0 && val) {
            score[b0 + jj] = ps;
            pairv[eid] = pp;
            atomicMax(&maxs[src], enc_f(pp));
        }
    }

    float m = -1e30f;
    for (int i = lane; i < deg; i += 64) m = fmaxf(m, score[b0 + i]);
    #pragma unroll
    for (int mk = 1; mk < 64; mk <<= 1) m = fmaxf(m, __shfl_xor(m, mk));
    float psum = 0.f;
    for (int i = lane; i < deg; i += 64) {
        const float e = expf(score[b0 + i] - m);
        score[b0 + i] = e;
        psum += e;
    }
    #pragma unroll
    for (int mk = 1; mk < 64; mk <<= 1) psum += __shfl_xor(psum, mk);
    if (lane == 0) sumt_inv[t] = 1.f / psum;
}

// per edge: e = exp(pair - max_src); sums[s] += e; num[s] += e * exp(-psi[t])
__global__ __launch_bounds__(256) void k_beta(
    const int* __restrict__ esrc, const int* __restrict__ etgt,
    const float* __restrict__ pairv, const unsigned* __restrict__ maxs,
    const float* __restrict__ psi,
    float* __restrict__ sums, float* __restrict__ num, int E)
{
    const int e = blockIdx.x * 256 + threadIdx.x;
    if (e >= E) return;
    const int s = esrc[e], t = etgt[e];
    const float ep = expf(pairv[e] - dec_f(maxs[s]));
    atomicAdd(&sums[s], ep);
    atomicAdd(&num[s], ep * expf(-psi[t]));
}

// per node: sum_term = num/sums; rho1m = 1 - sigmoid(GAMMA*(-log(st+1e-8)-DELTA))
__global__ __launch_bounds__(256) void k_rho(
    const float* __restrict__ sums, const float* __restrict__ num,
    float* __restrict__ rho1m, int N)
{
    const int n = blockIdx.x * 256 + threadIdx.x;
    if (n >= N) return;
    const float sm = sums[n];
    const float st = (sm > 0.f) ? num[n] / sm : 0.f;
    const float d  = -logf(st + 1e-8f);
    rho1m[n] = 1.f - 1.f / (1.f + expf(-(GAMMA * (d - DELTA))));
}

// ---------------------------------------------------------------------------
// k_matt: wave per TARGET, 16-lane edge groups; Hphi gathered as bf16.
// ---------------------------------------------------------------------------
__global__ __launch_bounds__(256) void k_matt(
    const int* __restrict__ eid_t, const int* __restrict__ base_t,
    const int* __restrict__ esrc,
    const float* __restrict__ score, const float* __restrict__ sumt_inv,
    const float* __restrict__ rho1m,
    const unsigned short* __restrict__ HphiB,
    float* __restrict__ matt, int N)
{
    const int lane = threadIdx.x & 63, wv = threadIdx.x >> 6;
    const int t = blockIdx.x * 4 + wv;
    if (t >= N) return;
    const int b0 = base_t[t], deg = base_t[t + 1] - b0;
    const int sub = lane & 15, grp = lane >> 4;
    const size_t to = (size_t)t * HID;

    float acc[8];
    #pragma unroll
    for (int d = 0; d < 8; ++d) acc[d] = 0.f;
    const float inv = (deg > 0) ? sumt_inv[t] : 0.f;

    for (int j0 = 0; j0 < deg; j0 += 4) {
        const int jj = j0 + grp;
        const bool val = jj < deg;
        float c = 0.f;
        size_t so = 0;
        if (val) {
            const int eid = eid_t[b0 + jj];
            const int src = esrc[eid];
            c = score[b0 + jj] * inv * rho1m[src];
            so = (size_t)src * HID;
        }
        float hf[8];
        unpack8(*(const uint4*)&HphiB[so + sub * 8], hf);
        #pragma unroll
        for (int d = 0; d < 8; ++d) acc[d] = fmaf(c, hf[d], acc[d]);
    }
    #pragma unroll
    for (int d = 0; d < 8; ++d) {
        acc[d] += __shfl_xor(acc[d], 16);
        acc[d] += __shfl_xor(acc[d], 32);
    }
    if (grp == 0) {
        f4 o0, o1;
        #pragma unroll
        for (int d = 0; d < 4; ++d) { o0[d] = acc[d]; o1[d] = acc[d + 4]; }
        *(f4*)&matt[to + sub * 8]     = o0;
        *(f4*)&matt[to + sub * 8 + 4] = o1;
    }
}

extern "C" void kernel_launch(void* const* d_in, const int* in_sizes, int n_in,
                              void* d_out, int out_size, void* d_ws, size_t ws_size,
                              hipStream_t stream)
{
    const int*   eidx   = (const int*)  d_in[0];
    const float* H      = (const float*)d_in[1];
    const float* W_att  = (const float*)d_in[2];
    const float* phi_w  = (const float*)d_in[3];
    const float* phi_b  = (const float*)d_in[4];
    const float* W_p    = (const float*)d_in[5];
    const float* W_pp   = (const float*)d_in[6];
    const float* fdef_w = (const float*)d_in[7];
    const float* fdef_b = (const float*)d_in[8];
    const float* Wself  = (const float*)d_in[9];
    const float* bself  = (const float*)d_in[10];
    const float* WA     = (const float*)d_in[11];
    const float* bA     = (const float*)d_in[12];
    const float* Wstr   = (const float*)d_in[13];
    const float* bstr   = (const float*)d_in[14];
    const float* lng    = (const float*)d_in[15];
    const float* lnb    = (const float*)d_in[16];
    float* out = (float*)d_out;

    const int E = in_sizes[0] / 2;
    const int N = in_sizes[1] / HID;
    const int* esrc = eidx;
    const int* etgt = eidx + E;

    // ---- workspace layout (~88 MB) ----
    char* w = (char*)d_ws;
    const size_t NHb  = (size_t)N * HID * sizeof(unsigned short);     // 12.8 MB
    const size_t NH   = (size_t)N * HID * sizeof(float);              // 25.6 MB
    const size_t Epad = (((size_t)E * sizeof(float)) + 255) & ~255ull;
    const size_t Npad = (((size_t)(N + 1) * sizeof(float)) + 255) & ~255ull;

    unsigned short* WhB   = (unsigned short*)w; w += NHb;
    unsigned short* HpB   = (unsigned short*)w; w += NHb;
    unsigned short* HqB   = (unsigned short*)w; w += NHb;
    unsigned short* HphiB = (unsigned short*)w; w += NHb;
    float* matt  = (float*)w; w += NH;
    float* score = (float*)w; w += Epad; // raw then exp'ed alpha, CSR order
    float* pairv = (float*)w; w += Epad; // raw pair scores, edge order
    int*   eid_t = (int*)  w; w += Epad;
    char*  zero0 = w;                    // 5 contiguous zero-init arrays
    int*      deg_t = (int*)     w; w += Npad;
    int*      cur_t = (int*)     w; w += Npad;
    unsigned* maxs  = (unsigned*)w; w += Npad;
    float*    sums  = (float*)   w; w += Npad;
    float*    num   = (float*)   w; w += Npad;
    int*   base_t   = (int*)     w; w += Npad;  // N+1 entries
    float* sumt_inv = (float*)   w; w += Npad;
    float* psi      = (float*)   w; w += Npad;
    float* rho1m    = (float*)   w; w += Npad;

    const int nblk128 = (N + 127) / 128;
    const int nblkN4  = (N + 3) / 4;
    const int nblkE   = (E + 255) / 256;
    const size_t lds_gemm = (size_t)(CHUNK * PADT + CHUNK * HID) * sizeof(float); // 65 KB

    hipMemsetAsync(zero0, 0, 5 * Npad, stream);  // deg_t, cur_t, maxs, sums, num

    GemmArgs g4;
    g4.W[0] = W_att; g4.W[1] = W_p; g4.W[2] = W_pp; g4.W[3] = phi_w;
    g4.b[0] = nullptr; g4.b[1] = nullptr; g4.b[2] = nullptr; g4.b[3] = phi_b;
    g4.O[0] = WhB; g4.O[1] = HpB; g4.O[2] = HqB; g4.O[3] = HphiB;
    g4.nph = 4;
    k_gemm<<<nblk128, 256, lds_gemm, stream>>>(H, g4, N);

    k_psi<<<nblkN4, 256, 0, stream>>>(H, fdef_w, fdef_b, psi, N);

    k_hist<<<nblkE, 256, 0, stream>>>(etgt, deg_t, E);
    k_scan<<<1, 1024, 0, stream>>>(deg_t, base_t, N);
    k_fill<<<nblkE, 256, 0, stream>>>(etgt, base_t, cur_t, eid_t, E);

    k_score<<<nblkN4, 256, 0, stream>>>(eid_t, base_t, esrc, H, WhB, HpB, HqB,
                                        score, pairv, maxs, sumt_inv, N);
    k_beta<<<nblkE, 256, 0, stream>>>(esrc, etgt, pairv, maxs, psi, sums, num, E);
    k_rho<<<(N + 255) / 256, 256, 0, stream>>>(sums, num, rho1m, N);

    k_matt<<<nblkN4, 256, 0, stream>>>(eid_t, base_t, esrc, score, sumt_inv,
                                       rho1m, HphiB, matt, N);

    k_final<<<nblk128, 256, lds_gemm, stream>>>(H, matt, Wself, bself, WA, bA,
                                                Wstr, bstr, lng, lnb, out, N);
}

// Round 6
// 620.042 us; speedup vs baseline: 4.8960x; 1.0669x over previous
//
#include <hip/hip_runtime.h>
#include <math.h>

#define HID 128
#define NSTR 6              // STRUCT-1
#define GAMMA 1.0f
#define DELTA 0.5f
#define LN_EPS 1e-5f
#define PADT 132            // padded row stride for transposed A tile
#define CHUNK 64            // k-chunk: LDS = 64*132*4 + 64*128*4 = 65 KB -> 2 blocks/CU

typedef __attribute__((ext_vector_type(4))) float f4;

// order-preserving float<->uint encoding for atomicMax on floats
__device__ __forceinline__ unsigned enc_f(float f) {
    unsigned i = __float_as_uint(f);
    return (i & 0x80000000u) ? ~i : (i | 0x80000000u);
}
__device__ __forceinline__ float dec_f(unsigned u) {
    unsigned i = (u & 0x80000000u) ? (u ^ 0x80000000u) : ~u;
    return __uint_as_float(i);
}

// f32 -> bf16 (round-to-nearest-even), bf16x2-in-uint -> two f32
__device__ __forceinline__ unsigned short f2bf(float f) {
    unsigned u = __float_as_uint(f);
    unsigned r = u + 0x7FFFu + ((u >> 16) & 1u);
    return (unsigned short)(r >> 16);
}
__device__ __forceinline__ void bf2f2(unsigned u, float& lo, float& hi) {
    lo = __uint_as_float(u << 16);
    hi = __uint_as_float(u & 0xFFFF0000u);
}
__device__ __forceinline__ void unpack8(const uint4 u, float* f) {
    bf2f2(u.x, f[0], f[1]); bf2f2(u.y, f[2], f[3]);
    bf2f2(u.z, f[4], f[5]); bf2f2(u.w, f[6], f[7]);
}

struct GemmArgs {
    const float*    W[4];
    const float*    b[4];
    unsigned short* O[4];
};

// ---------------------------------------------------------------------------
// Tall-skinny GEMM: O[ph] = bf16( A @ W[ph] (+ b[ph]) ).  128x128 tile,
// 256 threads, 8x8 micro-tile/thread, k staged in 64-wide chunks (2 blk/CU).
// blockIdx.y = phase -> 4x more blocks, cross-phase overlap, better balance.
// ---------------------------------------------------------------------------
__global__ __launch_bounds__(256) void k_gemm(const float* __restrict__ A,
                                              GemmArgs g, int N)
{
    extern __shared__ float sm[];
    float* AsT = sm;                  // [CHUNK][PADT]  (k-major, transposed)
    float* Ws  = sm + CHUNK * PADT;   // [CHUNK][HID]
    const int tid  = threadIdx.x;
    const int row0 = blockIdx.x * HID;
    const int nrows = min(HID, N - row0);
    const int rg = tid >> 4, cg = tid & 15;
    const int r0 = rg * 8, c0 = cg * 4;
    const int ph = blockIdx.y;

    const float* __restrict__ W = g.W[ph];
    const float* bp = g.b[ph];
    float bj[8];
    #pragma unroll
    for (int j = 0; j < 4; ++j) {
        bj[j]     = bp ? bp[c0 + j]      : 0.f;
        bj[j + 4] = bp ? bp[64 + c0 + j] : 0.f;
    }
    float acc[8][8];
    #pragma unroll
    for (int i = 0; i < 8; ++i)
        #pragma unroll
        for (int j = 0; j < 8; ++j) acc[i][j] = bj[j];

    for (int ch = 0; ch < 2; ++ch) {
        __syncthreads();   // protect prev chunk readers
        for (int i = tid; i < CHUNK * HID; i += 256) {
            const int kl = i & 63, r = i >> 6;
            AsT[kl * PADT + r] =
                (r < nrows) ? A[(size_t)(row0 + r) * HID + ch * CHUNK + kl] : 0.f;
        }
        for (int i = tid; i < CHUNK * HID; i += 256) {
            const int kl = i >> 7, c = i & 127;
            Ws[kl * HID + c] = W[(size_t)(ch * CHUNK + kl) * HID + c];
        }
        __syncthreads();

        #pragma unroll 4
        for (int k = 0; k < CHUNK; ++k) {
            const f4 a0 = *(const f4*)&AsT[k * PADT + r0];
            const f4 a1 = *(const f4*)&AsT[k * PADT + r0 + 4];
            const f4 w0 = *(const f4*)&Ws[k * HID + c0];
            const f4 w1 = *(const f4*)&Ws[k * HID + 64 + c0];
            #pragma unroll
            for (int i = 0; i < 4; ++i)
                #pragma unroll
                for (int j = 0; j < 4; ++j) {
                    acc[i][j]         = fmaf(a0[i], w0[j], acc[i][j]);
                    acc[i][j + 4]     = fmaf(a0[i], w1[j], acc[i][j + 4]);
                    acc[i + 4][j]     = fmaf(a1[i], w0[j], acc[i + 4][j]);
                    acc[i + 4][j + 4] = fmaf(a1[i], w1[j], acc[i + 4][j + 4]);
                }
        }
    }

    unsigned short* __restrict__ O = g.O[ph];
    #pragma unroll
    for (int i = 0; i < 8; ++i) {
        const int r = r0 + i;
        if (r < nrows) {
            ushort4 v0, v1;
            v0.x = f2bf(acc[i][0]); v0.y = f2bf(acc[i][1]);
            v0.z = f2bf(acc[i][2]); v0.w = f2bf(acc[i][3]);
            v1.x = f2bf(acc[i][4]); v1.y = f2bf(acc[i][5]);
            v1.z = f2bf(acc[i][6]); v1.w = f2bf(acc[i][7]);
            *(ushort4*)&O[(size_t)(row0 + r) * HID + c0]      = v0;
            *(ushort4*)&O[(size_t)(row0 + r) * HID + 64 + c0] = v1;
        }
    }
}

// ---------------------------------------------------------------------------
// Fused final: out = LN(relu(H@Wself + Matt@WA + s@Wstr + biases) + H)
// Chunked-k structure; residual re-read from global (L2-hot).
// ---------------------------------------------------------------------------
__global__ __launch_bounds__(256) void k_final(
    const float* __restrict__ H, const float* __restrict__ Matt,
    const float* __restrict__ Wself, const float* __restrict__ bself,
    const float* __restrict__ WA, const float* __restrict__ bA,
    const float* __restrict__ Wstr, const float* __restrict__ bstr,
    const float* __restrict__ lng, const float* __restrict__ lnb,
    float* __restrict__ out, int N)
{
    extern __shared__ float sm[];
    float* AsT = sm;                  // [CHUNK][PADT]
    float* Ws  = sm + CHUNK * PADT;   // [CHUNK][HID]
    const int tid  = threadIdx.x;
    const int row0 = blockIdx.x * HID;
    const int nrows = min(HID, N - row0);
    const int rg = tid >> 4, cg = tid & 15;
    const int r0 = rg * 8, c0 = cg * 4;

    float gg[8], bb[8], acc[8][8];
    #pragma unroll
    for (int j = 0; j < 4; ++j) {
        const int ca = c0 + j, cb = 64 + c0 + j;
        gg[j] = lng[ca];  gg[j + 4] = lng[cb];
        bb[j] = lnb[ca];  bb[j + 4] = lnb[cb];
        const float ba = bself[ca] + bA[ca] + bstr[ca];
        const float bc = bself[cb] + bA[cb] + bstr[cb];
        #pragma unroll
        for (int i = 0; i < 8; ++i) { acc[i][j] = ba; acc[i][j + 4] = bc; }
    }

    // ---- two phases: 0 = Matt @ WA, 1 = H @ Wself (+ Wstr on chunk 0) ----
    for (int ph = 0; ph < 2; ++ph) {
        const float* __restrict__ Am = ph ? H : Matt;
        const float* __restrict__ W  = ph ? Wself : WA;
        for (int ch = 0; ch < 2; ++ch) {
            __syncthreads();
            for (int i = tid; i < CHUNK * HID; i += 256) {
                const int kl = i & 63, r = i >> 6;
                AsT[kl * PADT + r] =
                    (r < nrows) ? Am[(size_t)(row0 + r) * HID + ch * CHUNK + kl] : 0.f;
            }
            for (int i = tid; i < CHUNK * HID; i += 256) {
                const int kl = i >> 7, c = i & 127;
                Ws[kl * HID + c] = W[(size_t)(ch * CHUNK + kl) * HID + c];
            }
            __syncthreads();

            #pragma unroll 4
            for (int k = 0; k < CHUNK; ++k) {
                const f4 a0 = *(const f4*)&AsT[k * PADT + r0];
                const f4 a1 = *(const f4*)&AsT[k * PADT + r0 + 4];
                const f4 w0 = *(const f4*)&Ws[k * HID + c0];
                const f4 w1 = *(const f4*)&Ws[k * HID + 64 + c0];
                #pragma unroll
                for (int i = 0; i < 4; ++i)
                    #pragma unroll
                    for (int j = 0; j < 4; ++j) {
                        acc[i][j]         = fmaf(a0[i], w0[j], acc[i][j]);
                        acc[i][j + 4]     = fmaf(a0[i], w1[j], acc[i][j + 4]);
                        acc[i + 4][j]     = fmaf(a1[i], w0[j], acc[i + 4][j]);
                        acc[i + 4][j + 4] = fmaf(a1[i], w1[j], acc[i + 4][j + 4]);
                    }
            }

            if (ph == 1 && ch == 0) {
                // s_feat (= H[:, :6]) @ Wstr — H cols 0..5 live in this chunk
                #pragma unroll
                for (int k = 0; k < NSTR; ++k) {
                    const f4 a0 = *(const f4*)&AsT[k * PADT + r0];
                    const f4 a1 = *(const f4*)&AsT[k * PADT + r0 + 4];
                    #pragma unroll
                    for (int j = 0; j < 4; ++j) {
                        const float wa = Wstr[k * HID + c0 + j];
                        const float wb = Wstr[k * HID + 64 + c0 + j];
                        #pragma unroll
                        for (int i = 0; i < 4; ++i) {
                            acc[i][j]         = fmaf(a0[i], wa, acc[i][j]);
                            acc[i][j + 4]     = fmaf(a0[i], wb, acc[i][j + 4]);
                            acc[i + 4][j]     = fmaf(a1[i], wa, acc[i + 4][j]);
                            acc[i + 4][j + 4] = fmaf(a1[i], wb, acc[i + 4][j + 4]);
                        }
                    }
                }
            }
        }
    }

    // ---- relu + residual (global re-read, L2-hot) + LayerNorm ----
    #pragma unroll
    for (int i = 0; i < 8; ++i) {
        const int r = r0 + i;
        float v[8];
        if (r < nrows) {
            const size_t n = (size_t)(row0 + r);
            const f4 h0 = *(const f4*)&H[n * HID + c0];
            const f4 h1 = *(const f4*)&H[n * HID + 64 + c0];
            #pragma unroll
            for (int j = 0; j < 4; ++j) {
                v[j]     = fmaxf(acc[i][j],     0.f) + h0[j];
                v[j + 4] = fmaxf(acc[i][j + 4], 0.f) + h1[j];
            }
        } else {
            #pragma unroll
            for (int j = 0; j < 8; ++j) v[j] = 0.f;
        }
        float s1 = 0.f, s2 = 0.f;
        #pragma unroll
        for (int j = 0; j < 8; ++j) { s1 += v[j]; s2 += v[j] * v[j]; }
        #pragma unroll
        for (int m = 1; m < 16; m <<= 1) {
            s1 += __shfl_xor(s1, m);
            s2 += __shfl_xor(s2, m);
        }
        const float mean = s1 * (1.f / HID);
        const float var  = s2 * (1.f / HID) - mean * mean;
        const float rs   = rsqrtf(var + LN_EPS);
        if (r < nrows) {
            f4 o0, o1;
            #pragma unroll
            for (int j = 0; j < 4; ++j) {
                o0[j] = (v[j]     - mean) * rs * gg[j]     + bb[j];
                o1[j] = (v[j + 4] - mean) * rs * gg[j + 4] + bb[j + 4];
            }
            *(f4*)&out[(size_t)(row0 + r) * HID + c0]      = o0;
            *(f4*)&out[(size_t)(row0 + r) * HID + 64 + c0] = o1;
        }
    }
}

// psi[n] = dot(H[n], f_def_w) + f_def_b   (wave per node)
__global__ __launch_bounds__(256) void k_psi(
    const float* __restrict__ H, const float* __restrict__ fw, const float* __restrict__ fb,
    float* __restrict__ psi, int N)
{
    const int wid = threadIdx.x >> 6, lane = threadIdx.x & 63;
    const int n = blockIdx.x * 4 + wid;
    if (n >= N) return;
    const size_t o = (size_t)n * HID;
    float a = H[o + lane] * fw[lane] + H[o + 64 + lane] * fw[64 + lane];
    #pragma unroll
    for (int off = 32; off; off >>= 1) a += __shfl_down(a, off);
    if (lane == 0) psi[n] = a + fb[0];
}

// ---------------------------------------------------------------------------
// CSR-by-target build: histogram, single-block scan, fill
// ---------------------------------------------------------------------------
__global__ __launch_bounds__(256) void k_hist(
    const int* __restrict__ etgt, int* __restrict__ deg, int E)
{
    const int e = blockIdx.x * 256 + threadIdx.x;
    if (e < E) atomicAdd(&deg[etgt[e]], 1);
}

__global__ __launch_bounds__(1024) void k_scan(
    const int* __restrict__ deg, int* __restrict__ base, int N)
{
    __shared__ int warp_sums[16];
    __shared__ int carry_s;
    const int tid = threadIdx.x, lane = tid & 63, wid = tid >> 6;
    if (tid == 0) carry_s = 0;
    __syncthreads();
    for (int i0 = 0; i0 < N; i0 += 1024) {
        const int i = i0 + tid;
        const int v = (i < N) ? deg[i] : 0;
        int x = v;
        #pragma unroll
        for (int d = 1; d < 64; d <<= 1) {
            const int y = __shfl_up(x, d);
            if (lane >= d) x += y;
        }
        if (lane == 63) warp_sums[wid] = x;
        __syncthreads();
        if (wid == 0) {
            int ws = (lane < 16) ? warp_sums[lane] : 0;
            #pragma unroll
            for (int d = 1; d < 16; d <<= 1) {
                const int y = __shfl_up(ws, d);
                if (lane >= d) ws += y;
            }
            if (lane < 16) warp_sums[lane] = ws;
        }
        __syncthreads();
        const int carry = carry_s;
        if (i < N) base[i] = carry + (wid ? warp_sums[wid - 1] : 0) + x - v;
        __syncthreads();
        if (tid == 1023) carry_s = carry + warp_sums[15];
        __syncthreads();
    }
    if (tid == 0) base[N] = carry_s;
}

__global__ __launch_bounds__(256) void k_fill(
    const int* __restrict__ etgt, const int* __restrict__ base,
    int* __restrict__ cur, int* __restrict__ eid_t, int E)
{
    const int e = blockIdx.x * 256 + threadIdx.x;
    if (e < E) {
        const int t = etgt[e];
        const int p = atomicAdd(&cur[t], 1);
        eid_t[base[t] + p] = e;
    }
}

// ---------------------------------------------------------------------------
// k_score: wave per TARGET node, 16-lane edge groups (4 edges in flight).
// Gathers are bf16 rows (256 B). Alpha softmax in-wave via score[] re-pass.
// ---------------------------------------------------------------------------
__global__ __launch_bounds__(256) void k_score(
    const int* __restrict__ eid_t, const int* __restrict__ base_t,
    const int* __restrict__ esrc,
    const float* __restrict__ H,
    const unsigned short* __restrict__ WhB,
    const unsigned short* __restrict__ HpB,
    const unsigned short* __restrict__ HqB,
    float* __restrict__ score, float* __restrict__ pairv,
    unsigned* __restrict__ maxs, float* __restrict__ sumt_inv, int N)
{
    const int lane = threadIdx.x & 63, wv = threadIdx.x >> 6;
    const int t = blockIdx.x * 4 + wv;
    if (t >= N) return;
    const int b0 = base_t[t], deg = base_t[t + 1] - b0;
    if (deg == 0) { if (lane == 0) sumt_inv[t] = 0.f; return; }
    const int sub = lane & 15, grp = lane >> 4;
    const size_t to = (size_t)t * HID;

    float ht[8], hq[8];
    {
        const f4 h0 = *(const f4*)&H[to + sub * 8];
        const f4 h1 = *(const f4*)&H[to + sub * 8 + 4];
        ht[0] = h0[0]; ht[1] = h0[1]; ht[2] = h0[2]; ht[3] = h0[3];
        ht[4] = h1[0]; ht[5] = h1[1]; ht[6] = h1[2]; ht[7] = h1[3];
        unpack8(*(const uint4*)&HqB[to + sub * 8], hq);
    }

    for (int j0 = 0; j0 < deg; j0 += 4) {
        const int jj = j0 + grp;
        const bool val = jj < deg;
        int eid = 0, src = 0;
        if (val) { eid = eid_t[b0 + jj]; src = esrc[eid]; }
        const size_t so = (size_t)src * HID;
        float wh[8], hp[8];
        unpack8(*(const uint4*)&WhB[so + sub * 8], wh);
        unpack8(*(const uint4*)&HpB[so + sub * 8], hp);
        float ps = 0.f, pp = 0.f;
        #pragma unroll
        for (int d = 0; d < 8; ++d) {
            ps = fmaf(ht[d], wh[d], ps);
            pp = fmaf(hp[d], hq[d], pp);
        }
        if (sub == 0) {
            const f4 s0 = *(const f4*)&H[so];
            const float2 s1 = *(const float2*)&H[so + 4];
            ps += s0[0]*ht[0] + s0[1]*ht[1] + s0[2]*ht[2] + s0[3]*ht[3]
                + s1.x*ht[4] + s1.y*ht[5];
        }
        #pragma unroll
        for (int mk = 1; mk < 16; mk <<= 1) {
            ps += __shfl_xor(ps, mk);
            pp += __shfl_xor(pp, mk);
        }
        if (sub == 0 && val) {
            score[b0 + jj] = ps;
            pairv[eid] = pp;
            atomicMax(&maxs[src], enc_f(pp));
        }
    }

    float m = -1e30f;
    for (int i = lane; i < deg; i += 64) m = fmaxf(m, score[b0 + i]);
    #pragma unroll
    for (int mk = 1; mk < 64; mk <<= 1) m = fmaxf(m, __shfl_xor(m, mk));
    float psum = 0.f;
    for (int i = lane; i < deg; i += 64) {
        const float e = expf(score[b0 + i] - m);
        score[b0 + i] = e;
        psum += e;
    }
    #pragma unroll
    for (int mk = 1; mk < 64; mk <<= 1) psum += __shfl_xor(psum, mk);
    if (lane == 0) sumt_inv[t] = 1.f / psum;
}

// per edge: e = exp(pair - max_src); sums[s] += e; num[s] += e * exp(-psi[t])
__global__ __launch_bounds__(256) void k_beta(
    const int* __restrict__ esrc, const int* __restrict__ etgt,
    const float* __restrict__ pairv, const unsigned* __restrict__ maxs,
    const float* __restrict__ psi,
    float* __restrict__ sums, float* __restrict__ num, int E)
{
    const int e = blockIdx.x * 256 + threadIdx.x;
    if (e >= E) return;
    const int s = esrc[e], t = etgt[e];
    const float ep = expf(pairv[e] - dec_f(maxs[s]));
    atomicAdd(&sums[s], ep);
    atomicAdd(&num[s], ep * expf(-psi[t]));
}

// per node: sum_term = num/sums; rho1m = 1 - sigmoid(GAMMA*(-log(st+1e-8)-DELTA))
__global__ __launch_bounds__(256) void k_rho(
    const float* __restrict__ sums, const float* __restrict__ num,
    float* __restrict__ rho1m, int N)
{
    const int n = blockIdx.x * 256 + threadIdx.x;
    if (n >= N) return;
    const float sm = sums[n];
    const float st = (sm > 0.f) ? num[n] / sm : 0.f;
    const float d  = -logf(st + 1e-8f);
    rho1m[n] = 1.f - 1.f / (1.f + expf(-(GAMMA * (d - DELTA))));
}

// ---------------------------------------------------------------------------
// k_matt: wave per TARGET, 16-lane edge groups; Hphi gathered as bf16.
// ---------------------------------------------------------------------------
__global__ __launch_bounds__(256) void k_matt(
    const int* __restrict__ eid_t, const int* __restrict__ base_t,
    const int* __restrict__ esrc,
    const float* __restrict__ score, const float* __restrict__ sumt_inv,
    const float* __restrict__ rho1m,
    const unsigned short* __restrict__ HphiB,
    float* __restrict__ matt, int N)
{
    const int lane = threadIdx.x & 63, wv = threadIdx.x >> 6;
    const int t = blockIdx.x * 4 + wv;
    if (t >= N) return;
    const int b0 = base_t[t], deg = base_t[t + 1] - b0;
    const int sub = lane & 15, grp = lane >> 4;
    const size_t to = (size_t)t * HID;

    float acc[8];
    #pragma unroll
    for (int d = 0; d < 8; ++d) acc[d] = 0.f;
    const float inv = (deg > 0) ? sumt_inv[t] : 0.f;

    for (int j0 = 0; j0 < deg; j0 += 4) {
        const int jj = j0 + grp;
        const bool val = jj < deg;
        float c = 0.f;
        size_t so = 0;
        if (val) {
            const int eid = eid_t[b0 + jj];
            const int src = esrc[eid];
            c = score[b0 + jj] * inv * rho1m[src];
            so = (size_t)src * HID;
        }
        float hf[8];
        unpack8(*(const uint4*)&HphiB[so + sub * 8], hf);
        #pragma unroll
        for (int d = 0; d < 8; ++d) acc[d] = fmaf(c, hf[d], acc[d]);
    }
    #pragma unroll
    for (int d = 0; d < 8; ++d) {
        acc[d] += __shfl_xor(acc[d], 16);
        acc[d] += __shfl_xor(acc[d], 32);
    }
    if (grp == 0) {
        f4 o0, o1;
        #pragma unroll
        for (int d = 0; d < 4; ++d) { o0[d] = acc[d]; o1[d] = acc[d + 4]; }
        *(f4*)&matt[to + sub * 8]     = o0;
        *(f4*)&matt[to + sub * 8 + 4] = o1;
    }
}

extern "C" void kernel_launch(void* const* d_in, const int* in_sizes, int n_in,
                              void* d_out, int out_size, void* d_ws, size_t ws_size,
                              hipStream_t stream)
{
    const int*   eidx   = (const int*)  d_in[0];
    const float* H      = (const float*)d_in[1];
    const float* W_att  = (const float*)d_in[2];
    const float* phi_w  = (const float*)d_in[3];
    const float* phi_b  = (const float*)d_in[4];
    const float* W_p    = (const float*)d_in[5];
    const float* W_pp   = (const float*)d_in[6];
    const float* fdef_w = (const float*)d_in[7];
    const float* fdef_b = (const float*)d_in[8];
    const float* Wself  = (const float*)d_in[9];
    const float* bself  = (const float*)d_in[10];
    const float* WA     = (const float*)d_in[11];
    const float* bA     = (const float*)d_in[12];
    const float* Wstr   = (const float*)d_in[13];
    const float* bstr   = (const float*)d_in[14];
    const float* lng    = (const float*)d_in[15];
    const float* lnb    = (const float*)d_in[16];
    float* out = (float*)d_out;

    const int E = in_sizes[0] / 2;
    const int N = in_sizes[1] / HID;
    const int* esrc = eidx;
    const int* etgt = eidx + E;

    // ---- workspace layout (~88 MB) ----
    char* w = (char*)d_ws;
    const size_t NHb  = (size_t)N * HID * sizeof(unsigned short);     // 12.8 MB
    const size_t NH   = (size_t)N * HID * sizeof(float);              // 25.6 MB
    const size_t Epad = (((size_t)E * sizeof(float)) + 255) & ~255ull;
    const size_t Npad = (((size_t)(N + 1) * sizeof(float)) + 255) & ~255ull;

    unsigned short* WhB   = (unsigned short*)w; w += NHb;
    unsigned short* HpB   = (unsigned short*)w; w += NHb;
    unsigned short* HqB   = (unsigned short*)w; w += NHb;
    unsigned short* HphiB = (unsigned short*)w; w += NHb;
    float* matt  = (float*)w; w += NH;
    float* score = (float*)w; w += Epad; // raw then exp'ed alpha, CSR order
    float* pairv = (float*)w; w += Epad; // raw pair scores, edge order
    int*   eid_t = (int*)  w; w += Epad;
    char*  zero0 = w;                    // 5 contiguous zero-init arrays
    int*      deg_t = (int*)     w; w += Npad;
    int*      cur_t = (int*)     w; w += Npad;
    unsigned* maxs  = (unsigned*)w; w += Npad;
    float*    sums  = (float*)   w; w += Npad;
    float*    num   = (float*)   w; w += Npad;
    int*   base_t   = (int*)     w; w += Npad;  // N+1 entries
    float* sumt_inv = (float*)   w; w += Npad;
    float* psi      = (float*)   w; w += Npad;
    float* rho1m    = (float*)   w; w += Npad;

    const int nblk128 = (N + 127) / 128;
    const int nblkN4  = (N + 3) / 4;
    const int nblkE   = (E + 255) / 256;
    const size_t lds_gemm = (size_t)(CHUNK * PADT + CHUNK * HID) * sizeof(float); // 65 KB

    hipMemsetAsync(zero0, 0, 5 * Npad, stream);  // deg_t, cur_t, maxs, sums, num

    GemmArgs g4;
    g4.W[0] = W_att; g4.W[1] = W_p; g4.W[2] = W_pp; g4.W[3] = phi_w;
    g4.b[0] = nullptr; g4.b[1] = nullptr; g4.b[2] = nullptr; g4.b[3] = phi_b;
    g4.O[0] = WhB; g4.O[1] = HpB; g4.O[2] = HqB; g4.O[3] = HphiB;
    k_gemm<<<dim3(nblk128, 4), 256, lds_gemm, stream>>>(H, g4, N);

    k_psi<<<nblkN4, 256, 0, stream>>>(H, fdef_w, fdef_b, psi, N);

    k_hist<<<nblkE, 256, 0, stream>>>(etgt, deg_t, E);
    k_scan<<<1, 1024, 0, stream>>>(deg_t, base_t, N);
    k_fill<<<nblkE, 256, 0, stream>>>(etgt, base_t, cur_t, eid_t, E);

    k_score<<<nblkN4, 256, 0, stream>>>(eid_t, base_t, esrc, H, WhB, HpB, HqB,
                                        score, pairv, maxs, sumt_inv, N);
    k_beta<<<nblkE, 256, 0, stream>>>(esrc, etgt, pairv, maxs, psi, sums, num, E);
    k_rho<<<(N + 255) / 256, 256, 0, stream>>>(sums, num, rho1m, N);

    k_matt<<<nblkN4, 256, 0, stream>>>(eid_t, base_t, esrc, score, sumt_inv,
                                       rho1m, HphiB, matt, N);

    k_final<<<nblk128, 256, lds_gemm, stream>>>(H, matt, Wself, bself, WA, bA,
                                                Wstr, bstr, lng, lnb, out, N);
}

// Round 7
// 482.401 us; speedup vs baseline: 6.2930x; 1.2853x over previous
//
#include <hip/hip_runtime.h>
#include <math.h>

#define HID 128
#define NSTR 6              // STRUCT-1
#define GAMMA 1.0f
#define DELTA 0.5f
#define LN_EPS 1e-5f
#define KPAD 72             // bf16 elems per LDS row (64 + 8 pad)

typedef __attribute__((ext_vector_type(4))) float f4;
typedef __attribute__((ext_vector_type(8))) short bf16x8;
typedef __attribute__((ext_vector_type(4))) float f32x4;

// order-preserving float<->uint encoding for atomicMax on floats
__device__ __forceinline__ unsigned enc_f(float f) {
    unsigned i = __float_as_uint(f);
    return (i & 0x80000000u) ? ~i : (i | 0x80000000u);
}
__device__ __forceinline__ float dec_f(unsigned u) {
    unsigned i = (u & 0x80000000u) ? (u ^ 0x80000000u) : ~u;
    return __uint_as_float(i);
}

// f32 -> bf16 (round-to-nearest-even) and helpers
__device__ __forceinline__ unsigned short f2bf(float f) {
    unsigned u = __float_as_uint(f);
    unsigned r = u + 0x7FFFu + ((u >> 16) & 1u);
    return (unsigned short)(r >> 16);
}
__device__ __forceinline__ float bf2f(unsigned short h) {
    return __uint_as_float((unsigned)h << 16);
}
// split f32 into hi+lo bf16 (3-MFMA f32 emulation operands)
__device__ __forceinline__ void split2(float v, unsigned short& h, unsigned short& l) {
    h = f2bf(v);
    l = f2bf(v - bf2f(h));
}
__device__ __forceinline__ void bf2f2(unsigned u, float& lo, float& hi) {
    lo = __uint_as_float(u << 16);
    hi = __uint_as_float(u & 0xFFFF0000u);
}
__device__ __forceinline__ void unpack8(const uint4 u, float* f) {
    bf2f2(u.x, f[0], f[1]); bf2f2(u.y, f[2], f[3]);
    bf2f2(u.z, f[4], f[5]); bf2f2(u.w, f[6], f[7]);
}

// ---------------------------------------------------------------------------
// k_prep: transpose + hi/lo-split the 6 weight matrices into WT
// WT layout per matrix m: [2][128 cols][128 k] bf16 (hi plane, lo plane)
// ---------------------------------------------------------------------------
struct PrepArgs { const float* W[6]; };

__global__ __launch_bounds__(256) void k_prep(PrepArgs p, unsigned short* WT)
{
    __shared__ float T[128][17];
    const int m = blockIdx.y, c0 = blockIdx.x * 16;
    const int tid = threadIdx.x;
    const float* __restrict__ W = p.W[m];
    for (int idx = tid; idx < 2048; idx += 256) {
        const int k = idx >> 4, c = idx & 15;
        T[k][c] = W[k * HID + c0 + c];
    }
    __syncthreads();
    unsigned short* hi = WT + (size_t)m * 2 * HID * HID;
    unsigned short* lo = hi + HID * HID;
    for (int idx = tid; idx < 2048; idx += 256) {
        const int c = idx >> 7, k = idx & 127;
        unsigned short h, l;
        split2(T[k][c], h, l);
        hi[(size_t)(c0 + c) * HID + k] = h;
        lo[(size_t)(c0 + c) * HID + k] = l;
    }
}

struct GemmArgsT {
    const unsigned short* Whi[4];
    const unsigned short* Wlo[4];
    const float*          b[4];
    unsigned short*       O[4];
};

// ---------------------------------------------------------------------------
// MFMA GEMM: O[ph] = bf16( A @ W[ph] (+b) ), split-precision (hi/lo bf16,
// 3 MFMA per k-step per tile => f32-equivalent numerics).
// Block 256 thr = 4 waves; wave w owns rows [w*32,w*32+32) x 128 cols
// = 2x8 tiles of 16x16. K chunked by 64 (2 chunks). LDS 72KB -> 2 blk/CU.
// Fragment maps: A/B row(col)=l&15, k=(l>>4)*8+e; D col=l&15,row=(l>>4)*4+reg.
// ---------------------------------------------------------------------------
__global__ __launch_bounds__(256, 2) void k_gemm(const float* __restrict__ A,
                                                 GemmArgsT g, int N)
{
    extern __shared__ unsigned short lds[];
    unsigned short* Ahi = lds;
    unsigned short* Alo = lds + 128 * KPAD;
    unsigned short* Bhi = lds + 2 * 128 * KPAD;
    unsigned short* Blo = lds + 3 * 128 * KPAD;
    const int tid  = threadIdx.x;
    const int row0 = blockIdx.x * 128;
    const int nrows = min(128, N - row0);
    const int ph   = blockIdx.y;
    const int w    = tid >> 6, lane = tid & 63;
    const int lrow = lane & 15, kgrp = lane >> 4;

    const float* bp = g.b[ph];
    f32x4 acc[2][8];
    #pragma unroll
    for (int tc = 0; tc < 8; ++tc) {
        const float bv = bp ? bp[tc * 16 + lrow] : 0.f;
        acc[0][tc] = f32x4{bv, bv, bv, bv};
        acc[1][tc] = f32x4{bv, bv, bv, bv};
    }

    const unsigned short* __restrict__ Wh = g.Whi[ph];
    const unsigned short* __restrict__ Wl = g.Wlo[ph];

    for (int ch = 0; ch < 2; ++ch) {
        __syncthreads();
        // stage A chunk: 128 rows x 64 k f32 -> split -> hi/lo bf16
        #pragma unroll
        for (int it = 0; it < 8; ++it) {
            const int idx = tid + 256 * it;          // 0..2047 (f4 units)
            const int r = idx >> 4, kq = (idx & 15) * 4;
            f4 v = {0.f, 0.f, 0.f, 0.f};
            if (r < nrows) v = *(const f4*)&A[(size_t)(row0 + r) * HID + ch * 64 + kq];
            ushort4 h, l;
            split2(v[0], h.x, l.x); split2(v[1], h.y, l.y);
            split2(v[2], h.z, l.z); split2(v[3], h.w, l.w);
            *(ushort4*)&Ahi[r * KPAD + kq] = h;
            *(ushort4*)&Alo[r * KPAD + kq] = l;
        }
        // stage W chunk from pre-transposed/split global: [c][k] bf16
        #pragma unroll
        for (int it = 0; it < 4; ++it) {
            const int idx = tid + 256 * it;          // 0..1023 (uint4 units)
            const int c = idx >> 3, k8 = (idx & 7) * 8;
            *(uint4*)&Bhi[c * KPAD + k8] = *(const uint4*)&Wh[(size_t)c * HID + ch * 64 + k8];
            *(uint4*)&Blo[c * KPAD + k8] = *(const uint4*)&Wl[(size_t)c * HID + ch * 64 + k8];
        }
        __syncthreads();

        #pragma unroll
        for (int ks = 0; ks < 2; ++ks) {
            const int ko = ks * 32 + kgrp * 8;
            bf16x8 ah[2], al[2], bh[8], bl[8];
            #pragma unroll
            for (int tr = 0; tr < 2; ++tr) {
                const int rr = w * 32 + tr * 16 + lrow;
                ah[tr] = *(const bf16x8*)&Ahi[rr * KPAD + ko];
                al[tr] = *(const bf16x8*)&Alo[rr * KPAD + ko];
            }
            #pragma unroll
            for (int tc = 0; tc < 8; ++tc) {
                const int cc = tc * 16 + lrow;
                bh[tc] = *(const bf16x8*)&Bhi[cc * KPAD + ko];
                bl[tc] = *(const bf16x8*)&Blo[cc * KPAD + ko];
            }
            #pragma unroll
            for (int tr = 0; tr < 2; ++tr)
                #pragma unroll
                for (int tc = 0; tc < 8; ++tc) {
                    acc[tr][tc] = __builtin_amdgcn_mfma_f32_16x16x32_bf16(ah[tr], bh[tc], acc[tr][tc], 0, 0, 0);
                    acc[tr][tc] = __builtin_amdgcn_mfma_f32_16x16x32_bf16(al[tr], bh[tc], acc[tr][tc], 0, 0, 0);
                    acc[tr][tc] = __builtin_amdgcn_mfma_f32_16x16x32_bf16(ah[tr], bl[tc], acc[tr][tc], 0, 0, 0);
                }
        }
    }

    unsigned short* __restrict__ O = g.O[ph];
    #pragma unroll
    for (int tr = 0; tr < 2; ++tr)
        #pragma unroll
        for (int j = 0; j < 4; ++j) {
            const int r = w * 32 + tr * 16 + kgrp * 4 + j;
            if (r < nrows) {
                #pragma unroll
                for (int tc = 0; tc < 8; ++tc)
                    O[(size_t)(row0 + r) * HID + tc * 16 + lrow] = f2bf(acc[tr][tc][j]);
            }
        }
}

// ---------------------------------------------------------------------------
// k_final: out = LN(relu(Matt@WA + H@Wself + s@Wstr + biases) + H)
// Same MFMA split-precision structure (2 phases x 2 chunks, acc persists);
// Wstr term = small VALU block off staged H chunk 0; fused ReLU+resid+LN.
// ---------------------------------------------------------------------------
__global__ __launch_bounds__(256, 2) void k_final(
    const float* __restrict__ Matt, const float* __restrict__ H,
    const unsigned short* __restrict__ WAhi, const unsigned short* __restrict__ WAlo,
    const unsigned short* __restrict__ WShi, const unsigned short* __restrict__ WSlo,
    const float* __restrict__ Wstr,
    const float* __restrict__ bself, const float* __restrict__ bA,
    const float* __restrict__ bstr,
    const float* __restrict__ lng, const float* __restrict__ lnb,
    float* __restrict__ out, int N)
{
    extern __shared__ unsigned short lds[];
    unsigned short* Ahi = lds;
    unsigned short* Alo = lds + 128 * KPAD;
    unsigned short* Bhi = lds + 2 * 128 * KPAD;
    unsigned short* Blo = lds + 3 * 128 * KPAD;
    const int tid  = threadIdx.x;
    const int row0 = blockIdx.x * 128;
    const int nrows = min(128, N - row0);
    const int w    = tid >> 6, lane = tid & 63;
    const int lrow = lane & 15, kgrp = lane >> 4;

    f32x4 acc[2][8];
    float gl[8], bl_[8];
    #pragma unroll
    for (int tc = 0; tc < 8; ++tc) {
        const int c = tc * 16 + lrow;
        const float bv = bself[c] + bA[c] + bstr[c];
        acc[0][tc] = f32x4{bv, bv, bv, bv};
        acc[1][tc] = f32x4{bv, bv, bv, bv};
        gl[tc] = lng[c]; bl_[tc] = lnb[c];
    }

    for (int ph = 0; ph < 2; ++ph) {
        const float* __restrict__ Am = ph ? H : Matt;
        const unsigned short* __restrict__ Wh = ph ? WShi : WAhi;
        const unsigned short* __restrict__ Wl = ph ? WSlo : WAlo;
        for (int ch = 0; ch < 2; ++ch) {
            __syncthreads();
            #pragma unroll
            for (int it = 0; it < 8; ++it) {
                const int idx = tid + 256 * it;
                const int r = idx >> 4, kq = (idx & 15) * 4;
                f4 v = {0.f, 0.f, 0.f, 0.f};
                if (r < nrows) v = *(const f4*)&Am[(size_t)(row0 + r) * HID + ch * 64 + kq];
                ushort4 h, l;
                split2(v[0], h.x, l.x); split2(v[1], h.y, l.y);
                split2(v[2], h.z, l.z); split2(v[3], h.w, l.w);
                *(ushort4*)&Ahi[r * KPAD + kq] = h;
                *(ushort4*)&Alo[r * KPAD + kq] = l;
            }
            #pragma unroll
            for (int it = 0; it < 4; ++it) {
                const int idx = tid + 256 * it;
                const int c = idx >> 3, k8 = (idx & 7) * 8;
                *(uint4*)&Bhi[c * KPAD + k8] = *(const uint4*)&Wh[(size_t)c * HID + ch * 64 + k8];
                *(uint4*)&Blo[c * KPAD + k8] = *(const uint4*)&Wl[(size_t)c * HID + ch * 64 + k8];
            }
            __syncthreads();

            #pragma unroll
            for (int ks = 0; ks < 2; ++ks) {
                const int ko = ks * 32 + kgrp * 8;
                bf16x8 ah[2], al[2], bh[8], bl[8];
                #pragma unroll
                for (int tr = 0; tr < 2; ++tr) {
                    const int rr = w * 32 + tr * 16 + lrow;
                    ah[tr] = *(const bf16x8*)&Ahi[rr * KPAD + ko];
                    al[tr] = *(const bf16x8*)&Alo[rr * KPAD + ko];
                }
                #pragma unroll
                for (int tc = 0; tc < 8; ++tc) {
                    const int cc = tc * 16 + lrow;
                    bh[tc] = *(const bf16x8*)&Bhi[cc * KPAD + ko];
                    bl[tc] = *(const bf16x8*)&Blo[cc * KPAD + ko];
                }
                #pragma unroll
                for (int tr = 0; tr < 2; ++tr)
                    #pragma unroll
                    for (int tc = 0; tc < 8; ++tc) {
                        acc[tr][tc] = __builtin_amdgcn_mfma_f32_16x16x32_bf16(ah[tr], bh[tc], acc[tr][tc], 0, 0, 0);
                        acc[tr][tc] = __builtin_amdgcn_mfma_f32_16x16x32_bf16(al[tr], bh[tc], acc[tr][tc], 0, 0, 0);
                        acc[tr][tc] = __builtin_amdgcn_mfma_f32_16x16x32_bf16(ah[tr], bl[tc], acc[tr][tc], 0, 0, 0);
                    }
            }

            if (ph == 1 && ch == 0) {
                // s_feat (= H[:, :6]) @ Wstr off the staged H chunk (hi+lo)
                #pragma unroll
                for (int tr = 0; tr < 2; ++tr)
                    #pragma unroll
                    for (int j = 0; j < 4; ++j) {
                        const int rr = w * 32 + tr * 16 + kgrp * 4 + j;
                        float s[NSTR];
                        #pragma unroll
                        for (int k = 0; k < NSTR; ++k)
                            s[k] = bf2f(Ahi[rr * KPAD + k]) + bf2f(Alo[rr * KPAD + k]);
                        #pragma unroll
                        for (int tc = 0; tc < 8; ++tc) {
                            float a = 0.f;
                            #pragma unroll
                            for (int k = 0; k < NSTR; ++k)
                                a = fmaf(s[k], Wstr[k * HID + tc * 16 + lrow], a);
                            acc[tr][tc][j] += a;
                        }
                    }
            }
        }
    }

    // ---- relu + residual + LayerNorm (16-lane shfl reduce per row) ----
    #pragma unroll
    for (int tr = 0; tr < 2; ++tr)
        #pragma unroll
        for (int j = 0; j < 4; ++j) {
            const int r = w * 32 + tr * 16 + kgrp * 4 + j;
            const bool valid = r < nrows;
            const size_t rb = (size_t)(row0 + r) * HID;
            float v[8], s1 = 0.f, s2 = 0.f;
            #pragma unroll
            for (int tc = 0; tc < 8; ++tc) {
                float x = fmaxf(acc[tr][tc][j], 0.f);
                if (valid) x += H[rb + tc * 16 + lrow];
                v[tc] = x;
                s1 += x; s2 += x * x;
            }
            #pragma unroll
            for (int mk = 1; mk < 16; mk <<= 1) {
                s1 += __shfl_xor(s1, mk);
                s2 += __shfl_xor(s2, mk);
            }
            const float mean = s1 * (1.f / HID);
            const float var  = s2 * (1.f / HID) - mean * mean;
            const float rs   = rsqrtf(var + LN_EPS);
            if (valid) {
                #pragma unroll
                for (int tc = 0; tc < 8; ++tc)
                    out[rb + tc * 16 + lrow] = (v[tc] - mean) * rs * gl[tc] + bl_[tc];
            }
        }
}

// psi[n] = dot(H[n], f_def_w) + f_def_b   (wave per node)
__global__ __launch_bounds__(256) void k_psi(
    const float* __restrict__ H, const float* __restrict__ fw, const float* __restrict__ fb,
    float* __restrict__ psi, int N)
{
    const int wid = threadIdx.x >> 6, lane = threadIdx.x & 63;
    const int n = blockIdx.x * 4 + wid;
    if (n >= N) return;
    const size_t o = (size_t)n * HID;
    float a = H[o + lane] * fw[lane] + H[o + 64 + lane] * fw[64 + lane];
    #pragma unroll
    for (int off = 32; off; off >>= 1) a += __shfl_down(a, off);
    if (lane == 0) psi[n] = a + fb[0];
}

// ---------------------------------------------------------------------------
// CSR-by-target build: histogram, single-block scan, fill
// ---------------------------------------------------------------------------
__global__ __launch_bounds__(256) void k_hist(
    const int* __restrict__ etgt, int* __restrict__ deg, int E)
{
    const int e = blockIdx.x * 256 + threadIdx.x;
    if (e < E) atomicAdd(&deg[etgt[e]], 1);
}

__global__ __launch_bounds__(1024) void k_scan(
    const int* __restrict__ deg, int* __restrict__ base, int N)
{
    __shared__ int warp_sums[16];
    __shared__ int carry_s;
    const int tid = threadIdx.x, lane = tid & 63, wid = tid >> 6;
    if (tid == 0) carry_s = 0;
    __syncthreads();
    for (int i0 = 0; i0 < N; i0 += 1024) {
        const int i = i0 + tid;
        const int v = (i < N) ? deg[i] : 0;
        int x = v;
        #pragma unroll
        for (int d = 1; d < 64; d <<= 1) {
            const int y = __shfl_up(x, d);
            if (lane >= d) x += y;
        }
        if (lane == 63) warp_sums[wid] = x;
        __syncthreads();
        if (wid == 0) {
            int ws = (lane < 16) ? warp_sums[lane] : 0;
            #pragma unroll
            for (int d = 1; d < 16; d <<= 1) {
                const int y = __shfl_up(ws, d);
                if (lane >= d) ws += y;
            }
            if (lane < 16) warp_sums[lane] = ws;
        }
        __syncthreads();
        const int carry = carry_s;
        if (i < N) base[i] = carry + (wid ? warp_sums[wid - 1] : 0) + x - v;
        __syncthreads();
        if (tid == 1023) carry_s = carry + warp_sums[15];
        __syncthreads();
    }
    if (tid == 0) base[N] = carry_s;
}

__global__ __launch_bounds__(256) void k_fill(
    const int* __restrict__ etgt, const int* __restrict__ base,
    int* __restrict__ cur, int* __restrict__ eid_t, int E)
{
    const int e = blockIdx.x * 256 + threadIdx.x;
    if (e < E) {
        const int t = etgt[e];
        const int p = atomicAdd(&cur[t], 1);
        eid_t[base[t] + p] = e;
    }
}

// ---------------------------------------------------------------------------
// k_score: wave per TARGET node, 16-lane edge groups (4 edges in flight).
// ---------------------------------------------------------------------------
__global__ __launch_bounds__(256) void k_score(
    const int* __restrict__ eid_t, const int* __restrict__ base_t,
    const int* __restrict__ esrc,
    const float* __restrict__ H,
    const unsigned short* __restrict__ WhB,
    const unsigned short* __restrict__ HpB,
    const unsigned short* __restrict__ HqB,
    float* __restrict__ score, float* __restrict__ pairv,
    unsigned* __restrict__ maxs, float* __restrict__ sumt_inv, int N)
{
    const int lane = threadIdx.x & 63, wv = threadIdx.x >> 6;
    const int t = blockIdx.x * 4 + wv;
    if (t >= N) return;
    const int b0 = base_t[t], deg = base_t[t + 1] - b0;
    if (deg == 0) { if (lane == 0) sumt_inv[t] = 0.f; return; }
    const int sub = lane & 15, grp = lane >> 4;
    const size_t to = (size_t)t * HID;

    float ht[8], hq[8];
    {
        const f4 h0 = *(const f4*)&H[to + sub * 8];
        const f4 h1 = *(const f4*)&H[to + sub * 8 + 4];
        ht[0] = h0[0]; ht[1] = h0[1]; ht[2] = h0[2]; ht[3] = h0[3];
        ht[4] = h1[0]; ht[5] = h1[1]; ht[6] = h1[2]; ht[7] = h1[3];
        unpack8(*(const uint4*)&HqB[to + sub * 8], hq);
    }

    for (int j0 = 0; j0 < deg; j0 += 4) {
        const int jj = j0 + grp;
        const bool val = jj < deg;
        int eid = 0, src = 0;
        if (val) { eid = eid_t[b0 + jj]; src = esrc[eid]; }
        const size_t so = (size_t)src * HID;
        float wh[8], hp[8];
        unpack8(*(const uint4*)&WhB[so + sub * 8], wh);
        unpack8(*(const uint4*)&HpB[so + sub * 8], hp);
        float ps = 0.f, pp = 0.f;
        #pragma unroll
        for (int d = 0; d < 8; ++d) {
            ps = fmaf(ht[d], wh[d], ps);
            pp = fmaf(hp[d], hq[d], pp);
        }
        if (sub == 0) {
            const f4 s0 = *(const f4*)&H[so];
            const float2 s1 = *(const float2*)&H[so + 4];
            ps += s0[0]*ht[0] + s0[1]*ht[1] + s0[2]*ht[2] + s0[3]*ht[3]
                + s1.x*ht[4] + s1.y*ht[5];
        }
        #pragma unroll
        for (int mk = 1; mk < 16; mk <<= 1) {
            ps += __shfl_xor(ps, mk);
            pp += __shfl_xor(pp, mk);
        }
        if (sub == 0 && val) {
            score[b0 + jj] = ps;
            pairv[eid] = pp;
            atomicMax(&maxs[src], enc_f(pp));
        }
    }

    float m = -1e30f;
    for (int i = lane; i < deg; i += 64) m = fmaxf(m, score[b0 + i]);
    #pragma unroll
    for (int mk = 1; mk < 64; mk <<= 1) m = fmaxf(m, __shfl_xor(m, mk));
    float psum = 0.f;
    for (int i = lane; i < deg; i += 64) {
        const float e = expf(score[b0 + i] - m);
        score[b0 + i] = e;
        psum += e;
    }
    #pragma unroll
    for (int mk = 1; mk < 64; mk <<= 1) psum += __shfl_xor(psum, mk);
    if (lane == 0) sumt_inv[t] = 1.f / psum;
}

// per edge: e = exp(pair - max_src); sums[s] += e; num[s] += e * exp(-psi[t])
__global__ __launch_bounds__(256) void k_beta(
    const int* __restrict__ esrc, const int* __restrict__ etgt,
    const float* __restrict__ pairv, const unsigned* __restrict__ maxs,
    const float* __restrict__ psi,
    float* __restrict__ sums, float* __restrict__ num, int E)
{
    const int e = blockIdx.x * 256 + threadIdx.x;
    if (e >= E) return;
    const int s = esrc[e], t = etgt[e];
    const float ep = expf(pairv[e] - dec_f(maxs[s]));
    atomicAdd(&sums[s], ep);
    atomicAdd(&num[s], ep * expf(-psi[t]));
}

// per node: sum_term = num/sums; rho1m = 1 - sigmoid(GAMMA*(-log(st+1e-8)-DELTA))
__global__ __launch_bounds__(256) void k_rho(
    const float* __restrict__ sums, const float* __restrict__ num,
    float* __restrict__ rho1m, int N)
{
    const int n = blockIdx.x * 256 + threadIdx.x;
    if (n >= N) return;
    const float sm = sums[n];
    const float st = (sm > 0.f) ? num[n] / sm : 0.f;
    const float d  = -logf(st + 1e-8f);
    rho1m[n] = 1.f - 1.f / (1.f + expf(-(GAMMA * (d - DELTA))));
}

// ---------------------------------------------------------------------------
// k_matt: wave per TARGET, 16-lane edge groups; Hphi gathered as bf16.
// ---------------------------------------------------------------------------
__global__ __launch_bounds__(256) void k_matt(
    const int* __restrict__ eid_t, const int* __restrict__ base_t,
    const int* __restrict__ esrc,
    const float* __restrict__ score, const float* __restrict__ sumt_inv,
    const float* __restrict__ rho1m,
    const unsigned short* __restrict__ HphiB,
    float* __restrict__ matt, int N)
{
    const int lane = threadIdx.x & 63, wv = threadIdx.x >> 6;
    const int t = blockIdx.x * 4 + wv;
    if (t >= N) return;
    const int b0 = base_t[t], deg = base_t[t + 1] - b0;
    const int sub = lane & 15, grp = lane >> 4;
    const size_t to = (size_t)t * HID;

    float acc[8];
    #pragma unroll
    for (int d = 0; d < 8; ++d) acc[d] = 0.f;
    const float inv = (deg > 0) ? sumt_inv[t] : 0.f;

    for (int j0 = 0; j0 < deg; j0 += 4) {
        const int jj = j0 + grp;
        const bool val = jj < deg;
        float c = 0.f;
        size_t so = 0;
        if (val) {
            const int eid = eid_t[b0 + jj];
            const int src = esrc[eid];
            c = score[b0 + jj] * inv * rho1m[src];
            so = (size_t)src * HID;
        }
        float hf[8];
        unpack8(*(const uint4*)&HphiB[so + sub * 8], hf);
        #pragma unroll
        for (int d = 0; d < 8; ++d) acc[d] = fmaf(c, hf[d], acc[d]);
    }
    #pragma unroll
    for (int d = 0; d < 8; ++d) {
        acc[d] += __shfl_xor(acc[d], 16);
        acc[d] += __shfl_xor(acc[d], 32);
    }
    if (grp == 0) {
        f4 o0, o1;
        #pragma unroll
        for (int d = 0; d < 4; ++d) { o0[d] = acc[d]; o1[d] = acc[d + 4]; }
        *(f4*)&matt[to + sub * 8]     = o0;
        *(f4*)&matt[to + sub * 8 + 4] = o1;
    }
}

extern "C" void kernel_launch(void* const* d_in, const int* in_sizes, int n_in,
                              void* d_out, int out_size, void* d_ws, size_t ws_size,
                              hipStream_t stream)
{
    const int*   eidx   = (const int*)  d_in[0];
    const float* H      = (const float*)d_in[1];
    const float* W_att  = (const float*)d_in[2];
    const float* phi_w  = (const float*)d_in[3];
    const float* phi_b  = (const float*)d_in[4];
    const float* W_p    = (const float*)d_in[5];
    const float* W_pp   = (const float*)d_in[6];
    const float* fdef_w = (const float*)d_in[7];
    const float* fdef_b = (const float*)d_in[8];
    const float* Wself  = (const float*)d_in[9];
    const float* bself  = (const float*)d_in[10];
    const float* WA     = (const float*)d_in[11];
    const float* bA     = (const float*)d_in[12];
    const float* Wstr   = (const float*)d_in[13];
    const float* bstr   = (const float*)d_in[14];
    const float* lng    = (const float*)d_in[15];
    const float* lnb    = (const float*)d_in[16];
    float* out = (float*)d_out;

    const int E = in_sizes[0] / 2;
    const int N = in_sizes[1] / HID;
    const int* esrc = eidx;
    const int* etgt = eidx + E;

    // ---- workspace layout (~89 MB) ----
    char* w = (char*)d_ws;
    const size_t NHb  = (size_t)N * HID * sizeof(unsigned short);     // 12.8 MB
    const size_t NH   = (size_t)N * HID * sizeof(float);              // 25.6 MB
    const size_t Epad = (((size_t)E * sizeof(float)) + 255) & ~255ull;
    const size_t Npad = (((size_t)(N + 1) * sizeof(float)) + 255) & ~255ull;

    unsigned short* WhB   = (unsigned short*)w; w += NHb;
    unsigned short* HpB   = (unsigned short*)w; w += NHb;
    unsigned short* HqB   = (unsigned short*)w; w += NHb;
    unsigned short* HphiB = (unsigned short*)w; w += NHb;
    float* matt  = (float*)w; w += NH;
    float* score = (float*)w; w += Epad;
    float* pairv = (float*)w; w += Epad;
    int*   eid_t = (int*)  w; w += Epad;
    char*  zero0 = w;                    // 5 contiguous zero-init arrays
    int*      deg_t = (int*)     w; w += Npad;
    int*      cur_t = (int*)     w; w += Npad;
    unsigned* maxs  = (unsigned*)w; w += Npad;
    float*    sums  = (float*)   w; w += Npad;
    float*    num   = (float*)   w; w += Npad;
    int*   base_t   = (int*)     w; w += Npad;  // N+1 entries
    float* sumt_inv = (float*)   w; w += Npad;
    float* psi      = (float*)   w; w += Npad;
    float* rho1m    = (float*)   w; w += Npad;
    unsigned short* WT = (unsigned short*)w; w += 6 * 2 * HID * HID * sizeof(unsigned short);

    const int nblk128 = (N + 127) / 128;
    const int nblkN4  = (N + 3) / 4;
    const int nblkE   = (E + 255) / 256;
    const size_t lds_mfma = 4 * 128 * KPAD * sizeof(unsigned short);  // 72 KB

    hipMemsetAsync(zero0, 0, 5 * Npad, stream);  // deg_t, cur_t, maxs, sums, num

    // transpose + split weights: 0=Watt 1=Wp 2=Wpp 3=phiw 4=WA 5=Wself
    PrepArgs pa;
    pa.W[0] = W_att; pa.W[1] = W_p; pa.W[2] = W_pp;
    pa.W[3] = phi_w; pa.W[4] = WA;  pa.W[5] = Wself;
    k_prep<<<dim3(8, 6), 256, 0, stream>>>(pa, WT);

    const size_t MSZ = (size_t)2 * HID * HID;
    GemmArgsT g4;
    for (int m = 0; m < 4; ++m) {
        g4.Whi[m] = WT + m * MSZ;
        g4.Wlo[m] = WT + m * MSZ + HID * HID;
    }
    g4.b[0] = nullptr; g4.b[1] = nullptr; g4.b[2] = nullptr; g4.b[3] = phi_b;
    g4.O[0] = WhB; g4.O[1] = HpB; g4.O[2] = HqB; g4.O[3] = HphiB;
    k_gemm<<<dim3(nblk128, 4), 256, lds_mfma, stream>>>(H, g4, N);

    k_psi<<<nblkN4, 256, 0, stream>>>(H, fdef_w, fdef_b, psi, N);

    k_hist<<<nblkE, 256, 0, stream>>>(etgt, deg_t, E);
    k_scan<<<1, 1024, 0, stream>>>(deg_t, base_t, N);
    k_fill<<<nblkE, 256, 0, stream>>>(etgt, base_t, cur_t, eid_t, E);

    k_score<<<nblkN4, 256, 0, stream>>>(eid_t, base_t, esrc, H, WhB, HpB, HqB,
                                        score, pairv, maxs, sumt_inv, N);
    k_beta<<<nblkE, 256, 0, stream>>>(esrc, etgt, pairv, maxs, psi, sums, num, E);
    k_rho<<<(N + 255) / 256, 256, 0, stream>>>(sums, num, rho1m, N);

    k_matt<<<nblkN4, 256, 0, stream>>>(eid_t, base_t, esrc, score, sumt_inv,
                                       rho1m, HphiB, matt, N);

    k_final<<<nblk128, 256, lds_mfma, stream>>>(matt, H,
                                                WT + 4 * MSZ, WT + 4 * MSZ + HID * HID,
                                                WT + 5 * MSZ, WT + 5 * MSZ + HID * HID,
                                                Wstr, bself, bA, bstr, lng, lnb, out, N);
}

// Round 8
// 468.750 us; speedup vs baseline: 6.4763x; 1.0291x over previous
//
#include <hip/hip_runtime.h>
#include <math.h>

#define HID 128
#define NSTR 6              // STRUCT-1
#define GAMMA 1.0f
#define DELTA 0.5f
#define LN_EPS 1e-5f
#define KPAD 72             // bf16 elems per LDS row (64 + 8 pad)

typedef __attribute__((ext_vector_type(4))) float f4;
typedef __attribute__((ext_vector_type(8))) short bf16x8;
typedef __attribute__((ext_vector_type(4))) float f32x4;

// order-preserving float<->uint encoding for atomicMax on floats
__device__ __forceinline__ unsigned enc_f(float f) {
    unsigned i = __float_as_uint(f);
    return (i & 0x80000000u) ? ~i : (i | 0x80000000u);
}
__device__ __forceinline__ float dec_f(unsigned u) {
    unsigned i = (u & 0x80000000u) ? (u ^ 0x80000000u) : ~u;
    return __uint_as_float(i);
}

// f32 -> bf16 (round-to-nearest-even) and helpers
__device__ __forceinline__ unsigned short f2bf(float f) {
    unsigned u = __float_as_uint(f);
    unsigned r = u + 0x7FFFu + ((u >> 16) & 1u);
    return (unsigned short)(r >> 16);
}
__device__ __forceinline__ float bf2f(unsigned short h) {
    return __uint_as_float((unsigned)h << 16);
}
__device__ __forceinline__ void split2(float v, unsigned short& h, unsigned short& l) {
    h = f2bf(v);
    l = f2bf(v - bf2f(h));
}
__device__ __forceinline__ void bf2f2(unsigned u, float& lo, float& hi) {
    lo = __uint_as_float(u << 16);
    hi = __uint_as_float(u & 0xFFFF0000u);
}
__device__ __forceinline__ void unpack8(const uint4 u, float* f) {
    bf2f2(u.x, f[0], f[1]); bf2f2(u.y, f[2], f[3]);
    bf2f2(u.z, f[4], f[5]); bf2f2(u.w, f[6], f[7]);
}

// ---------------------------------------------------------------------------
// k_prep: split (optionally transpose) 4 weight matrices into WT slots.
// Slot layout per matrix: [hi 128x128][lo 128x128] bf16, table[c][k].
// tr=1: table[c][k] = W[k][c] (for O = A@W);  tr=0: table[c][k] = W[c][k]
// (for O = A@W^T).
// ---------------------------------------------------------------------------
struct PrepArgs { const float* W[4]; int tr[4]; };

__global__ __launch_bounds__(256) void k_prep(PrepArgs p, unsigned short* WT)
{
    __shared__ float T[128][17];
    const int m = blockIdx.y, c0 = blockIdx.x * 16;
    const int tid = threadIdx.x;
    const float* __restrict__ W = p.W[m];
    unsigned short* hi = WT + (size_t)m * 2 * HID * HID;
    unsigned short* lo = hi + HID * HID;
    if (p.tr[m]) {
        for (int idx = tid; idx < 2048; idx += 256) {
            const int k = idx >> 4, c = idx & 15;
            T[k][c] = W[k * HID + c0 + c];
        }
        __syncthreads();
        for (int idx = tid; idx < 2048; idx += 256) {
            const int c = idx >> 7, k = idx & 127;
            unsigned short h, l;
            split2(T[k][c], h, l);
            hi[(size_t)(c0 + c) * HID + k] = h;
            lo[(size_t)(c0 + c) * HID + k] = l;
        }
    } else {
        for (int idx = tid; idx < 2048; idx += 256) {
            const int c = idx >> 7, k = idx & 127;
            unsigned short h, l;
            split2(W[(size_t)(c0 + c) * HID + k], h, l);
            hi[(size_t)(c0 + c) * HID + k] = h;
            lo[(size_t)(c0 + c) * HID + k] = l;
        }
    }
}

// ---------------------------------------------------------------------------
// k_m2: M2[c][k] = sum_j W_p[c][j] * W_pp[k][j]  (= W_p @ W_pp^T), split into
// WT slot (row-major = table layout for U = H @ M2^T).
// ---------------------------------------------------------------------------
__global__ __launch_bounds__(256) void k_m2(
    const float* __restrict__ Wp, const float* __restrict__ Wpp,
    unsigned short* __restrict__ slot)
{
    __shared__ float Bs[128][129];
    __shared__ float As[16][129];
    const int tid = threadIdx.x, c0 = blockIdx.x * 16;
    for (int idx = tid; idx < 128 * 128; idx += 256)
        Bs[idx >> 7][idx & 127] = Wpp[idx];
    for (int idx = tid; idx < 16 * 128; idx += 256)
        As[idx >> 7][idx & 127] = Wp[(size_t)(c0 + (idx >> 7)) * HID + (idx & 127)];
    __syncthreads();
    unsigned short* hi = slot;
    unsigned short* lo = slot + HID * HID;
    for (int it = 0; it < 8; ++it) {
        const int idx = tid + 256 * it;         // 0..2047
        const int c = idx >> 7, k = idx & 127;
        float a = 0.f;
        #pragma unroll 4
        for (int j = 0; j < 128; ++j)
            a = fmaf(As[c][j], Bs[k][j], a);
        unsigned short h, l;
        split2(a, h, l);
        hi[(size_t)(c0 + c) * HID + k] = h;
        lo[(size_t)(c0 + c) * HID + k] = l;
    }
}

// HB = bf16(H)   elementwise cast, 8 elems/thread
__global__ __launch_bounds__(256) void k_cast(
    const float* __restrict__ H, unsigned short* __restrict__ HB, int total8)
{
    const int idx = blockIdx.x * 256 + threadIdx.x;
    if (idx >= total8) return;
    const size_t o = (size_t)idx * 8;
    const f4 v0 = *(const f4*)&H[o];
    const f4 v1 = *(const f4*)&H[o + 4];
    ushort4 a, b;
    a.x = f2bf(v0[0]); a.y = f2bf(v0[1]); a.z = f2bf(v0[2]); a.w = f2bf(v0[3]);
    b.x = f2bf(v1[0]); b.y = f2bf(v1[1]); b.z = f2bf(v1[2]); b.w = f2bf(v1[3]);
    *(ushort4*)&HB[o] = a;
    *(ushort4*)&HB[o + 4] = b;
}

struct GemmArgsT {
    const unsigned short* Whi[3];
    const unsigned short* Wlo[3];
    const float*          b[3];
    void*                 O[3];
    int                   of32[3];
};

// ---------------------------------------------------------------------------
// MFMA GEMM: O[ph] = A @ B[ph] (+b), split-precision (hi/lo bf16, 3 MFMA).
// Output f32 or bf16 per of32 flag. Block 256 = 4 waves; wave w: rows
// [w*32, w*32+32) x 128 cols = 2x8 tiles 16x16. K chunked by 64.
// ---------------------------------------------------------------------------
__global__ __launch_bounds__(256, 2) void k_gemm(const float* __restrict__ A,
                                                 GemmArgsT g, int N)
{
    extern __shared__ unsigned short lds[];
    unsigned short* Ahi = lds;
    unsigned short* Alo = lds + 128 * KPAD;
    unsigned short* Bhi = lds + 2 * 128 * KPAD;
    unsigned short* Blo = lds + 3 * 128 * KPAD;
    const int tid  = threadIdx.x;
    const int row0 = blockIdx.x * 128;
    const int nrows = min(128, N - row0);
    const int ph   = blockIdx.y;
    const int w    = tid >> 6, lane = tid & 63;
    const int lrow = lane & 15, kgrp = lane >> 4;

    const float* bp = g.b[ph];
    f32x4 acc[2][8];
    #pragma unroll
    for (int tc = 0; tc < 8; ++tc) {
        const float bv = bp ? bp[tc * 16 + lrow] : 0.f;
        acc[0][tc] = f32x4{bv, bv, bv, bv};
        acc[1][tc] = f32x4{bv, bv, bv, bv};
    }

    const unsigned short* __restrict__ Wh = g.Whi[ph];
    const unsigned short* __restrict__ Wl = g.Wlo[ph];

    for (int ch = 0; ch < 2; ++ch) {
        __syncthreads();
        #pragma unroll
        for (int it = 0; it < 8; ++it) {
            const int idx = tid + 256 * it;
            const int r = idx >> 4, kq = (idx & 15) * 4;
            f4 v = {0.f, 0.f, 0.f, 0.f};
            if (r < nrows) v = *(const f4*)&A[(size_t)(row0 + r) * HID + ch * 64 + kq];
            ushort4 h, l;
            split2(v[0], h.x, l.x); split2(v[1], h.y, l.y);
            split2(v[2], h.z, l.z); split2(v[3], h.w, l.w);
            *(ushort4*)&Ahi[r * KPAD + kq] = h;
            *(ushort4*)&Alo[r * KPAD + kq] = l;
        }
        #pragma unroll
        for (int it = 0; it < 4; ++it) {
            const int idx = tid + 256 * it;
            const int c = idx >> 3, k8 = (idx & 7) * 8;
            *(uint4*)&Bhi[c * KPAD + k8] = *(const uint4*)&Wh[(size_t)c * HID + ch * 64 + k8];
            *(uint4*)&Blo[c * KPAD + k8] = *(const uint4*)&Wl[(size_t)c * HID + ch * 64 + k8];
        }
        __syncthreads();

        #pragma unroll
        for (int ks = 0; ks < 2; ++ks) {
            const int ko = ks * 32 + kgrp * 8;
            bf16x8 ah[2], al[2], bh[8], bl[8];
            #pragma unroll
            for (int tr = 0; tr < 2; ++tr) {
                const int rr = w * 32 + tr * 16 + lrow;
                ah[tr] = *(const bf16x8*)&Ahi[rr * KPAD + ko];
                al[tr] = *(const bf16x8*)&Alo[rr * KPAD + ko];
            }
            #pragma unroll
            for (int tc = 0; tc < 8; ++tc) {
                const int cc = tc * 16 + lrow;
                bh[tc] = *(const bf16x8*)&Bhi[cc * KPAD + ko];
                bl[tc] = *(const bf16x8*)&Blo[cc * KPAD + ko];
            }
            #pragma unroll
            for (int tr = 0; tr < 2; ++tr)
                #pragma unroll
                for (int tc = 0; tc < 8; ++tc) {
                    acc[tr][tc] = __builtin_amdgcn_mfma_f32_16x16x32_bf16(ah[tr], bh[tc], acc[tr][tc], 0, 0, 0);
                    acc[tr][tc] = __builtin_amdgcn_mfma_f32_16x16x32_bf16(al[tr], bh[tc], acc[tr][tc], 0, 0, 0);
                    acc[tr][tc] = __builtin_amdgcn_mfma_f32_16x16x32_bf16(ah[tr], bl[tc], acc[tr][tc], 0, 0, 0);
                }
        }
    }

    #pragma unroll
    for (int tr = 0; tr < 2; ++tr)
        #pragma unroll
        for (int j = 0; j < 4; ++j) {
            const int r = w * 32 + tr * 16 + kgrp * 4 + j;
            if (r < nrows) {
                if (g.of32[ph]) {
                    float* O = (float*)g.O[ph];
                    #pragma unroll
                    for (int tc = 0; tc < 8; ++tc)
                        O[(size_t)(row0 + r) * HID + tc * 16 + lrow] = acc[tr][tc][j];
                } else {
                    unsigned short* O = (unsigned short*)g.O[ph];
                    #pragma unroll
                    for (int tc = 0; tc < 8; ++tc)
                        O[(size_t)(row0 + r) * HID + tc * 16 + lrow] = f2bf(acc[tr][tc][j]);
                }
            }
        }
}

// ---------------------------------------------------------------------------
// k_final: out = LN(relu(mattB@WA + H@Wself + s@Wstr + biases) + H)
// Phase 0: A = mattB (exact bf16 -> 2 MFMA); phase 1: A = H (split, 3 MFMA).
// ---------------------------------------------------------------------------
__global__ __launch_bounds__(256, 2) void k_final(
    const unsigned short* __restrict__ MattB, const float* __restrict__ H,
    const unsigned short* __restrict__ WAhi, const unsigned short* __restrict__ WAlo,
    const unsigned short* __restrict__ WShi, const unsigned short* __restrict__ WSlo,
    const float* __restrict__ Wstr,
    const float* __restrict__ bself, const float* __restrict__ bA,
    const float* __restrict__ bstr,
    const float* __restrict__ lng, const float* __restrict__ lnb,
    float* __restrict__ out, int N)
{
    extern __shared__ unsigned short lds[];
    unsigned short* Ahi = lds;
    unsigned short* Alo = lds + 128 * KPAD;
    unsigned short* Bhi = lds + 2 * 128 * KPAD;
    unsigned short* Blo = lds + 3 * 128 * KPAD;
    const int tid  = threadIdx.x;
    const int row0 = blockIdx.x * 128;
    const int nrows = min(128, N - row0);
    const int w    = tid >> 6, lane = tid & 63;
    const int lrow = lane & 15, kgrp = lane >> 4;

    f32x4 acc[2][8];
    float gl[8], bl_[8];
    #pragma unroll
    for (int tc = 0; tc < 8; ++tc) {
        const int c = tc * 16 + lrow;
        const float bv = bself[c] + bA[c] + bstr[c];
        acc[0][tc] = f32x4{bv, bv, bv, bv};
        acc[1][tc] = f32x4{bv, bv, bv, bv};
        gl[tc] = lng[c]; bl_[tc] = lnb[c];
    }

    for (int ph = 0; ph < 2; ++ph) {
        const unsigned short* __restrict__ Wh = ph ? WShi : WAhi;
        const unsigned short* __restrict__ Wl = ph ? WSlo : WAlo;
        for (int ch = 0; ch < 2; ++ch) {
            __syncthreads();
            if (ph == 0) {
                // A = mattB bf16 (exact): Ahi only
                #pragma unroll
                for (int it = 0; it < 4; ++it) {
                    const int idx = tid + 256 * it;          // uint4 units
                    const int r = idx >> 3, k8 = (idx & 7) * 8;
                    uint4 v = {0u, 0u, 0u, 0u};
                    if (r < nrows) v = *(const uint4*)&MattB[(size_t)(row0 + r) * HID + ch * 64 + k8];
                    *(uint4*)&Ahi[r * KPAD + k8] = v;
                }
            } else {
                #pragma unroll
                for (int it = 0; it < 8; ++it) {
                    const int idx = tid + 256 * it;
                    const int r = idx >> 4, kq = (idx & 15) * 4;
                    f4 v = {0.f, 0.f, 0.f, 0.f};
                    if (r < nrows) v = *(const f4*)&H[(size_t)(row0 + r) * HID + ch * 64 + kq];
                    ushort4 h, l;
                    split2(v[0], h.x, l.x); split2(v[1], h.y, l.y);
                    split2(v[2], h.z, l.z); split2(v[3], h.w, l.w);
                    *(ushort4*)&Ahi[r * KPAD + kq] = h;
                    *(ushort4*)&Alo[r * KPAD + kq] = l;
                }
            }
            #pragma unroll
            for (int it = 0; it < 4; ++it) {
                const int idx = tid + 256 * it;
                const int c = idx >> 3, k8 = (idx & 7) * 8;
                *(uint4*)&Bhi[c * KPAD + k8] = *(const uint4*)&Wh[(size_t)c * HID + ch * 64 + k8];
                *(uint4*)&Blo[c * KPAD + k8] = *(const uint4*)&Wl[(size_t)c * HID + ch * 64 + k8];
            }
            __syncthreads();

            #pragma unroll
            for (int ks = 0; ks < 2; ++ks) {
                const int ko = ks * 32 + kgrp * 8;
                bf16x8 ah[2], al[2], bh[8], bl[8];
                #pragma unroll
                for (int tr = 0; tr < 2; ++tr) {
                    const int rr = w * 32 + tr * 16 + lrow;
                    ah[tr] = *(const bf16x8*)&Ahi[rr * KPAD + ko];
                    if (ph) al[tr] = *(const bf16x8*)&Alo[rr * KPAD + ko];
                }
                #pragma unroll
                for (int tc = 0; tc < 8; ++tc) {
                    const int cc = tc * 16 + lrow;
                    bh[tc] = *(const bf16x8*)&Bhi[cc * KPAD + ko];
                    bl[tc] = *(const bf16x8*)&Blo[cc * KPAD + ko];
                }
                #pragma unroll
                for (int tr = 0; tr < 2; ++tr)
                    #pragma unroll
                    for (int tc = 0; tc < 8; ++tc) {
                        acc[tr][tc] = __builtin_amdgcn_mfma_f32_16x16x32_bf16(ah[tr], bh[tc], acc[tr][tc], 0, 0, 0);
                        if (ph)
                            acc[tr][tc] = __builtin_amdgcn_mfma_f32_16x16x32_bf16(al[tr], bh[tc], acc[tr][tc], 0, 0, 0);
                        acc[tr][tc] = __builtin_amdgcn_mfma_f32_16x16x32_bf16(ah[tr], bl[tc], acc[tr][tc], 0, 0, 0);
                    }
            }

            if (ph == 1 && ch == 0) {
                // s_feat (= H[:, :6]) @ Wstr off the staged H chunk (hi+lo)
                #pragma unroll
                for (int tr = 0; tr < 2; ++tr)
                    #pragma unroll
                    for (int j = 0; j < 4; ++j) {
                        const int rr = w * 32 + tr * 16 + kgrp * 4 + j;
                        float s[NSTR];
                        #pragma unroll
                        for (int k = 0; k < NSTR; ++k)
                            s[k] = bf2f(Ahi[rr * KPAD + k]) + bf2f(Alo[rr * KPAD + k]);
                        #pragma unroll
                        for (int tc = 0; tc < 8; ++tc) {
                            float a = 0.f;
                            #pragma unroll
                            for (int k = 0; k < NSTR; ++k)
                                a = fmaf(s[k], Wstr[k * HID + tc * 16 + lrow], a);
                            acc[tr][tc][j] += a;
                        }
                    }
            }
        }
    }

    // ---- relu + residual + LayerNorm ----
    #pragma unroll
    for (int tr = 0; tr < 2; ++tr)
        #pragma unroll
        for (int j = 0; j < 4; ++j) {
            const int r = w * 32 + tr * 16 + kgrp * 4 + j;
            const bool valid = r < nrows;
            const size_t rb = (size_t)(row0 + r) * HID;
            float v[8], s1 = 0.f, s2 = 0.f;
            #pragma unroll
            for (int tc = 0; tc < 8; ++tc) {
                float x = fmaxf(acc[tr][tc][j], 0.f);
                if (valid) x += H[rb + tc * 16 + lrow];
                v[tc] = x;
                s1 += x; s2 += x * x;
            }
            #pragma unroll
            for (int mk = 1; mk < 16; mk <<= 1) {
                s1 += __shfl_xor(s1, mk);
                s2 += __shfl_xor(s2, mk);
            }
            const float mean = s1 * (1.f / HID);
            const float var  = s2 * (1.f / HID) - mean * mean;
            const float rs   = rsqrtf(var + LN_EPS);
            if (valid) {
                #pragma unroll
                for (int tc = 0; tc < 8; ++tc)
                    out[rb + tc * 16 + lrow] = (v[tc] - mean) * rs * gl[tc] + bl_[tc];
            }
        }
}

// psi[n] = dot(H[n], f_def_w) + f_def_b   (wave per node)
__global__ __launch_bounds__(256) void k_psi(
    const float* __restrict__ H, const float* __restrict__ fw, const float* __restrict__ fb,
    float* __restrict__ psi, int N)
{
    const int wid = threadIdx.x >> 6, lane = threadIdx.x & 63;
    const int n = blockIdx.x * 4 + wid;
    if (n >= N) return;
    const size_t o = (size_t)n * HID;
    float a = H[o + lane] * fw[lane] + H[o + 64 + lane] * fw[64 + lane];
    #pragma unroll
    for (int off = 32; off; off >>= 1) a += __shfl_down(a, off);
    if (lane == 0) psi[n] = a + fb[0];
}

// ---------------------------------------------------------------------------
// CSR-by-target build: histogram, single-block scan, fill
// ---------------------------------------------------------------------------
__global__ __launch_bounds__(256) void k_hist(
    const int* __restrict__ etgt, int* __restrict__ deg, int E)
{
    const int e = blockIdx.x * 256 + threadIdx.x;
    if (e < E) atomicAdd(&deg[etgt[e]], 1);
}

__global__ __launch_bounds__(1024) void k_scan(
    const int* __restrict__ deg, int* __restrict__ base, int N)
{
    __shared__ int warp_sums[16];
    __shared__ int carry_s;
    const int tid = threadIdx.x, lane = tid & 63, wid = tid >> 6;
    if (tid == 0) carry_s = 0;
    __syncthreads();
    for (int i0 = 0; i0 < N; i0 += 1024) {
        const int i = i0 + tid;
        const int v = (i < N) ? deg[i] : 0;
        int x = v;
        #pragma unroll
        for (int d = 1; d < 64; d <<= 1) {
            const int y = __shfl_up(x, d);
            if (lane >= d) x += y;
        }
        if (lane == 63) warp_sums[wid] = x;
        __syncthreads();
        if (wid == 0) {
            int ws = (lane < 16) ? warp_sums[lane] : 0;
            #pragma unroll
            for (int d = 1; d < 16; d <<= 1) {
                const int y = __shfl_up(ws, d);
                if (lane >= d) ws += y;
            }
            if (lane < 16) warp_sums[lane] = ws;
        }
        __syncthreads();
        const int carry = carry_s;
        if (i < N) base[i] = carry + (wid ? warp_sums[wid - 1] : 0) + x - v;
        __syncthreads();
        if (tid == 1023) carry_s = carry + warp_sums[15];
        __syncthreads();
    }
    if (tid == 0) base[N] = carry_s;
}

__global__ __launch_bounds__(256) void k_fill(
    const int* __restrict__ etgt, const int* __restrict__ base,
    int* __restrict__ cur, int* __restrict__ eid_t, int E)
{
    const int e = blockIdx.x * 256 + threadIdx.x;
    if (e < E) {
        const int t = etgt[e];
        const int p = atomicAdd(&cur[t], 1);
        eid_t[base[t] + p] = e;
    }
}

// ---------------------------------------------------------------------------
// k_score v2: wave per TARGET node, 16-lane edge groups. SINGLE 256 B gather
// per edge (HB[src]); both dots use it: score = Wt[tgt].hs, pair = U[tgt].hs.
// ---------------------------------------------------------------------------
__global__ __launch_bounds__(256) void k_score(
    const int* __restrict__ eid_t, const int* __restrict__ base_t,
    const int* __restrict__ esrc,
    const float* __restrict__ Wt,
    const unsigned short* __restrict__ UB,
    const unsigned short* __restrict__ HB,
    float* __restrict__ score, float* __restrict__ pairv,
    unsigned* __restrict__ maxs, float* __restrict__ sumt_inv, int N)
{
    const int lane = threadIdx.x & 63, wv = threadIdx.x >> 6;
    const int t = blockIdx.x * 4 + wv;
    if (t >= N) return;
    const int b0 = base_t[t], deg = base_t[t + 1] - b0;
    if (deg == 0) { if (lane == 0) sumt_inv[t] = 0.f; return; }
    const int sub = lane & 15, grp = lane >> 4;
    const size_t to = (size_t)t * HID;

    float wt[8], u[8], htg[8];
    {
        const f4 w0 = *(const f4*)&Wt[to + sub * 8];
        const f4 w1 = *(const f4*)&Wt[to + sub * 8 + 4];
        wt[0] = w0[0]; wt[1] = w0[1]; wt[2] = w0[2]; wt[3] = w0[3];
        wt[4] = w1[0]; wt[5] = w1[1]; wt[6] = w1[2]; wt[7] = w1[3];
        unpack8(*(const uint4*)&UB[to + sub * 8], u);
        unpack8(*(const uint4*)&HB[to + sub * 8], htg);  // only sub==0 uses it
    }

    for (int j0 = 0; j0 < deg; j0 += 4) {
        const int jj = j0 + grp;
        const bool val = jj < deg;
        int eid = 0, src = 0;
        if (val) { eid = eid_t[b0 + jj]; src = esrc[eid]; }
        const size_t so = (size_t)src * HID;
        float hs[8];
        unpack8(*(const uint4*)&HB[so + sub * 8], hs);
        float ps = 0.f, pp = 0.f;
        #pragma unroll
        for (int d = 0; d < 8; ++d) {
            ps = fmaf(wt[d], hs[d], ps);
            pp = fmaf(u[d], hs[d], pp);
        }
        if (sub == 0) {  // struct term: dims 0..5 live in this lane's regs
            #pragma unroll
            for (int d = 0; d < NSTR; ++d) ps = fmaf(htg[d], hs[d], ps);
        }
        #pragma unroll
        for (int mk = 1; mk < 16; mk <<= 1) {
            ps += __shfl_xor(ps, mk);
            pp += __shfl_xor(pp, mk);
        }
        if (sub == 0 && val) {
            score[b0 + jj] = ps;
            pairv[eid] = pp;
            atomicMax(&maxs[src], enc_f(pp));
        }
    }

    float m = -1e30f;
    for (int i = lane; i < deg; i += 64) m = fmaxf(m, score[b0 + i]);
    #pragma unroll
    for (int mk = 1; mk < 64; mk <<= 1) m = fmaxf(m, __shfl_xor(m, mk));
    float psum = 0.f;
    for (int i = lane; i < deg; i += 64) {
        const float e = expf(score[b0 + i] - m);
        score[b0 + i] = e;
        psum += e;
    }
    #pragma unroll
    for (int mk = 1; mk < 64; mk <<= 1) psum += __shfl_xor(psum, mk);
    if (lane == 0) sumt_inv[t] = 1.f / psum;
}

// per edge: e = exp(pair - max_src); sums[s] += e; num[s] += e * exp(-psi[t])
__global__ __launch_bounds__(256) void k_beta(
    const int* __restrict__ esrc, const int* __restrict__ etgt,
    const float* __restrict__ pairv, const unsigned* __restrict__ maxs,
    const float* __restrict__ psi,
    float* __restrict__ sums, float* __restrict__ num, int E)
{
    const int e = blockIdx.x * 256 + threadIdx.x;
    if (e >= E) return;
    const int s = esrc[e], t = etgt[e];
    const float ep = expf(pairv[e] - dec_f(maxs[s]));
    atomicAdd(&sums[s], ep);
    atomicAdd(&num[s], ep * expf(-psi[t]));
}

// per node: sum_term = num/sums; rho1m = 1 - sigmoid(GAMMA*(-log(st+1e-8)-DELTA))
__global__ __launch_bounds__(256) void k_rho(
    const float* __restrict__ sums, const float* __restrict__ num,
    float* __restrict__ rho1m, int N)
{
    const int n = blockIdx.x * 256 + threadIdx.x;
    if (n >= N) return;
    const float sm = sums[n];
    const float st = (sm > 0.f) ? num[n] / sm : 0.f;
    const float d  = -logf(st + 1e-8f);
    rho1m[n] = 1.f - 1.f / (1.f + expf(-(GAMMA * (d - DELTA))));
}

// ---------------------------------------------------------------------------
// k_matt: wave per TARGET, 16-lane edge groups; Hphi gathered bf16; out bf16.
// ---------------------------------------------------------------------------
__global__ __launch_bounds__(256) void k_matt(
    const int* __restrict__ eid_t, const int* __restrict__ base_t,
    const int* __restrict__ esrc,
    const float* __restrict__ score, const float* __restrict__ sumt_inv,
    const float* __restrict__ rho1m,
    const unsigned short* __restrict__ HphiB,
    unsigned short* __restrict__ mattB, int N)
{
    const int lane = threadIdx.x & 63, wv = threadIdx.x >> 6;
    const int t = blockIdx.x * 4 + wv;
    if (t >= N) return;
    const int b0 = base_t[t], deg = base_t[t + 1] - b0;
    const int sub = lane & 15, grp = lane >> 4;
    const size_t to = (size_t)t * HID;

    float acc[8];
    #pragma unroll
    for (int d = 0; d < 8; ++d) acc[d] = 0.f;
    const float inv = (deg > 0) ? sumt_inv[t] : 0.f;

    for (int j0 = 0; j0 < deg; j0 += 4) {
        const int jj = j0 + grp;
        const bool val = jj < deg;
        float c = 0.f;
        size_t so = 0;
        if (val) {
            const int eid = eid_t[b0 + jj];
            const int src = esrc[eid];
            c = score[b0 + jj] * inv * rho1m[src];
            so = (size_t)src * HID;
        }
        float hf[8];
        unpack8(*(const uint4*)&HphiB[so + sub * 8], hf);
        #pragma unroll
        for (int d = 0; d < 8; ++d) acc[d] = fmaf(c, hf[d], acc[d]);
    }
    #pragma unroll
    for (int d = 0; d < 8; ++d) {
        acc[d] += __shfl_xor(acc[d], 16);
        acc[d] += __shfl_xor(acc[d], 32);
    }
    if (grp == 0) {
        ushort4 o0, o1;
        o0.x = f2bf(acc[0]); o0.y = f2bf(acc[1]); o0.z = f2bf(acc[2]); o0.w = f2bf(acc[3]);
        o1.x = f2bf(acc[4]); o1.y = f2bf(acc[5]); o1.z = f2bf(acc[6]); o1.w = f2bf(acc[7]);
        *(ushort4*)&mattB[to + sub * 8]     = o0;
        *(ushort4*)&mattB[to + sub * 8 + 4] = o1;
    }
}

extern "C" void kernel_launch(void* const* d_in, const int* in_sizes, int n_in,
                              void* d_out, int out_size, void* d_ws, size_t ws_size,
                              hipStream_t stream)
{
    const int*   eidx   = (const int*)  d_in[0];
    const float* H      = (const float*)d_in[1];
    const float* W_att  = (const float*)d_in[2];
    const float* phi_w  = (const float*)d_in[3];
    const float* phi_b  = (const float*)d_in[4];
    const float* W_p    = (const float*)d_in[5];
    const float* W_pp   = (const float*)d_in[6];
    const float* fdef_w = (const float*)d_in[7];
    const float* fdef_b = (const float*)d_in[8];
    const float* Wself  = (const float*)d_in[9];
    const float* bself  = (const float*)d_in[10];
    const float* WA     = (const float*)d_in[11];
    const float* bA     = (const float*)d_in[12];
    const float* Wstr   = (const float*)d_in[13];
    const float* bstr   = (const float*)d_in[14];
    const float* lng    = (const float*)d_in[15];
    const float* lnb    = (const float*)d_in[16];
    float* out = (float*)d_out;

    const int E = in_sizes[0] / 2;
    const int N = in_sizes[1] / HID;
    const int* esrc = eidx;
    const int* etgt = eidx + E;

    // ---- workspace layout (~88 MB) ----
    char* w = (char*)d_ws;
    const size_t NHb  = (size_t)N * HID * sizeof(unsigned short);     // 12.8 MB
    const size_t NH   = (size_t)N * HID * sizeof(float);              // 25.6 MB
    const size_t Epad = (((size_t)E * sizeof(float)) + 255) & ~255ull;
    const size_t Npad = (((size_t)(N + 1) * sizeof(float)) + 255) & ~255ull;

    float*          Wt    = (float*)w;          w += NH;   // f32 tgt table
    unsigned short* UB    = (unsigned short*)w; w += NHb;  // bf16 tgt table
    unsigned short* HB    = (unsigned short*)w; w += NHb;  // bf16 gather table
    unsigned short* HphiB = (unsigned short*)w; w += NHb;  // bf16 gather table
    unsigned short* mattB = (unsigned short*)w; w += NHb;
    float* score = (float*)w; w += Epad;
    float* pairv = (float*)w; w += Epad;
    int*   eid_t = (int*)  w; w += Epad;
    char*  zero0 = w;                    // 5 contiguous zero-init arrays
    int*      deg_t = (int*)     w; w += Npad;
    int*      cur_t = (int*)     w; w += Npad;
    unsigned* maxs  = (unsigned*)w; w += Npad;
    float*    sums  = (float*)   w; w += Npad;
    float*    num   = (float*)   w; w += Npad;
    int*   base_t   = (int*)     w; w += Npad;  // N+1 entries
    float* sumt_inv = (float*)   w; w += Npad;
    float* psi      = (float*)   w; w += Npad;
    float* rho1m    = (float*)   w; w += Npad;
    unsigned short* WT = (unsigned short*)w;    // 5 slots x 2 planes x 128x128
    w += 5 * 2 * HID * HID * sizeof(unsigned short);

    const int nblk128 = (N + 127) / 128;
    const int nblkN4  = (N + 3) / 4;
    const int nblkE   = (E + 255) / 256;
    const size_t lds_mfma = 4 * 128 * KPAD * sizeof(unsigned short);  // 72 KB
    const size_t MSZ = (size_t)2 * HID * HID;

    hipMemsetAsync(zero0, 0, 5 * Npad, stream);  // deg_t, cur_t, maxs, sums, num

    // weight prep: slot0 = W_att (natural, for H@W_att^T), slot1 = M2,
    // slot2 = phi_w (T), slot3 = WA (T), slot4 = Wself (T)
    PrepArgs pa;
    pa.W[0] = W_att; pa.tr[0] = 0;
    pa.W[1] = phi_w; pa.tr[1] = 1;
    pa.W[2] = WA;    pa.tr[2] = 1;
    pa.W[3] = Wself; pa.tr[3] = 1;
    k_prep<<<dim3(8, 4), 256, 0, stream>>>(pa, WT);        // writes slots 0..3
    k_m2<<<8, 256, 0, stream>>>(W_p, W_pp, WT + 4 * MSZ);  // slot 4 = M2

    k_cast<<<(N * HID / 8 + 255) / 256, 256, 0, stream>>>(H, HB, N * HID / 8);

    GemmArgsT g3;
    g3.Whi[0] = WT;            g3.Wlo[0] = WT + HID * HID;             // W_att nat
    g3.Whi[1] = WT + 4 * MSZ;  g3.Wlo[1] = WT + 4 * MSZ + HID * HID;   // M2
    g3.Whi[2] = WT + 1 * MSZ;  g3.Wlo[2] = WT + 1 * MSZ + HID * HID;   // phi_w T
    g3.b[0] = nullptr; g3.b[1] = nullptr; g3.b[2] = phi_b;
    g3.O[0] = Wt;  g3.of32[0] = 1;
    g3.O[1] = UB;  g3.of32[1] = 0;
    g3.O[2] = HphiB; g3.of32[2] = 0;
    k_gemm<<<dim3(nblk128, 3), 256, lds_mfma, stream>>>(H, g3, N);

    k_psi<<<nblkN4, 256, 0, stream>>>(H, fdef_w, fdef_b, psi, N);

    k_hist<<<nblkE, 256, 0, stream>>>(etgt, deg_t, E);
    k_scan<<<1, 1024, 0, stream>>>(deg_t, base_t, N);
    k_fill<<<nblkE, 256, 0, stream>>>(etgt, base_t, cur_t, eid_t, E);

    k_score<<<nblkN4, 256, 0, stream>>>(eid_t, base_t, esrc, Wt, UB, HB,
                                        score, pairv, maxs, sumt_inv, N);
    k_beta<<<nblkE, 256, 0, stream>>>(esrc, etgt, pairv, maxs, psi, sums, num, E);
    k_rho<<<(N + 255) / 256, 256, 0, stream>>>(sums, num, rho1m, N);

    k_matt<<<nblkN4, 256, 0, stream>>>(eid_t, base_t, esrc, score, sumt_inv,
                                       rho1m, HphiB, mattB, N);

    k_final<<<nblk128, 256, lds_mfma, stream>>>(mattB, H,
                                                WT + 2 * MSZ, WT + 2 * MSZ + HID * HID,
                                                WT + 3 * MSZ, WT + 3 * MSZ + HID * HID,
                                                Wstr, bself, bA, bstr, lng, lnb, out, N);
}